// Round 1
// baseline (3568.331 us; speedup 1.0000x reference)
//
#include <hip/hip_runtime.h>
#include <cstdint>
#include <cstddef>

#define S_ 512
#define B_ 16
#define H_ 8
#define D_ 64
#define E_ 512
#define FFN_ 2048
#define R_ (S_*B_)          // 8192 rows (s*B+b)
#define EPSF 1e-6f
#define PROJ_M 0.99999f     // 1 - 1e-5

typedef __attribute__((ext_vector_type(8))) short bf16x8;
typedef __attribute__((ext_vector_type(4))) float f32x4;

// ---------- small helpers ----------
__device__ __forceinline__ float bf2f(uint32_t u){
  union{uint32_t i; float f;} c; c.i = u<<16; return c.f;
}
__device__ __forceinline__ uint16_t f2bf(float f){
  union{float f; uint32_t i;} c; c.f = f;
  return (uint16_t)((c.i + 0x7FFFu + ((c.i>>16)&1u))>>16);
}
__device__ __forceinline__ void unpack8(uint4 u, float* f){
  f[0]=bf2f(u.x&0xFFFFu); f[1]=bf2f(u.x>>16);
  f[2]=bf2f(u.y&0xFFFFu); f[3]=bf2f(u.y>>16);
  f[4]=bf2f(u.z&0xFFFFu); f[5]=bf2f(u.z>>16);
  f[6]=bf2f(u.w&0xFFFFu); f[7]=bf2f(u.w>>16);
}
__device__ __forceinline__ uint4 pack8(const float* f){
  uint4 u;
  u.x = (uint32_t)f2bf(f[0]) | ((uint32_t)f2bf(f[1])<<16);
  u.y = (uint32_t)f2bf(f[2]) | ((uint32_t)f2bf(f[3])<<16);
  u.z = (uint32_t)f2bf(f[4]) | ((uint32_t)f2bf(f[5])<<16);
  u.w = (uint32_t)f2bf(f[6]) | ((uint32_t)f2bf(f[7])<<16);
  return u;
}
// artanh with the reference's clip at 1-1e-7; values >= f32(1-1e-7+) return atanh(1-1e-7)
__device__ __forceinline__ float artanh_c(float x){
  return (x >= 0.99999994f) ? 8.4056215f : atanhf(x);
}
__device__ __forceinline__ float wave_sum(float x){
  #pragma unroll
  for(int o=32;o>=1;o>>=1) x += __shfl_xor(x,o);
  return x;
}
__device__ __forceinline__ float block_sum(float x, float* sb){
  x = wave_sum(x);
  const int w = threadIdx.x >> 6;
  __syncthreads();
  if((threadIdx.x & 63)==0) sb[w] = x;
  __syncthreads();
  return sb[0]+sb[1]+sb[2]+sb[3];
}

// ---------- fp32 -> bf16 weight conversion ----------
__global__ void cvt_k(const float* __restrict__ s, uint16_t* __restrict__ d, int n){
  int i = blockIdx.x*256 + threadIdx.x;
  if(i < n) d[i] = f2bf(s[i]);
}

// ---------- plain layernorm (euclid), row=512, out bf16 ----------
__global__ __launch_bounds__(256) void ln_k(const float* __restrict__ x,
  const float* __restrict__ g, const float* __restrict__ b, uint16_t* __restrict__ out)
{
  __shared__ float sb[4];
  const int row = blockIdx.x, t = threadIdx.x;
  const size_t base = (size_t)row*E_;
  float v0 = x[base+t], v1 = x[base+t+256];
  const float mu  = block_sum(v0+v1, sb) * (1.f/E_);
  const float d0 = v0-mu, d1 = v1-mu;
  const float var = block_sum(d0*d0+d1*d1, sb) * (1.f/E_);
  const float rs = 1.f/sqrtf(var + 1e-5f);
  out[base+t]     = f2bf(d0*rs*g[t] + b[t]);
  out[base+t+256] = f2bf(d1*rs*g[t+256] + b[t+256]);
}

// ---------- hyp: expmap0(LN(logmap0(x))) [+projx], out bf16 + analytic row norm ----------
__global__ __launch_bounds__(256) void hyp_lnexp(const float* __restrict__ x,
  const float* __restrict__ g, const float* __restrict__ b,
  uint16_t* __restrict__ out, float* __restrict__ nout, int do_projx)
{
  __shared__ float sb[4];
  const int row = blockIdx.x, t = threadIdx.x;
  const size_t base = (size_t)row*E_;
  float v0 = x[base+t], v1 = x[base+t+256];
  const float s2 = block_sum(v0*v0+v1*v1, sb);
  const float n  = sqrtf(s2 + 1e-15f);
  const float ls = artanh_c(n)/n;          // logmap0 scale
  v0 *= ls; v1 *= ls;
  const float mu  = block_sum(v0+v1, sb) * (1.f/E_);
  const float d0 = v0-mu, d1 = v1-mu;
  const float var = block_sum(d0*d0+d1*d1, sb) * (1.f/E_);
  const float rs = 1.f/sqrtf(var + 1e-5f);
  float t0 = d0*rs*g[t] + b[t];
  float t1 = d1*rs*g[t+256] + b[t+256];
  const float n2s = block_sum(t0*t0+t1*t1, sb);
  const float n2 = sqrtf(n2s + 1e-15f);
  const float nh = tanhf(n2);               // expmap0: analytic output norm
  const float scl = nh/n2;
  t0 *= scl; t1 *= scl;
  float nrm = nh;
  if(do_projx && nrm > PROJ_M){ const float s = PROJ_M/nrm; t0*=s; t1*=s; nrm = PROJ_M; }
  out[base+t] = f2bf(t0); out[base+t+256] = f2bf(t1);
  if(t==0) nout[row] = nrm;
}

// ---------- y = expmap0(bias); y[C] = |y|^2 (analytic) ----------
__global__ __launch_bounds__(256) void expmap0_vec(const float* __restrict__ b,
  float* __restrict__ y, int C)
{
  __shared__ float sb[4];
  const int t = threadIdx.x;
  const int npc = C >> 8;
  float v[8];
  float s2 = 0.f;
  for(int i=0;i<npc;i++){ v[i] = b[t+256*i]; s2 += v[i]*v[i]; }
  s2 = block_sum(s2, sb);
  const float n = sqrtf(s2 + 1e-15f);
  const float sc = tanhf(n)/n;
  for(int i=0;i<npc;i++) y[t+256*i] = v[i]*sc;
  if(t==0) y[C] = tanhf(n)*tanhf(n);
}

// ---------- man_linear epilogue: mobius_matvec scale + mobius_add(y) + projx
// flags: 1 = relu after (recompute norm), 2 = per-head(64) projx (C==512 only)
template<int NPC>
__global__ __launch_bounds__(256) void man_epi(
  const float* __restrict__ mx, const float* __restrict__ nxbuf,
  const float* __restrict__ y, uint16_t* __restrict__ outb,
  float* __restrict__ outf, float* __restrict__ nout, int flags)
{
  constexpr int C = NPC*256;
  __shared__ float sb[4];
  const int row = blockIdx.x;
  const int t = threadIdx.x;
  float v[NPC], yv[NPC];
  float s2 = 0.f;
  #pragma unroll
  for(int i=0;i<NPC;i++){
    v[i]  = mx[(size_t)row*C + t + 256*i];
    yv[i] = y[t + 256*i];
    s2 += v[i]*v[i];
  }
  s2 = block_sum(s2, sb);
  const float nmx = sqrtf(s2 + 1e-15f);
  const float nx  = nxbuf[row];
  const float sc  = tanhf(nmx/nx * artanh_c(nx));
  const bool ok   = (nmx > 1e-7f);
  const float fmul = ok ? (sc/nmx) : 0.f;
  const float x2   = ok ? sc*sc : 0.f;     // |x~|^2 analytic
  float xy = 0.f;
  #pragma unroll
  for(int i=0;i<NPC;i++){ v[i] *= fmul; xy += v[i]*yv[i]; }
  xy = block_sum(xy, sb);
  const float y2 = y[C];
  const float aa = 1.f + 2.f*xy + y2;
  const float bb = 1.f - x2;
  const float den = fmaxf(1.f + 2.f*xy + x2*y2, EPSF);
  const float iden = 1.f/den;
  const float num2 = aa*aa*x2 + 2.f*aa*bb*xy + bb*bb*y2;   // |num|^2 analytic
  const float nz = sqrtf(num2*iden*iden + 1e-15f);
  const float ps = (nz > PROJ_M) ? (PROJ_M/nz) : 1.f;
  float nfin = (nz > PROJ_M) ? PROJ_M : nz;
  #pragma unroll
  for(int i=0;i<NPC;i++) v[i] = (aa*v[i] + bb*yv[i]) * iden * ps;
  if(flags & 2){
    // per-head projx: seg w handled by wave w (v[0]) and seg w+4 (v[1])
    const float h0 = wave_sum(v[0]*v[0]);
    const float h1 = wave_sum(v[1]*v[1]);
    const float n0 = sqrtf(h0 + 1e-15f);
    const float n1 = sqrtf(h1 + 1e-15f);
    if(n0 > PROJ_M) v[0] *= PROJ_M/n0;
    if(n1 > PROJ_M) v[1] *= PROJ_M/n1;
  }
  if(flags & 1){
    float rs = 0.f;
    #pragma unroll
    for(int i=0;i<NPC;i++){ v[i] = fmaxf(v[i],0.f); rs += v[i]*v[i]; }
    rs = block_sum(rs, sb);
    nfin = sqrtf(rs + 1e-15f);
  }
  #pragma unroll
  for(int i=0;i<NPC;i++){
    if(outb) outb[(size_t)row*C + t + 256*i] = f2bf(v[i]);
    if(outf) outf[(size_t)row*C + t + 256*i] = v[i];
  }
  if(nout && t==0) nout[row] = nfin;
}

// ---------- hyp attention-output finish: per-head msm(0.5)+projx, full projx, bf16 out + norm ----------
__global__ __launch_bounds__(256) void o_finish(const float* __restrict__ op,
  uint16_t* __restrict__ outb, float* __restrict__ nout)
{
  __shared__ float segn2[8];
  const int row = blockIdx.x, t = threadIdx.x, w = t>>6;
  const size_t base = (size_t)row*E_;
  float v0 = op[base+t], v1 = op[base+t+256];
  const float h0 = wave_sum(v0*v0);
  const float h1 = wave_sum(v1*v1);
  const float ns0 = sqrtf(h0+1e-15f), ns1 = sqrtf(h1+1e-15f);
  const float tt0 = tanhf(0.5f*artanh_c(ns0));
  const float tt1 = tanhf(0.5f*artanh_c(ns1));
  v0 *= tt0/ns0; v1 *= tt1/ns1;
  float sn0 = tt0, sn1 = tt1;
  if(sn0 > PROJ_M){ v0 *= PROJ_M/sn0; sn0 = PROJ_M; }
  if(sn1 > PROJ_M){ v1 *= PROJ_M/sn1; sn1 = PROJ_M; }
  if((t&63)==0){ segn2[w] = sn0*sn0; segn2[w+4] = sn1*sn1; }
  __syncthreads();
  const float tot = segn2[0]+segn2[1]+segn2[2]+segn2[3]+segn2[4]+segn2[5]+segn2[6]+segn2[7];
  const float n = sqrtf(tot + 1e-15f);
  float nf = n;
  if(n > PROJ_M){ const float s = PROJ_M/n; v0*=s; v1*=s; nf = PROJ_M; }
  outb[base+t] = f2bf(v0);
  outb[base+t+256] = f2bf(v1);
  if(t==0) nout[row] = nf;
}

// ---------- Mobius gyromidpoint residual (+optional projx), fp32 in/out ----------
__global__ __launch_bounds__(256) void midpoint_k(const float* __restrict__ A,
  const float* __restrict__ Bv, float* __restrict__ outf, int do_projx)
{
  __shared__ float sb[4];
  const int row = blockIdx.x, t = threadIdx.x;
  const size_t base = (size_t)row*E_;
  const float a0 = A[base+t], a1 = A[base+t+256];
  const float b0 = Bv[base+t], b1 = Bv[base+t+256];
  const float sa  = block_sum(a0*a0+a1*a1, sb);
  const float sbb = block_sum(b0*b0+b1*b1, sb);
  const float sab = block_sum(a0*b0+a1*b1, sb);
  const float l1 = 2.f/fmaxf(1.f-sa,  EPSF);
  const float l2 = 2.f/fmaxf(1.f-sbb, EPSF);
  const float idn = 1.f/fmaxf(l1+l2-2.f, EPSF);
  const float t0 = (a0*l1 + b0*l2)*idn;
  const float t1 = (a1*l1 + b1*l2)*idn;
  const float nt2 = (l1*l1*sa + 2.f*l1*l2*sab + l2*l2*sbb)*idn*idn;
  const float nt = sqrtf(nt2 + 1e-15f);
  const float s = tanhf(0.5f*artanh_c(nt));
  float sc = s/nt;
  if(do_projx && s > PROJ_M) sc *= PROJ_M/s;
  outf[base+t]     = t0*sc;
  outf[base+t+256] = t1*sc;
}

// ---------- bf16 MFMA GEMM: C = A[M,K] @ W[N,K]^T, 128x128 tile, BK=32 ----------
// mode: 0 raw->outf ; 1 +bias->outb ; 2 +bias+res->outf ; 3 relu(+bias)->outb ; 4 relu(+bias)+res->outf
__global__ __launch_bounds__(256) void gemm_bf16(
    const uint16_t* __restrict__ A, const uint16_t* __restrict__ Bw,
    int M, int N, int K, int mode,
    const float* __restrict__ bias, const float* __restrict__ res,
    float* __restrict__ outf, uint16_t* __restrict__ outb)
{
  __shared__ uint16_t As[128*32];
  __shared__ uint16_t Bs[128*32];
  const int tid = threadIdx.x;
  const int l = tid & 63;
  const int w = tid >> 6;
  const int wm = w >> 1, wn = w & 1;
  const int m0 = blockIdx.y * 128, n0 = blockIdx.x * 128;
  const int srow = tid >> 1;
  const int skc  = (tid & 1) * 16;
  const int lr = l & 15;
  const int lk = (l >> 4)*8;

  f32x4 acc[4][4];
  #pragma unroll
  for(int i=0;i<4;i++)
    #pragma unroll
    for(int j=0;j<4;j++) acc[i][j] = (f32x4){0.f,0.f,0.f,0.f};

  for(int k0=0;k0<K;k0+=32){
    __syncthreads();
    {
      const uint16_t* ga = A + (size_t)(m0+srow)*K + k0 + skc;
      uint4 a0 = *(const uint4*)ga;
      uint4 a1 = *(const uint4*)(ga+8);
      *(uint4*)&As[srow*32 + skc]     = a0;
      *(uint4*)&As[srow*32 + skc + 8] = a1;
      const uint16_t* gb = Bw + (size_t)(n0+srow)*K + k0 + skc;
      uint4 b0 = *(const uint4*)gb;
      uint4 b1 = *(const uint4*)(gb+8);
      *(uint4*)&Bs[srow*32 + skc]     = b0;
      *(uint4*)&Bs[srow*32 + skc + 8] = b1;
    }
    __syncthreads();
    bf16x8 av[4], bv[4];
    #pragma unroll
    for(int i=0;i<4;i++) av[i] = *(const bf16x8*)&As[(wm*64 + i*16 + lr)*32 + lk];
    #pragma unroll
    for(int j=0;j<4;j++) bv[j] = *(const bf16x8*)&Bs[(wn*64 + j*16 + lr)*32 + lk];
    #pragma unroll
    for(int i=0;i<4;i++)
      #pragma unroll
      for(int j=0;j<4;j++)
        acc[i][j] = __builtin_amdgcn_mfma_f32_16x16x32_bf16(av[i], bv[j], acc[i][j], 0,0,0);
  }
  const int orow = (l>>4)*4;
  #pragma unroll
  for(int i=0;i<4;i++){
    #pragma unroll
    for(int j=0;j<4;j++){
      const int gn = n0 + wn*64 + j*16 + lr;
      const float bval = (mode!=0) ? bias[gn] : 0.f;
      #pragma unroll
      for(int r=0;r<4;r++){
        const int gm = m0 + wm*64 + i*16 + orow + r;
        const float v = acc[i][j][r];
        const size_t off = (size_t)gm*N + gn;
        if(mode==0){ outf[off] = v; }
        else if(mode==1){ outb[off] = f2bf(v + bval); }
        else if(mode==2){ outf[off] = v + bval + res[off]; }
        else if(mode==3){ outb[off] = f2bf(fmaxf(v + bval, 0.f)); }
        else { outf[off] = fmaxf(v + bval, 0.f) + res[off]; }
      }
    }
  }
}

// ---------- flash attention, fp32 vector. HYP=0: euclid (-|q-k|/8); HYP=1: Poincare dist + gyromidpoint agg ----------
template<int HYP>
__global__ __launch_bounds__(256) void attn_k(
  const uint16_t* __restrict__ Qb, const uint16_t* __restrict__ Kb,
  const uint16_t* __restrict__ Vb, float* __restrict__ outf,
  uint16_t* __restrict__ outb)
{
  __shared__ float Qs[64][68];
  __shared__ float Ks[64][68];
  __shared__ float Vs[64][68];
  __shared__ float qqs[64], kks[64], lams[64];

  const int tid = threadIdx.x;
  const int l = tid & 63;
  const int w = tid >> 6;
  const int b = blockIdx.y >> 3;
  const int h = blockIdx.y & 7;
  const int i0 = blockIdx.x * 64;
  const int sr = tid >> 2;
  const int scol = (tid & 3) << 4;

  { // stage Q tile + qq
    const size_t g = ((size_t)(i0+sr)*B_ + b)*E_ + h*D_ + scol;
    uint4 u0 = *(const uint4*)(Qb + g);
    uint4 u1 = *(const uint4*)(Qb + g + 8);
    float f[16]; unpack8(u0,f); unpack8(u1,f+8);
    float ss = 0.f;
    #pragma unroll
    for(int i=0;i<16;i++){ ss += f[i]*f[i]; Qs[sr][scol+i] = f[i]; }
    ss += __shfl_xor(ss,1); ss += __shfl_xor(ss,2);
    if((tid&3)==0) qqs[sr] = ss;
  }

  const int il = w*16 + (l & 15);     // my query row in tile
  const int dbase = (l >> 4) << 4;    // my j-chunk (scores) / d-chunk (PV)
  float oacc[16];
  #pragma unroll
  for(int i=0;i<16;i++) oacc[i] = 0.f;
  float mrun = -1e30f, lrun = 0.f, dnrun = 0.f;

  for(int kt=0; kt<8; kt++){
    __syncthreads();
    { // stage K,V tile + kk (+lam, V*=lam for HYP)
      const size_t g = ((size_t)(kt*64+sr)*B_ + b)*E_ + h*D_ + scol;
      uint4 u0 = *(const uint4*)(Kb + g);
      uint4 u1 = *(const uint4*)(Kb + g + 8);
      float f[16]; unpack8(u0,f); unpack8(u1,f+8);
      float ss = 0.f;
      #pragma unroll
      for(int i=0;i<16;i++){ ss += f[i]*f[i]; Ks[sr][scol+i] = f[i]; }
      ss += __shfl_xor(ss,1); ss += __shfl_xor(ss,2);
      if((tid&3)==0) kks[sr] = ss;
      uint4 w0 = *(const uint4*)(Vb + g);
      uint4 w1 = *(const uint4*)(Vb + g + 8);
      float fv[16]; unpack8(w0,fv); unpack8(w1,fv+8);
      if(HYP){
        float sv = 0.f;
        #pragma unroll
        for(int i=0;i<16;i++) sv += fv[i]*fv[i];
        sv += __shfl_xor(sv,1); sv += __shfl_xor(sv,2);
        const float lam = 2.f/fmaxf(1.f - sv, EPSF);
        if((tid&3)==0) lams[sr] = lam;
        #pragma unroll
        for(int i=0;i<16;i++) fv[i] *= lam;
      }
      #pragma unroll
      for(int i=0;i<16;i++) Vs[sr][scol+i] = fv[i];
    }
    __syncthreads();

    const float qq = qqs[il];
    float acc[16];
    #pragma unroll
    for(int j=0;j<16;j++) acc[j] = 0.f;
    #pragma unroll
    for(int d4=0; d4<16; d4++){
      const float4 q4 = *(const float4*)&Qs[il][d4<<2];
      #pragma unroll
      for(int j=0;j<16;j++){
        const float4 k4 = *(const float4*)&Ks[dbase+j][d4<<2];
        acc[j] = fmaf(q4.x,k4.x, fmaf(q4.y,k4.y, fmaf(q4.z,k4.z, fmaf(q4.w,k4.w, acc[j]))));
      }
    }
    float mloc = -1e30f;
    #pragma unroll
    for(int j=0;j<16;j++){
      const float kk = kks[dbase+j];
      float s;
      if(HYP){
        const float qk = acc[j];
        const float diff2 = fmaxf(qq + kk - 2.f*qk, 0.f);
        const float den = fmaxf(1.f - 2.f*qk + qq*kk, EPSF);
        const float arg = sqrtf(diff2/den + 1e-15f);
        s = -0.25f * artanh_c(arg);           // -2*artanh(arg)/sqrt(64)
      } else {
        const float d2 = fmaxf(qq + kk - 2.f*acc[j], 0.f);
        s = -0.125f * sqrtf(d2 + 1e-12f);
      }
      acc[j] = s;
      mloc = fmaxf(mloc, s);
    }
    mloc = fmaxf(mloc, __shfl_xor(mloc,16));
    mloc = fmaxf(mloc, __shfl_xor(mloc,32));
    const float mnew = fmaxf(mrun, mloc);
    const float corr = expf(mrun - mnew);
    float ls = 0.f, dl = 0.f;
    #pragma unroll
    for(int j=0;j<16;j++){
      const float e = expf(acc[j] - mnew);
      acc[j] = e;
      ls += e;
      if(HYP) dl += e*(lams[dbase+j] - 1.f);
    }
    ls += __shfl_xor(ls,16); ls += __shfl_xor(ls,32);
    lrun = lrun*corr + ls;
    if(HYP){
      dl += __shfl_xor(dl,16); dl += __shfl_xor(dl,32);
      dnrun = dnrun*corr + dl;
    }
    mrun = mnew;
    #pragma unroll
    for(int d=0; d<16; d++) oacc[d] *= corr;
    // PV: fetch p[i][j] from owning lane via shfl, accumulate over this K-tile
    #pragma unroll
    for(int j=0;j<64;j++){
      const int src = (l & 15) | ((j >> 4) << 4);
      const float pj = __shfl(acc[j & 15], src);
      const float4 va  = *(const float4*)&Vs[j][dbase];
      const float4 vb2 = *(const float4*)&Vs[j][dbase+4];
      const float4 vc  = *(const float4*)&Vs[j][dbase+8];
      const float4 vd  = *(const float4*)&Vs[j][dbase+12];
      oacc[0]  = fmaf(pj, va.x,  oacc[0]);
      oacc[1]  = fmaf(pj, va.y,  oacc[1]);
      oacc[2]  = fmaf(pj, va.z,  oacc[2]);
      oacc[3]  = fmaf(pj, va.w,  oacc[3]);
      oacc[4]  = fmaf(pj, vb2.x, oacc[4]);
      oacc[5]  = fmaf(pj, vb2.y, oacc[5]);
      oacc[6]  = fmaf(pj, vb2.z, oacc[6]);
      oacc[7]  = fmaf(pj, vb2.w, oacc[7]);
      oacc[8]  = fmaf(pj, vc.x,  oacc[8]);
      oacc[9]  = fmaf(pj, vc.y,  oacc[9]);
      oacc[10] = fmaf(pj, vc.z,  oacc[10]);
      oacc[11] = fmaf(pj, vc.w,  oacc[11]);
      oacc[12] = fmaf(pj, vd.x,  oacc[12]);
      oacc[13] = fmaf(pj, vd.y,  oacc[13]);
      oacc[14] = fmaf(pj, vd.z,  oacc[14]);
      oacc[15] = fmaf(pj, vd.w,  oacc[15]);
    }
  }
  const float invl = 1.f/lrun;
  const size_t gb = ((size_t)(i0+il)*B_ + b)*E_ + h*D_ + dbase;
  if(HYP){
    const float dn = fmaxf(dnrun*invl, EPSF);
    const float scale = invl/dn;
    *(float4*)(outf+gb)    = make_float4(oacc[0]*scale,  oacc[1]*scale,  oacc[2]*scale,  oacc[3]*scale);
    *(float4*)(outf+gb+4)  = make_float4(oacc[4]*scale,  oacc[5]*scale,  oacc[6]*scale,  oacc[7]*scale);
    *(float4*)(outf+gb+8)  = make_float4(oacc[8]*scale,  oacc[9]*scale,  oacc[10]*scale, oacc[11]*scale);
    *(float4*)(outf+gb+12) = make_float4(oacc[12]*scale, oacc[13]*scale, oacc[14]*scale, oacc[15]*scale);
  } else {
    float f[16];
    #pragma unroll
    for(int d=0; d<16; d++) f[d] = oacc[d]*invl;
    *(uint4*)(outb + gb)     = pack8(f);
    *(uint4*)(outb + gb + 8) = pack8(f+8);
  }
}

// =====================================================================
extern "C" void kernel_launch(void* const* d_in, const int* in_sizes, int n_in,
                              void* d_out, int out_size, void* d_ws, size_t ws_size,
                              hipStream_t stream)
{
  (void)in_sizes; (void)n_in; (void)out_size; (void)ws_size;
  const float* x    = (const float*)d_in[0];
  const float* ln1g = (const float*)d_in[1];
  const float* ln1b = (const float*)d_in[2];
  const float* ln2g = (const float*)d_in[3];
  const float* ln2b = (const float*)d_in[4];
  const float* Wq = (const float*)d_in[5];
  const float* bq = (const float*)d_in[6];
  const float* Wk = (const float*)d_in[7];
  const float* bk = (const float*)d_in[8];
  const float* Wv = (const float*)d_in[9];
  const float* bv = (const float*)d_in[10];
  const float* Wo = (const float*)d_in[11];
  const float* bo = (const float*)d_in[12];
  const float* W1 = (const float*)d_in[13];
  const float* b1 = (const float*)d_in[14];
  const float* W2 = (const float*)d_in[15];
  const float* b2 = (const float*)d_in[16];
  float* out = (float*)d_out;

  char* ws = (char*)d_ws;
  float*    MX  = (float*)   (ws);                        // 16MB fp32 GEMM scratch
  float*    X2  = (float*)   (ws + ((size_t)16<<20));     // 16MB
  float*    OP  = (float*)   (ws + ((size_t)32<<20));     // 16MB
  uint16_t* HB  = (uint16_t*)(ws + ((size_t)48<<20));     // 8MB bf16
  uint16_t* QB  = (uint16_t*)(ws + ((size_t)56<<20));
  uint16_t* KB  = (uint16_t*)(ws + ((size_t)64<<20));
  uint16_t* VB  = (uint16_t*)(ws + ((size_t)72<<20));
  uint16_t* OB  = (uint16_t*)(ws + ((size_t)80<<20));
  uint16_t* F1B = (uint16_t*)(ws + ((size_t)88<<20));     // 32MB bf16
  uint16_t* WB  = (uint16_t*)(ws + ((size_t)120<<20));    // 6MB bf16 weights
  float*    YV  = (float*)   (ws + ((size_t)126<<20) + (512<<10));
  float*    NH  = (float*)   (ws + ((size_t)127<<20));
  float*    NO  = NH + R_;
  float*    N3  = NO + R_;
  float*    N4  = N3 + R_;

  uint16_t* WBq = WB;
  uint16_t* WBk = WB + 262144;
  uint16_t* WBv = WB + 524288;
  uint16_t* WBo = WB + 786432;
  uint16_t* WB1 = WB + 1048576;
  uint16_t* WB2 = WB + 2097152;
  float* yq = YV;
  float* yk = YV + 513;
  float* yvv = YV + 1026;
  float* yo = YV + 1539;
  float* y1 = YV + 2052;
  float* y2 = YV + 4101;

  // ================= Expert 0: Euclidean =================
  cvt_k<<<1024,256,0,stream>>>(Wq, WBq, E_*E_);
  cvt_k<<<1024,256,0,stream>>>(Wk, WBk, E_*E_);
  cvt_k<<<1024,256,0,stream>>>(Wv, WBv, E_*E_);
  cvt_k<<<1024,256,0,stream>>>(Wo, WBo, E_*E_);
  cvt_k<<<4096,256,0,stream>>>(W1, WB1, FFN_*E_);
  cvt_k<<<4096,256,0,stream>>>(W2, WB2, E_*FFN_);
  ln_k<<<R_,256,0,stream>>>(x, ln1g, ln1b, HB);
  gemm_bf16<<<dim3(4,64),256,0,stream>>>(HB, WBq, R_,512,512, 1, bq, nullptr, nullptr, QB);
  gemm_bf16<<<dim3(4,64),256,0,stream>>>(HB, WBk, R_,512,512, 1, bk, nullptr, nullptr, KB);
  gemm_bf16<<<dim3(4,64),256,0,stream>>>(HB, WBv, R_,512,512, 1, bv, nullptr, nullptr, VB);
  attn_k<0><<<dim3(8,128),256,0,stream>>>(QB, KB, VB, nullptr, OB);
  gemm_bf16<<<dim3(4,64),256,0,stream>>>(OB, WBo, R_,512,512, 2, bo, x, X2, nullptr);
  ln_k<<<R_,256,0,stream>>>(X2, ln2g, ln2b, HB);
  gemm_bf16<<<dim3(16,64),256,0,stream>>>(HB, WB1, R_,2048,512, 3, b1, nullptr, nullptr, F1B);
  gemm_bf16<<<dim3(4,64),256,0,stream>>>(F1B, WB2, R_,512,2048, 4, b2, X2, out, nullptr);

  // ================= Expert 1: Hyperbolic =================
  const float* x1 = x + (size_t)R_*E_;
  cvt_k<<<1024,256,0,stream>>>(Wq + (size_t)E_*E_, WBq, E_*E_);
  cvt_k<<<1024,256,0,stream>>>(Wk + (size_t)E_*E_, WBk, E_*E_);
  cvt_k<<<1024,256,0,stream>>>(Wv + (size_t)E_*E_, WBv, E_*E_);
  cvt_k<<<1024,256,0,stream>>>(Wo + (size_t)E_*E_, WBo, E_*E_);
  cvt_k<<<4096,256,0,stream>>>(W1 + (size_t)FFN_*E_, WB1, FFN_*E_);
  cvt_k<<<4096,256,0,stream>>>(W2 + (size_t)E_*FFN_, WB2, E_*FFN_);
  expmap0_vec<<<1,256,0,stream>>>(bq + E_,   yq, E_);
  expmap0_vec<<<1,256,0,stream>>>(bk + E_,   yk, E_);
  expmap0_vec<<<1,256,0,stream>>>(bv + E_,   yvv, E_);
  expmap0_vec<<<1,256,0,stream>>>(bo + E_,   yo, E_);
  expmap0_vec<<<1,256,0,stream>>>(b1 + FFN_, y1, FFN_);
  expmap0_vec<<<1,256,0,stream>>>(b2 + E_,   y2, E_);
  hyp_lnexp<<<R_,256,0,stream>>>(x1, ln1g+E_, ln1b+E_, HB, NH, 0);
  gemm_bf16<<<dim3(4,64),256,0,stream>>>(HB, WBq, R_,512,512, 0, nullptr,nullptr, MX, nullptr);
  man_epi<2><<<R_,256,0,stream>>>(MX, NH, yq, QB, nullptr, nullptr, 2);
  gemm_bf16<<<dim3(4,64),256,0,stream>>>(HB, WBk, R_,512,512, 0, nullptr,nullptr, MX, nullptr);
  man_epi<2><<<R_,256,0,stream>>>(MX, NH, yk, KB, nullptr, nullptr, 2);
  gemm_bf16<<<dim3(4,64),256,0,stream>>>(HB, WBv, R_,512,512, 0, nullptr,nullptr, MX, nullptr);
  man_epi<2><<<R_,256,0,stream>>>(MX, NH, yvv, VB, nullptr, nullptr, 2);
  attn_k<1><<<dim3(8,128),256,0,stream>>>(QB, KB, VB, OP, nullptr);
  o_finish<<<R_,256,0,stream>>>(OP, OB, NO);
  gemm_bf16<<<dim3(4,64),256,0,stream>>>(OB, WBo, R_,512,512, 0, nullptr,nullptr, MX, nullptr);
  man_epi<2><<<R_,256,0,stream>>>(MX, NO, yo, nullptr, OP, nullptr, 0);
  midpoint_k<<<R_,256,0,stream>>>(OP, x1, X2, 0);
  hyp_lnexp<<<R_,256,0,stream>>>(X2, ln2g+E_, ln2b+E_, HB, N3, 1);
  for(int c=0;c<4;c++){
    gemm_bf16<<<dim3(16,16),256,0,stream>>>(HB + (size_t)c*2048*E_, WB1, 2048, 2048, 512, 0,
                                            nullptr, nullptr, MX, nullptr);
    man_epi<8><<<2048,256,0,stream>>>(MX, N3 + c*2048, y1, F1B + (size_t)c*2048*FFN_,
                                      nullptr, N4 + c*2048, 1);
  }
  gemm_bf16<<<dim3(4,64),256,0,stream>>>(F1B, WB2, R_,512,2048, 0, nullptr,nullptr, MX, nullptr);
  man_epi<2><<<R_,256,0,stream>>>(MX, N4, y2, nullptr, OP, nullptr, 1);
  midpoint_k<<<R_,256,0,stream>>>(OP, X2, out + (size_t)R_*E_, 1);
}

// Round 2
// 881.783 us; speedup vs baseline: 4.0467x; 4.0467x over previous
//
#include <hip/hip_runtime.h>
#include <cstdint>
#include <cstddef>

#define S_ 512
#define B_ 16
#define H_ 8
#define D_ 64
#define E_ 512
#define FFN_ 2048
#define R_ (S_*B_)          // 8192 rows (s*B+b)
#define EPSF 1e-6f
#define PROJ_M 0.99999f     // 1 - 1e-5

typedef __attribute__((ext_vector_type(8))) short bf16x8;
typedef __attribute__((ext_vector_type(4))) float f32x4;

// ---------- small helpers ----------
__device__ __forceinline__ float bf2f(uint32_t u){
  union{uint32_t i; float f;} c; c.i = u<<16; return c.f;
}
__device__ __forceinline__ uint16_t f2bf(float f){
  union{float f; uint32_t i;} c; c.f = f;
  return (uint16_t)((c.i + 0x7FFFu + ((c.i>>16)&1u))>>16);
}
__device__ __forceinline__ void unpack8(uint4 u, float* f){
  f[0]=bf2f(u.x&0xFFFFu); f[1]=bf2f(u.x>>16);
  f[2]=bf2f(u.y&0xFFFFu); f[3]=bf2f(u.y>>16);
  f[4]=bf2f(u.z&0xFFFFu); f[5]=bf2f(u.z>>16);
  f[6]=bf2f(u.w&0xFFFFu); f[7]=bf2f(u.w>>16);
}
__device__ __forceinline__ uint4 pack8(const float* f){
  uint4 u;
  u.x = (uint32_t)f2bf(f[0]) | ((uint32_t)f2bf(f[1])<<16);
  u.y = (uint32_t)f2bf(f[2]) | ((uint32_t)f2bf(f[3])<<16);
  u.z = (uint32_t)f2bf(f[4]) | ((uint32_t)f2bf(f[5])<<16);
  u.w = (uint32_t)f2bf(f[6]) | ((uint32_t)f2bf(f[7])<<16);
  return u;
}
// artanh with the reference's clip at 1-1e-7
__device__ __forceinline__ float artanh_c(float x){
  return (x >= 0.99999994f) ? 8.4056215f : atanhf(x);
}
// fast artanh for the attention inner loop (same clip)
__device__ __forceinline__ float artanh_fast(float x){
  return (x >= 0.99999994f) ? 8.4056215f : 0.5f*__logf((1.f+x)/(1.f-x));
}
__device__ __forceinline__ float wave_sum(float x){
  #pragma unroll
  for(int o=32;o>=1;o>>=1) x += __shfl_xor(x,o);
  return x;
}
__device__ __forceinline__ float block_sum(float x, float* sb){
  x = wave_sum(x);
  const int w = threadIdx.x >> 6;
  __syncthreads();
  if((threadIdx.x & 63)==0) sb[w] = x;
  __syncthreads();
  return sb[0]+sb[1]+sb[2]+sb[3];
}
__device__ __forceinline__ int swz_row(int row){ return ((row ^ (row>>3)) & 7) << 4; }

// ---------- fp32 -> bf16 weight conversion ----------
__global__ void cvt_k(const float* __restrict__ s, uint16_t* __restrict__ d, int n){
  int i = blockIdx.x*256 + threadIdx.x;
  if(i < n) d[i] = f2bf(s[i]);
}

// ---------- plain layernorm (euclid), row=512, out bf16 ----------
__global__ __launch_bounds__(256) void ln_k(const float* __restrict__ x,
  const float* __restrict__ g, const float* __restrict__ b, uint16_t* __restrict__ out)
{
  __shared__ float sb[4];
  const int row = blockIdx.x, t = threadIdx.x;
  const size_t base = (size_t)row*E_;
  float v0 = x[base+t], v1 = x[base+t+256];
  const float mu  = block_sum(v0+v1, sb) * (1.f/E_);
  const float d0 = v0-mu, d1 = v1-mu;
  const float var = block_sum(d0*d0+d1*d1, sb) * (1.f/E_);
  const float rs = 1.f/sqrtf(var + 1e-5f);
  out[base+t]     = f2bf(d0*rs*g[t] + b[t]);
  out[base+t+256] = f2bf(d1*rs*g[t+256] + b[t+256]);
}

// ---------- hyp: expmap0(LN(logmap0(x))) [+projx], out bf16 + analytic row norm ----------
__global__ __launch_bounds__(256) void hyp_lnexp(const float* __restrict__ x,
  const float* __restrict__ g, const float* __restrict__ b,
  uint16_t* __restrict__ out, float* __restrict__ nout, int do_projx)
{
  __shared__ float sb[4];
  const int row = blockIdx.x, t = threadIdx.x;
  const size_t base = (size_t)row*E_;
  float v0 = x[base+t], v1 = x[base+t+256];
  const float s2 = block_sum(v0*v0+v1*v1, sb);
  const float n  = sqrtf(s2 + 1e-15f);
  const float ls = artanh_c(n)/n;          // logmap0 scale
  v0 *= ls; v1 *= ls;
  const float mu  = block_sum(v0+v1, sb) * (1.f/E_);
  const float d0 = v0-mu, d1 = v1-mu;
  const float var = block_sum(d0*d0+d1*d1, sb) * (1.f/E_);
  const float rs = 1.f/sqrtf(var + 1e-5f);
  float t0 = d0*rs*g[t] + b[t];
  float t1 = d1*rs*g[t+256] + b[t+256];
  const float n2s = block_sum(t0*t0+t1*t1, sb);
  const float n2 = sqrtf(n2s + 1e-15f);
  const float nh = tanhf(n2);               // expmap0: analytic output norm
  const float scl = nh/n2;
  t0 *= scl; t1 *= scl;
  float nrm = nh;
  if(do_projx && nrm > PROJ_M){ const float s = PROJ_M/nrm; t0*=s; t1*=s; nrm = PROJ_M; }
  out[base+t] = f2bf(t0); out[base+t+256] = f2bf(t1);
  if(t==0) nout[row] = nrm;
}

// ---------- y = expmap0(bias); y[C] = |y|^2 (analytic) ----------
__global__ __launch_bounds__(256) void expmap0_vec(const float* __restrict__ b,
  float* __restrict__ y, int C)
{
  __shared__ float sb[4];
  const int t = threadIdx.x;
  const int npc = C >> 8;
  float v[8];
  float s2 = 0.f;
  for(int i=0;i<npc;i++){ v[i] = b[t+256*i]; s2 += v[i]*v[i]; }
  s2 = block_sum(s2, sb);
  const float n = sqrtf(s2 + 1e-15f);
  const float sc = tanhf(n)/n;
  for(int i=0;i<npc;i++) y[t+256*i] = v[i]*sc;
  if(t==0) y[C] = tanhf(n)*tanhf(n);
}

// ---------- man_linear epilogue ----------
template<int NPC>
__global__ __launch_bounds__(256) void man_epi(
  const float* __restrict__ mx, const float* __restrict__ nxbuf,
  const float* __restrict__ y, uint16_t* __restrict__ outb,
  float* __restrict__ outf, float* __restrict__ nout, int flags)
{
  constexpr int C = NPC*256;
  __shared__ float sb[4];
  const int row = blockIdx.x;
  const int t = threadIdx.x;
  float v[NPC], yv[NPC];
  float s2 = 0.f;
  #pragma unroll
  for(int i=0;i<NPC;i++){
    v[i]  = mx[(size_t)row*C + t + 256*i];
    yv[i] = y[t + 256*i];
    s2 += v[i]*v[i];
  }
  s2 = block_sum(s2, sb);
  const float nmx = sqrtf(s2 + 1e-15f);
  const float nx  = nxbuf[row];
  const float sc  = tanhf(nmx/nx * artanh_c(nx));
  const bool ok   = (nmx > 1e-7f);
  const float fmul = ok ? (sc/nmx) : 0.f;
  const float x2   = ok ? sc*sc : 0.f;
  float xy = 0.f;
  #pragma unroll
  for(int i=0;i<NPC;i++){ v[i] *= fmul; xy += v[i]*yv[i]; }
  xy = block_sum(xy, sb);
  const float y2 = y[C];
  const float aa = 1.f + 2.f*xy + y2;
  const float bb = 1.f - x2;
  const float den = fmaxf(1.f + 2.f*xy + x2*y2, EPSF);
  const float iden = 1.f/den;
  const float num2 = aa*aa*x2 + 2.f*aa*bb*xy + bb*bb*y2;
  const float nz = sqrtf(num2*iden*iden + 1e-15f);
  const float ps = (nz > PROJ_M) ? (PROJ_M/nz) : 1.f;
  float nfin = (nz > PROJ_M) ? PROJ_M : nz;
  #pragma unroll
  for(int i=0;i<NPC;i++) v[i] = (aa*v[i] + bb*yv[i]) * iden * ps;
  if(flags & 2){
    const float h0 = wave_sum(v[0]*v[0]);
    const float h1 = wave_sum(v[1]*v[1]);
    const float n0 = sqrtf(h0 + 1e-15f);
    const float n1 = sqrtf(h1 + 1e-15f);
    if(n0 > PROJ_M) v[0] *= PROJ_M/n0;
    if(n1 > PROJ_M) v[1] *= PROJ_M/n1;
  }
  if(flags & 1){
    float rs = 0.f;
    #pragma unroll
    for(int i=0;i<NPC;i++){ v[i] = fmaxf(v[i],0.f); rs += v[i]*v[i]; }
    rs = block_sum(rs, sb);
    nfin = sqrtf(rs + 1e-15f);
  }
  #pragma unroll
  for(int i=0;i<NPC;i++){
    if(outb) outb[(size_t)row*C + t + 256*i] = f2bf(v[i]);
    if(outf) outf[(size_t)row*C + t + 256*i] = v[i];
  }
  if(nout && t==0) nout[row] = nfin;
}

// ---------- hyp attention-output finish ----------
__global__ __launch_bounds__(256) void o_finish(const float* __restrict__ op,
  uint16_t* __restrict__ outb, float* __restrict__ nout)
{
  __shared__ float segn2[8];
  const int row = blockIdx.x, t = threadIdx.x, w = t>>6;
  const size_t base = (size_t)row*E_;
  float v0 = op[base+t], v1 = op[base+t+256];
  const float h0 = wave_sum(v0*v0);
  const float h1 = wave_sum(v1*v1);
  const float ns0 = sqrtf(h0+1e-15f), ns1 = sqrtf(h1+1e-15f);
  const float tt0 = tanhf(0.5f*artanh_c(ns0));
  const float tt1 = tanhf(0.5f*artanh_c(ns1));
  v0 *= tt0/ns0; v1 *= tt1/ns1;
  float sn0 = tt0, sn1 = tt1;
  if(sn0 > PROJ_M){ v0 *= PROJ_M/sn0; sn0 = PROJ_M; }
  if(sn1 > PROJ_M){ v1 *= PROJ_M/sn1; sn1 = PROJ_M; }
  if((t&63)==0){ segn2[w] = sn0*sn0; segn2[w+4] = sn1*sn1; }
  __syncthreads();
  const float tot = segn2[0]+segn2[1]+segn2[2]+segn2[3]+segn2[4]+segn2[5]+segn2[6]+segn2[7];
  const float n = sqrtf(tot + 1e-15f);
  float nf = n;
  if(n > PROJ_M){ const float s = PROJ_M/n; v0*=s; v1*=s; nf = PROJ_M; }
  outb[base+t] = f2bf(v0);
  outb[base+t+256] = f2bf(v1);
  if(t==0) nout[row] = nf;
}

// ---------- Mobius gyromidpoint residual ----------
__global__ __launch_bounds__(256) void midpoint_k(const float* __restrict__ A,
  const float* __restrict__ Bv, float* __restrict__ outf, int do_projx)
{
  __shared__ float sb[4];
  const int row = blockIdx.x, t = threadIdx.x;
  const size_t base = (size_t)row*E_;
  const float a0 = A[base+t], a1 = A[base+t+256];
  const float b0 = Bv[base+t], b1 = Bv[base+t+256];
  const float sa  = block_sum(a0*a0+a1*a1, sb);
  const float sbb = block_sum(b0*b0+b1*b1, sb);
  const float sab = block_sum(a0*b0+a1*b1, sb);
  const float l1 = 2.f/fmaxf(1.f-sa,  EPSF);
  const float l2 = 2.f/fmaxf(1.f-sbb, EPSF);
  const float idn = 1.f/fmaxf(l1+l2-2.f, EPSF);
  const float t0 = (a0*l1 + b0*l2)*idn;
  const float t1 = (a1*l1 + b1*l2)*idn;
  const float nt2 = (l1*l1*sa + 2.f*l1*l2*sab + l2*l2*sbb)*idn*idn;
  const float nt = sqrtf(nt2 + 1e-15f);
  const float s = tanhf(0.5f*artanh_c(nt));
  float sc = s/nt;
  if(do_projx && s > PROJ_M) sc *= PROJ_M/s;
  outf[base+t]     = t0*sc;
  outf[base+t+256] = t1*sc;
}

// ---------- bf16 MFMA GEMM: C = A[M,K] @ W[N,K]^T, 128x128 tile, BK=32 ----------
__global__ __launch_bounds__(256) void gemm_bf16(
    const uint16_t* __restrict__ A, const uint16_t* __restrict__ Bw,
    int M, int N, int K, int mode,
    const float* __restrict__ bias, const float* __restrict__ res,
    float* __restrict__ outf, uint16_t* __restrict__ outb)
{
  __shared__ uint16_t As[128*32];
  __shared__ uint16_t Bs[128*32];
  const int tid = threadIdx.x;
  const int l = tid & 63;
  const int w = tid >> 6;
  const int wm = w >> 1, wn = w & 1;
  const int m0 = blockIdx.y * 128, n0 = blockIdx.x * 128;
  const int srow = tid >> 1;
  const int skc  = (tid & 1) * 16;
  const int lr = l & 15;
  const int lk = (l >> 4)*8;

  f32x4 acc[4][4];
  #pragma unroll
  for(int i=0;i<4;i++)
    #pragma unroll
    for(int j=0;j<4;j++) acc[i][j] = (f32x4){0.f,0.f,0.f,0.f};

  for(int k0=0;k0<K;k0+=32){
    __syncthreads();
    {
      const uint16_t* ga = A + (size_t)(m0+srow)*K + k0 + skc;
      uint4 a0 = *(const uint4*)ga;
      uint4 a1 = *(const uint4*)(ga+8);
      *(uint4*)&As[srow*32 + skc]     = a0;
      *(uint4*)&As[srow*32 + skc + 8] = a1;
      const uint16_t* gb = Bw + (size_t)(n0+srow)*K + k0 + skc;
      uint4 b0 = *(const uint4*)gb;
      uint4 b1 = *(const uint4*)(gb+8);
      *(uint4*)&Bs[srow*32 + skc]     = b0;
      *(uint4*)&Bs[srow*32 + skc + 8] = b1;
    }
    __syncthreads();
    bf16x8 av[4], bv[4];
    #pragma unroll
    for(int i=0;i<4;i++) av[i] = *(const bf16x8*)&As[(wm*64 + i*16 + lr)*32 + lk];
    #pragma unroll
    for(int j=0;j<4;j++) bv[j] = *(const bf16x8*)&Bs[(wn*64 + j*16 + lr)*32 + lk];
    #pragma unroll
    for(int i=0;i<4;i++)
      #pragma unroll
      for(int j=0;j<4;j++)
        acc[i][j] = __builtin_amdgcn_mfma_f32_16x16x32_bf16(av[i], bv[j], acc[i][j], 0,0,0);
  }
  const int orow = (l>>4)*4;
  #pragma unroll
  for(int i=0;i<4;i++){
    #pragma unroll
    for(int j=0;j<4;j++){
      const int gn = n0 + wn*64 + j*16 + lr;
      const float bval = (mode!=0) ? bias[gn] : 0.f;
      #pragma unroll
      for(int r=0;r<4;r++){
        const int gm = m0 + wm*64 + i*16 + orow + r;
        const float v = acc[i][j][r];
        const size_t off = (size_t)gm*N + gn;
        if(mode==0){ outf[off] = v; }
        else if(mode==1){ outb[off] = f2bf(v + bval); }
        else if(mode==2){ outf[off] = v + bval + res[off]; }
        else if(mode==3){ outb[off] = f2bf(fmaxf(v + bval, 0.f)); }
        else { outf[off] = fmaxf(v + bval, 0.f) + res[off]; }
      }
    }
  }
}

// ---------- MFMA flash attention (swapped S^T = K*Q^T, O^T = V^T*P^T) ----------
// HYP=0: euclid (-|q-k|/8) -> bf16 out; HYP=1: Poincare dist + gyromidpoint -> f32 out
template<int HYP>
__global__ __launch_bounds__(256) void attn_mfma(
  const uint16_t* __restrict__ Qb, const uint16_t* __restrict__ Kb,
  const uint16_t* __restrict__ Vb, float* __restrict__ outf,
  uint16_t* __restrict__ outb)
{
  __shared__ __align__(16) char smem[33536];
  char* QsB = smem;                 // [64 q][64 d] bf16, row-swizzled (8 KB)
  char* KsB = smem + 8192;          // [64 k][64 d] bf16 (8 KB)
  char* VtB = smem + 16384;         // [64 d][64 k] bf16 transposed (8 KB)
  char* PlB = smem + 24576;         // 4 waves x [16 q][64 k] bf16 (8 KB)
  float* qqs  = (float*)(smem + 32768);
  float* kks  = qqs + 64;
  float* lams = qqs + 128;
  char* OTB = smem;                 // overlay (post-loop): 4 waves x [16 q][64 d] f32 (16 KB)

  const int tid = threadIdx.x;
  const int l  = tid & 63;
  const int w  = tid >> 6;
  const int lr = l & 15;
  const int g  = l >> 4;
  const int b  = blockIdx.y >> 3;
  const int h  = blockIdx.y & 7;
  const int i0 = blockIdx.x * 64;
  const int sr   = tid >> 2;            // staging row 0..63
  const int scol = (tid & 3) << 4;      // staging col {0,16,32,48}
  const size_t gstride = (size_t)B_ * E_;
  const size_t gbase = (size_t)b*E_ + h*D_;

  // ---- stage Q tile (bf16, swizzled) + qq ----
  {
    const uint16_t* gq = Qb + (size_t)(i0+sr)*gstride + gbase + scol;
    uint4 u0 = *(const uint4*)gq;
    uint4 u1 = *(const uint4*)(gq+8);
    float f[16]; unpack8(u0,f); unpack8(u1,f+8);
    float ss = 0.f;
    #pragma unroll
    for(int i=0;i<16;i++) ss += f[i]*f[i];
    ss += __shfl_xor(ss,1); ss += __shfl_xor(ss,2);
    if((tid&3)==0) qqs[sr] = ss;
    const int swz = swz_row(sr);
    *(uint4*)(QsB + sr*128 + ((scol*2)    ^ swz)) = u0;
    *(uint4*)(QsB + sr*128 + ((scol*2+16) ^ swz)) = u1;
  }
  __syncthreads();

  // hoist Q B-fragments (loop-invariant)
  const int qrow = w*16 + lr;
  const float qq = qqs[qrow];
  const int swq = swz_row(qrow);
  const bf16x8 qb0 = *(const bf16x8*)(QsB + qrow*128 + ((g*16)      ^ swq));
  const bf16x8 qb1 = *(const bf16x8*)(QsB + qrow*128 + ((64 + g*16) ^ swq));
  const int swl = swz_row(lr);
  char* PmyB = PlB + w*2048;

  f32x4 oa[4];
  #pragma unroll
  for(int m=0;m<4;m++) oa[m] = (f32x4){0.f,0.f,0.f,0.f};
  float mrun = -3.0e38f, lrun = 0.f, dnrun = 0.f;

  for(int kt=0; kt<8; kt++){
    __syncthreads();
    // ---- stage K (bf16, swizzled) + kk ; V transposed (bf16, x lam for HYP) + lam ----
    {
      const size_t grow = (size_t)(kt*64+sr)*gstride + gbase + scol;
      uint4 u0 = *(const uint4*)(Kb + grow);
      uint4 u1 = *(const uint4*)(Kb + grow + 8);
      float f[16]; unpack8(u0,f); unpack8(u1,f+8);
      float ss = 0.f;
      #pragma unroll
      for(int i=0;i<16;i++) ss += f[i]*f[i];
      ss += __shfl_xor(ss,1); ss += __shfl_xor(ss,2);
      if((tid&3)==0) kks[sr] = ss;
      const int swz = swz_row(sr);
      *(uint4*)(KsB + sr*128 + ((scol*2)    ^ swz)) = u0;
      *(uint4*)(KsB + sr*128 + ((scol*2+16) ^ swz)) = u1;

      uint4 w0 = *(const uint4*)(Vb + grow);
      uint4 w1 = *(const uint4*)(Vb + grow + 8);
      uint16_t us[16];
      if(HYP){
        float fv[16]; unpack8(w0,fv); unpack8(w1,fv+8);
        float sv = 0.f;
        #pragma unroll
        for(int i=0;i<16;i++) sv += fv[i]*fv[i];
        sv += __shfl_xor(sv,1); sv += __shfl_xor(sv,2);
        const float lam = 2.f/fmaxf(1.f - sv, EPSF);
        if((tid&3)==0) lams[sr] = lam;
        #pragma unroll
        for(int i=0;i<16;i++) us[i] = f2bf(fv[i]*lam);
      } else {
        *(uint4*)&us[0] = w0; *(uint4*)&us[8] = w1;
      }
      #pragma unroll
      for(int i=0;i<16;i++){
        const int d = scol + i;
        *(uint16_t*)(VtB + d*128 + ((sr*2) ^ swz_row(d))) = us[i];
      }
    }
    __syncthreads();

    // ---- S^T = K * Q^T : lane holds 16 scores, all for query qrow ----
    f32x4 st[4];
    #pragma unroll
    for(int t=0;t<4;t++){
      const int key = t*16 + lr;
      const int swk = swz_row(key);
      const bf16x8 a0 = *(const bf16x8*)(KsB + key*128 + ((g*16)      ^ swk));
      const bf16x8 a1 = *(const bf16x8*)(KsB + key*128 + ((64 + g*16) ^ swk));
      f32x4 c = (f32x4){0.f,0.f,0.f,0.f};
      c = __builtin_amdgcn_mfma_f32_16x16x32_bf16(a0, qb0, c, 0,0,0);
      c = __builtin_amdgcn_mfma_f32_16x16x32_bf16(a1, qb1, c, 0,0,0);
      st[t] = c;
    }

    // ---- score transform (lane-local q) ----
    float ps[4][4];
    float mloc = -3.0e38f;
    #pragma unroll
    for(int t=0;t<4;t++){
      const f32x4 kkv = *(const f32x4*)(kks + t*16 + g*4);
      #pragma unroll
      for(int r=0;r<4;r++){
        const float qk = st[t][r];
        const float kk = kkv[r];
        float s;
        if(HYP){
          const float diff2 = fmaxf(qq + kk - 2.f*qk, 0.f);
          const float den = fmaxf(1.f - 2.f*qk + qq*kk, EPSF);
          const float arg = sqrtf(diff2/den + 1e-15f);
          s = -0.25f * artanh_fast(arg);
        } else {
          s = -0.125f * sqrtf(fmaxf(qq + kk - 2.f*qk, 0.f) + 1e-12f);
        }
        ps[t][r] = s;
        mloc = fmaxf(mloc, s);
      }
    }
    mloc = fmaxf(mloc, __shfl_xor(mloc,16));
    mloc = fmaxf(mloc, __shfl_xor(mloc,32));
    const float mnew = fmaxf(mrun, mloc);
    const float corr = __expf(mrun - mnew);
    mrun = mnew;

    float ls = 0.f, dl = 0.f;
    #pragma unroll
    for(int t=0;t<4;t++){
      f32x4 lamv;
      if(HYP) lamv = *(const f32x4*)(lams + t*16 + g*4);
      uint32_t lo, hi;
      float e0 = __expf(ps[t][0]-mnew), e1 = __expf(ps[t][1]-mnew);
      float e2 = __expf(ps[t][2]-mnew), e3 = __expf(ps[t][3]-mnew);
      ls += (e0+e1)+(e2+e3);
      if(HYP) dl += e0*(lamv[0]-1.f) + e1*(lamv[1]-1.f) + e2*(lamv[2]-1.f) + e3*(lamv[3]-1.f);
      lo = (uint32_t)f2bf(e0) | ((uint32_t)f2bf(e1)<<16);
      hi = (uint32_t)f2bf(e2) | ((uint32_t)f2bf(e3)<<16);
      *(uint2*)(PmyB + lr*128 + ((t*32 + g*8) ^ swl)) = make_uint2(lo, hi);
    }
    ls += __shfl_xor(ls,16); ls += __shfl_xor(ls,32);
    lrun = lrun*corr + ls;
    if(HYP){
      dl += __shfl_xor(dl,16); dl += __shfl_xor(dl,32);
      dnrun = dnrun*corr + dl;
    }
    #pragma unroll
    for(int m=0;m<4;m++){
      oa[m][0]*=corr; oa[m][1]*=corr; oa[m][2]*=corr; oa[m][3]*=corr;
    }

    // ---- O^T += V^T * P^T ----
    #pragma unroll
    for(int stp=0; stp<2; stp++){
      const bf16x8 pb = *(const bf16x8*)(PmyB + lr*128 + ((g*16 + stp*64) ^ swl));
      #pragma unroll
      for(int m=0;m<4;m++){
        const int d = m*16 + lr;
        const bf16x8 va = *(const bf16x8*)(VtB + d*128 + ((g*16 + stp*64) ^ swz_row(d)));
        oa[m] = __builtin_amdgcn_mfma_f32_16x16x32_bf16(va, pb, oa[m], 0,0,0);
      }
    }
  }

  // ---- epilogue: scale (lane-local q), restage via LDS, coalesced store ----
  __syncthreads();
  float scale;
  {
    const float invl = 1.f/lrun;
    if(HYP){
      const float dn = fmaxf(dnrun*invl, EPSF);
      scale = invl/dn;
    } else scale = invl;
  }
  #pragma unroll
  for(int m=0;m<4;m++){
    #pragma unroll
    for(int r=0;r<4;r++){
      const int d = m*16 + g*4 + r;
      *(float*)(OTB + w*4096 + lr*256 + ((d*4) ^ (lr<<4))) = oa[m][r]*scale;
    }
  }
  __syncthreads();
  {
    const int row = tid>>2, cw = tid&3;
    const int wsrc = row>>4, ql = row&15;
    float vals[16];
    #pragma unroll
    for(int i=0;i<4;i++){
      *(f32x4*)&vals[i*4] = *(const f32x4*)(OTB + wsrc*4096 + ql*256 + (((cw*64 + i*16) ^ (ql<<4))));
    }
    const size_t go = (size_t)(i0+row)*gstride + gbase + cw*16;
    if(HYP){
      #pragma unroll
      for(int i=0;i<4;i++) *(f32x4*)(outf + go + i*4) = *(f32x4*)&vals[i*4];
    } else {
      *(uint4*)(outb + go)     = pack8(vals);
      *(uint4*)(outb + go + 8) = pack8(vals+8);
    }
  }
}

// =====================================================================
extern "C" void kernel_launch(void* const* d_in, const int* in_sizes, int n_in,
                              void* d_out, int out_size, void* d_ws, size_t ws_size,
                              hipStream_t stream)
{
  (void)in_sizes; (void)n_in; (void)out_size; (void)ws_size;
  const float* x    = (const float*)d_in[0];
  const float* ln1g = (const float*)d_in[1];
  const float* ln1b = (const float*)d_in[2];
  const float* ln2g = (const float*)d_in[3];
  const float* ln2b = (const float*)d_in[4];
  const float* Wq = (const float*)d_in[5];
  const float* bq = (const float*)d_in[6];
  const float* Wk = (const float*)d_in[7];
  const float* bk = (const float*)d_in[8];
  const float* Wv = (const float*)d_in[9];
  const float* bv = (const float*)d_in[10];
  const float* Wo = (const float*)d_in[11];
  const float* bo = (const float*)d_in[12];
  const float* W1 = (const float*)d_in[13];
  const float* b1 = (const float*)d_in[14];
  const float* W2 = (const float*)d_in[15];
  const float* b2 = (const float*)d_in[16];
  float* out = (float*)d_out;

  char* ws = (char*)d_ws;
  float*    MX  = (float*)   (ws);                        // 16MB fp32 GEMM scratch
  float*    X2  = (float*)   (ws + ((size_t)16<<20));     // 16MB
  float*    OP  = (float*)   (ws + ((size_t)32<<20));     // 16MB
  uint16_t* HB  = (uint16_t*)(ws + ((size_t)48<<20));     // 8MB bf16
  uint16_t* QB  = (uint16_t*)(ws + ((size_t)56<<20));
  uint16_t* KB  = (uint16_t*)(ws + ((size_t)64<<20));
  uint16_t* VB  = (uint16_t*)(ws + ((size_t)72<<20));
  uint16_t* OB  = (uint16_t*)(ws + ((size_t)80<<20));
  uint16_t* F1B = (uint16_t*)(ws + ((size_t)88<<20));     // 32MB bf16
  uint16_t* WB  = (uint16_t*)(ws + ((size_t)120<<20));    // 6MB bf16 weights
  float*    YV  = (float*)   (ws + ((size_t)126<<20) + (512<<10));
  float*    NH  = (float*)   (ws + ((size_t)127<<20));
  float*    NO  = NH + R_;
  float*    N3  = NO + R_;
  float*    N4  = N3 + R_;

  uint16_t* WBq = WB;
  uint16_t* WBk = WB + 262144;
  uint16_t* WBv = WB + 524288;
  uint16_t* WBo = WB + 786432;
  uint16_t* WB1 = WB + 1048576;
  uint16_t* WB2 = WB + 2097152;
  float* yq = YV;
  float* yk = YV + 513;
  float* yvv = YV + 1026;
  float* yo = YV + 1539;
  float* y1 = YV + 2052;
  float* y2 = YV + 4101;

  // ================= Expert 0: Euclidean =================
  cvt_k<<<1024,256,0,stream>>>(Wq, WBq, E_*E_);
  cvt_k<<<1024,256,0,stream>>>(Wk, WBk, E_*E_);
  cvt_k<<<1024,256,0,stream>>>(Wv, WBv, E_*E_);
  cvt_k<<<1024,256,0,stream>>>(Wo, WBo, E_*E_);
  cvt_k<<<4096,256,0,stream>>>(W1, WB1, FFN_*E_);
  cvt_k<<<4096,256,0,stream>>>(W2, WB2, E_*FFN_);
  ln_k<<<R_,256,0,stream>>>(x, ln1g, ln1b, HB);
  gemm_bf16<<<dim3(4,64),256,0,stream>>>(HB, WBq, R_,512,512, 1, bq, nullptr, nullptr, QB);
  gemm_bf16<<<dim3(4,64),256,0,stream>>>(HB, WBk, R_,512,512, 1, bk, nullptr, nullptr, KB);
  gemm_bf16<<<dim3(4,64),256,0,stream>>>(HB, WBv, R_,512,512, 1, bv, nullptr, nullptr, VB);
  attn_mfma<0><<<dim3(8,128),256,0,stream>>>(QB, KB, VB, nullptr, OB);
  gemm_bf16<<<dim3(4,64),256,0,stream>>>(OB, WBo, R_,512,512, 2, bo, x, X2, nullptr);
  ln_k<<<R_,256,0,stream>>>(X2, ln2g, ln2b, HB);
  gemm_bf16<<<dim3(16,64),256,0,stream>>>(HB, WB1, R_,2048,512, 3, b1, nullptr, nullptr, F1B);
  gemm_bf16<<<dim3(4,64),256,0,stream>>>(F1B, WB2, R_,512,2048, 4, b2, X2, out, nullptr);

  // ================= Expert 1: Hyperbolic =================
  const float* x1 = x + (size_t)R_*E_;
  cvt_k<<<1024,256,0,stream>>>(Wq + (size_t)E_*E_, WBq, E_*E_);
  cvt_k<<<1024,256,0,stream>>>(Wk + (size_t)E_*E_, WBk, E_*E_);
  cvt_k<<<1024,256,0,stream>>>(Wv + (size_t)E_*E_, WBv, E_*E_);
  cvt_k<<<1024,256,0,stream>>>(Wo + (size_t)E_*E_, WBo, E_*E_);
  cvt_k<<<4096,256,0,stream>>>(W1 + (size_t)FFN_*E_, WB1, FFN_*E_);
  cvt_k<<<4096,256,0,stream>>>(W2 + (size_t)E_*FFN_, WB2, E_*FFN_);
  expmap0_vec<<<1,256,0,stream>>>(bq + E_,   yq, E_);
  expmap0_vec<<<1,256,0,stream>>>(bk + E_,   yk, E_);
  expmap0_vec<<<1,256,0,stream>>>(bv + E_,   yvv, E_);
  expmap0_vec<<<1,256,0,stream>>>(bo + E_,   yo, E_);
  expmap0_vec<<<1,256,0,stream>>>(b1 + FFN_, y1, FFN_);
  expmap0_vec<<<1,256,0,stream>>>(b2 + E_,   y2, E_);
  hyp_lnexp<<<R_,256,0,stream>>>(x1, ln1g+E_, ln1b+E_, HB, NH, 0);
  gemm_bf16<<<dim3(4,64),256,0,stream>>>(HB, WBq, R_,512,512, 0, nullptr,nullptr, MX, nullptr);
  man_epi<2><<<R_,256,0,stream>>>(MX, NH, yq, QB, nullptr, nullptr, 2);
  gemm_bf16<<<dim3(4,64),256,0,stream>>>(HB, WBk, R_,512,512, 0, nullptr,nullptr, MX, nullptr);
  man_epi<2><<<R_,256,0,stream>>>(MX, NH, yk, KB, nullptr, nullptr, 2);
  gemm_bf16<<<dim3(4,64),256,0,stream>>>(HB, WBv, R_,512,512, 0, nullptr,nullptr, MX, nullptr);
  man_epi<2><<<R_,256,0,stream>>>(MX, NH, yvv, VB, nullptr, nullptr, 2);
  attn_mfma<1><<<dim3(8,128),256,0,stream>>>(QB, KB, VB, OP, nullptr);
  o_finish<<<R_,256,0,stream>>>(OP, OB, NO);
  gemm_bf16<<<dim3(4,64),256,0,stream>>>(OB, WBo, R_,512,512, 0, nullptr,nullptr, MX, nullptr);
  man_epi<2><<<R_,256,0,stream>>>(MX, NO, yo, nullptr, OP, nullptr, 0);
  midpoint_k<<<R_,256,0,stream>>>(OP, x1, X2, 0);
  hyp_lnexp<<<R_,256,0,stream>>>(X2, ln2g+E_, ln2b+E_, HB, N3, 1);
  for(int c=0;c<4;c++){
    gemm_bf16<<<dim3(16,16),256,0,stream>>>(HB + (size_t)c*2048*E_, WB1, 2048, 2048, 512, 0,
                                            nullptr, nullptr, MX, nullptr);
    man_epi<8><<<2048,256,0,stream>>>(MX, N3 + c*2048, y1, F1B + (size_t)c*2048*FFN_,
                                      nullptr, N4 + c*2048, 1);
  }
  gemm_bf16<<<dim3(4,64),256,0,stream>>>(F1B, WB2, R_,512,2048, 0, nullptr,nullptr, MX, nullptr);
  man_epi<2><<<R_,256,0,stream>>>(MX, N4, y2, nullptr, OP, nullptr, 1);
  midpoint_k<<<R_,256,0,stream>>>(OP, X2, out + (size_t)R_*E_, 1);
}

// Round 3
// 671.080 us; speedup vs baseline: 5.3173x; 1.3140x over previous
//
#include <hip/hip_runtime.h>
#include <cstdint>
#include <cstddef>

#define S_ 512
#define B_ 16
#define H_ 8
#define D_ 64
#define E_ 512
#define FFN_ 2048
#define R_ (S_*B_)          // 8192 rows (s*B+b)
#define EPSF 1e-6f
#define PROJ_M 0.99999f     // 1 - 1e-5

typedef __attribute__((ext_vector_type(8))) short bf16x8;
typedef __attribute__((ext_vector_type(4))) float f32x4;

// ---------- helpers ----------
__device__ __forceinline__ float bf2f(uint32_t u){
  union{uint32_t i; float f;} c; c.i = u<<16; return c.f;
}
__device__ __forceinline__ uint16_t f2bf(float f){
  union{float f; uint32_t i;} c; c.f = f;
  return (uint16_t)((c.i + 0x7FFFu + ((c.i>>16)&1u))>>16);
}
__device__ __forceinline__ void unpack8(uint4 u, float* f){
  f[0]=bf2f(u.x&0xFFFFu); f[1]=bf2f(u.x>>16);
  f[2]=bf2f(u.y&0xFFFFu); f[3]=bf2f(u.y>>16);
  f[4]=bf2f(u.z&0xFFFFu); f[5]=bf2f(u.z>>16);
  f[6]=bf2f(u.w&0xFFFFu); f[7]=bf2f(u.w>>16);
}
__device__ __forceinline__ uint4 pack8(const float* f){
  uint4 u;
  u.x = (uint32_t)f2bf(f[0]) | ((uint32_t)f2bf(f[1])<<16);
  u.y = (uint32_t)f2bf(f[2]) | ((uint32_t)f2bf(f[3])<<16);
  u.z = (uint32_t)f2bf(f[4]) | ((uint32_t)f2bf(f[5])<<16);
  u.w = (uint32_t)f2bf(f[6]) | ((uint32_t)f2bf(f[7])<<16);
  return u;
}
__device__ __forceinline__ float artanh_c(float x){
  return (x >= 0.99999994f) ? 8.4056215f : atanhf(x);
}
__device__ __forceinline__ float wave_sum(float x){
  #pragma unroll
  for(int o=32;o>=1;o>>=1) x += __shfl_xor(x,o);
  return x;
}
__device__ __forceinline__ float halfsum32(float x){
  #pragma unroll
  for(int o=16;o>=1;o>>=1) x += __shfl_xor(x,o);
  return x;
}
__device__ __forceinline__ float block_sum(float x, float* sb){
  x = wave_sum(x);
  const int w = threadIdx.x >> 6;
  __syncthreads();
  if((threadIdx.x & 63)==0) sb[w] = x;
  __syncthreads();
  return sb[0]+sb[1]+sb[2]+sb[3];
}
// async global->LDS, 16B per lane; LDS dest = wave-uniform base + lane*16
__device__ __forceinline__ void gl_lds16(const void* g, void* l){
  __builtin_amdgcn_global_load_lds(
    (const __attribute__((address_space(1))) void*)(uintptr_t)g,
    (__attribute__((address_space(3))) void*)(uint32_t)(uintptr_t)l, 16, 0, 0);
}

// ---------- all weights fp32 -> bf16 (both experts), one launch ----------
__global__ __launch_bounds__(256) void cvt_all(
  const float* __restrict__ Wq, const float* __restrict__ Wk,
  const float* __restrict__ Wv, const float* __restrict__ Wo,
  const float* __restrict__ W1, const float* __restrict__ W2,
  uint16_t* __restrict__ dst)
{
  int i4 = blockIdx.x*256 + threadIdx.x;   // 4-elem units, total 1572864
  int e = 0;
  if(i4 >= 786432){ e = 1; i4 -= 786432; }
  const int r = i4;
  const float* s;
  if(r < 65536)        s = Wq + (size_t)(r)*4        + (size_t)e*262144;
  else if(r < 131072)  s = Wk + (size_t)(r-65536)*4  + (size_t)e*262144;
  else if(r < 196608)  s = Wv + (size_t)(r-131072)*4 + (size_t)e*262144;
  else if(r < 262144)  s = Wo + (size_t)(r-196608)*4 + (size_t)e*262144;
  else if(r < 524288)  s = W1 + (size_t)(r-262144)*4 + (size_t)e*1048576;
  else                 s = W2 + (size_t)(r-524288)*4 + (size_t)e*1048576;
  const float4 f = *(const float4*)s;
  uint2 o;
  o.x = (uint32_t)f2bf(f.x) | ((uint32_t)f2bf(f.y)<<16);
  o.y = (uint32_t)f2bf(f.z) | ((uint32_t)f2bf(f.w)<<16);
  *(uint2*)(dst + (size_t)e*3145728 + (size_t)r*4) = o;
}

// ---------- expmap0 of all 6 expert-1 biases, one launch (6 blocks) ----------
__global__ __launch_bounds__(256) void expmap_all(
  const float* __restrict__ bq, const float* __restrict__ bk,
  const float* __restrict__ bv, const float* __restrict__ bo,
  const float* __restrict__ b1, const float* __restrict__ b2,
  float* __restrict__ YV)
{
  __shared__ float sb[4];
  const int id = blockIdx.x, t = threadIdx.x;
  const float* src; float* dst; int C;
  if(id==0){ src=bq+E_;   dst=YV+0;    C=E_; }
  else if(id==1){ src=bk+E_;   dst=YV+513;  C=E_; }
  else if(id==2){ src=bv+E_;   dst=YV+1026; C=E_; }
  else if(id==3){ src=bo+E_;   dst=YV+1539; C=E_; }
  else if(id==4){ src=b1+FFN_; dst=YV+2052; C=FFN_; }
  else          { src=b2+E_;   dst=YV+4101; C=E_; }
  const int npc = C >> 8;
  float v[8]; float s2 = 0.f;
  for(int i=0;i<npc;i++){ v[i] = src[t+256*i]; s2 += v[i]*v[i]; }
  s2 = block_sum(s2, sb);
  const float n = sqrtf(s2 + 1e-15f);
  const float th = tanhf(n);
  const float sc = th/n;
  for(int i=0;i<npc;i++) dst[t+256*i] = v[i]*sc;
  if(t==0) dst[C] = th*th;
}

// ---------- plain layernorm (euclid), row=512, fp32 in -> bf16 ----------
__global__ __launch_bounds__(256) void ln_k(const float* __restrict__ x,
  const float* __restrict__ g, const float* __restrict__ b, uint16_t* __restrict__ out)
{
  __shared__ float sb[4];
  const int row = blockIdx.x, t = threadIdx.x;
  const size_t base = (size_t)row*E_;
  float v0 = x[base+t], v1 = x[base+t+256];
  const float mu  = block_sum(v0+v1, sb) * (1.f/E_);
  const float d0 = v0-mu, d1 = v1-mu;
  const float var = block_sum(d0*d0+d1*d1, sb) * (1.f/E_);
  const float rs = 1.f/sqrtf(var + 1e-5f);
  out[base+t]     = f2bf(d0*rs*g[t] + b[t]);
  out[base+t+256] = f2bf(d1*rs*g[t+256] + b[t+256]);
}

// ---------- hyp: expmap0(LN(logmap0(x))) [+projx], bf16 out + row norm ----------
__global__ __launch_bounds__(256) void hyp_lnexp(const float* __restrict__ x,
  const float* __restrict__ g, const float* __restrict__ b,
  uint16_t* __restrict__ out, float* __restrict__ nout, int do_projx)
{
  __shared__ float sb[4];
  const int row = blockIdx.x, t = threadIdx.x;
  const size_t base = (size_t)row*E_;
  float v0 = x[base+t], v1 = x[base+t+256];
  const float s2 = block_sum(v0*v0+v1*v1, sb);
  const float n  = sqrtf(s2 + 1e-15f);
  const float ls = artanh_c(n)/n;
  v0 *= ls; v1 *= ls;
  const float mu  = block_sum(v0+v1, sb) * (1.f/E_);
  const float d0 = v0-mu, d1 = v1-mu;
  const float var = block_sum(d0*d0+d1*d1, sb) * (1.f/E_);
  const float rs = 1.f/sqrtf(var + 1e-5f);
  float t0 = d0*rs*g[t] + b[t];
  float t1 = d1*rs*g[t+256] + b[t+256];
  const float n2s = block_sum(t0*t0+t1*t1, sb);
  const float n2 = sqrtf(n2s + 1e-15f);
  const float nh = tanhf(n2);
  const float scl = nh/n2;
  t0 *= scl; t1 *= scl;
  float nrm = nh;
  if(do_projx && nrm > PROJ_M){ const float s = PROJ_M/nrm; t0*=s; t1*=s; nrm = PROJ_M; }
  out[base+t] = f2bf(t0); out[base+t+256] = f2bf(t1);
  if(t==0) nout[row] = nrm;
}

// ---------- per-head squared norms of euclid Q,K (layout [b*8+h][s]) ----------
__global__ __launch_bounds__(256) void qk_norms(
  const uint16_t* __restrict__ Qb, const uint16_t* __restrict__ Kb,
  float* __restrict__ qn, float* __restrict__ kn)
{
  const int w = threadIdx.x >> 6, l = threadIdx.x & 63;
  const int row = blockIdx.x*4 + w;
  const int s = row >> 4, b = row & 15;
  const size_t base = (size_t)row*E_ + l*8;
  {
    uint4 u = *(const uint4*)(Qb + base);
    float f[8]; unpack8(u, f);
    float ss = 0.f;
    #pragma unroll
    for(int i=0;i<8;i++) ss += f[i]*f[i];
    ss += __shfl_xor(ss,1); ss += __shfl_xor(ss,2); ss += __shfl_xor(ss,4);
    if((l&7)==0) qn[((b<<3) + (l>>3))*512 + s] = ss;
  }
  {
    uint4 u = *(const uint4*)(Kb + base);
    float f[8]; unpack8(u, f);
    float ss = 0.f;
    #pragma unroll
    for(int i=0;i<8;i++) ss += f[i]*f[i];
    ss += __shfl_xor(ss,1); ss += __shfl_xor(ss,2); ss += __shfl_xor(ss,4);
    if((l&7)==0) kn[((b<<3) + (l>>3))*512 + s] = ss;
  }
}

// ---------- man_linear epilogue (+optional per-head projx/lambda, relu, fused midpoint) ----------
// flags: 1 relu; 2 per-head projx (NPC==2); 4 scale out by lambda; 8 projx on midpoint
template<int NPC>
__global__ __launch_bounds__(256) void man_epi(
  const uint16_t* __restrict__ mxb, const float* __restrict__ nxbuf,
  const float* __restrict__ y, uint16_t* __restrict__ outb,
  float* __restrict__ nout, float* __restrict__ hnout, float* __restrict__ lamout,
  const float* __restrict__ midres, float* __restrict__ midout, int flags)
{
  constexpr int C = NPC*256;
  __shared__ float sb[4];
  const int row = blockIdx.x, t = threadIdx.x;
  const size_t base = (size_t)row*C + (size_t)t*NPC;
  float v[NPC], yv[NPC];
  if(NPC==2){
    const uint32_t u = *(const uint32_t*)(mxb + base);
    v[0] = bf2f(u & 0xFFFFu); v[1] = bf2f(u >> 16);
  } else {
    const uint4 u = *(const uint4*)(mxb + base);
    unpack8(u, v);
  }
  float s2 = 0.f;
  #pragma unroll
  for(int i=0;i<NPC;i++){ yv[i] = y[t*NPC + i]; s2 += v[i]*v[i]; }
  s2 = block_sum(s2, sb);
  const float nmx = sqrtf(s2 + 1e-15f);
  const float nx  = nxbuf[row];
  const float sc  = tanhf(nmx/nx * artanh_c(nx));
  const bool ok   = (nmx > 1e-7f);
  const float fmul = ok ? (sc/nmx) : 0.f;
  const float x2   = ok ? sc*sc : 0.f;
  float xy = 0.f;
  #pragma unroll
  for(int i=0;i<NPC;i++){ v[i] *= fmul; xy += v[i]*yv[i]; }
  xy = block_sum(xy, sb);
  const float y2 = y[C];
  const float aa = 1.f + 2.f*xy + y2;
  const float bb = 1.f - x2;
  const float iden = 1.f/fmaxf(1.f + 2.f*xy + x2*y2, EPSF);
  const float num2 = aa*aa*x2 + 2.f*aa*bb*xy + bb*bb*y2;
  const float nz = sqrtf(num2*iden*iden + 1e-15f);
  const float ps = (nz > PROJ_M) ? (PROJ_M/nz) : 1.f;
  float nfin = (nz > PROJ_M) ? PROJ_M : nz;
  #pragma unroll
  for(int i=0;i<NPC;i++) v[i] = (aa*v[i] + bb*yv[i]) * iden * ps;
  if(NPC==2 && (flags & 2)){
    float hs = halfsum32(v[0]*v[0] + v[1]*v[1]);
    float nh = sqrtf(hs + 1e-15f);
    float phs = 1.f;
    if(nh > PROJ_M){ phs = PROJ_M/nh; nh = PROJ_M; }
    v[0] *= phs; v[1] *= phs;
    const float nh2 = nh*nh;
    const float lam = 2.f/fmaxf(1.f - nh2, EPSF);
    if(flags & 4){ v[0] *= lam; v[1] *= lam; }
    if((t & 31) == 0){
      const int s = row >> 4, b = row & 15;
      const int idx = ((b<<3) + (t>>5))*512 + s;
      if(hnout) hnout[idx] = nh2;
      if(lamout) lamout[idx] = lam;
    }
  }
  if(flags & 1){
    float rs = 0.f;
    #pragma unroll
    for(int i=0;i<NPC;i++){ v[i] = fmaxf(v[i], 0.f); rs += v[i]*v[i]; }
    rs = block_sum(rs, sb);
    nfin = sqrtf(rs + 1e-15f);
  }
  if(midres){
    float bv2[NPC];
    float pb = 0.f, pab = 0.f;
    #pragma unroll
    for(int i=0;i<NPC;i++){ bv2[i] = midres[base + i]; pb += bv2[i]*bv2[i]; pab += v[i]*bv2[i]; }
    const float sa  = nfin*nfin;
    const float sbb = block_sum(pb, sb);
    const float sab = block_sum(pab, sb);
    const float l1 = 2.f/fmaxf(1.f - sa,  EPSF);
    const float l2 = 2.f/fmaxf(1.f - sbb, EPSF);
    const float idn = 1.f/fmaxf(l1 + l2 - 2.f, EPSF);
    const float nt2 = (l1*l1*sa + 2.f*l1*l2*sab + l2*l2*sbb)*idn*idn;
    const float nt = sqrtf(nt2 + 1e-15f);
    const float sfin = tanhf(0.5f*artanh_c(nt));
    float scm = sfin/nt;
    if((flags & 8) && sfin > PROJ_M) scm *= PROJ_M/sfin;
    #pragma unroll
    for(int i=0;i<NPC;i++) midout[base + i] = (v[i]*l1 + bv2[i]*l2)*idn*scm;
  } else {
    if(NPC==2){
      uint32_t u = (uint32_t)f2bf(v[0]) | ((uint32_t)f2bf(v[1])<<16);
      *(uint32_t*)(outb + base) = u;
    } else {
      *(uint4*)(outb + base) = pack8(v);
    }
    if(nout && t==0) nout[row] = nfin;
  }
}

// ---------- hyp attention-output finish: per-head msm(0.5)+projx, full projx ----------
__global__ __launch_bounds__(256) void o_finish2(const uint16_t* __restrict__ op,
  uint16_t* __restrict__ outb, float* __restrict__ nout)
{
  __shared__ float sb[4];
  const int row = blockIdx.x, t = threadIdx.x;
  const size_t base = (size_t)row*E_ + t*2;
  const uint32_t u = *(const uint32_t*)(op + base);
  float v0 = bf2f(u & 0xFFFFu), v1 = bf2f(u >> 16);
  const float hs = halfsum32(v0*v0 + v1*v1);
  const float ns = sqrtf(hs + 1e-15f);
  const float tt = tanhf(0.5f*artanh_c(ns));
  float scv = tt/ns;
  float sn = tt;
  if(sn > PROJ_M){ scv *= PROJ_M/sn; sn = PROJ_M; }
  v0 *= scv; v1 *= scv;
  const float tot = block_sum(v0*v0 + v1*v1, sb);
  const float n = sqrtf(tot + 1e-15f);
  float nf = n;
  if(n > PROJ_M){ const float s = PROJ_M/n; v0 *= s; v1 *= s; nf = PROJ_M; }
  *(uint32_t*)(outb + base) = (uint32_t)f2bf(v0) | ((uint32_t)f2bf(v1)<<16);
  if(t==0) nout[row] = nf;
}

// ---------- bf16 MFMA GEMM: C = A[M,K] @ W[N,K]^T, 128x128 tile, BK=64 ----------
// double-buffered LDS via global_load_lds, XOR-swizzled (pre-swizzled global source)
// mode: 0 raw->outf; 1 +bias->outb; 2 +bias+res->outf; 3 relu+bias->outb;
//       4 relu+bias+res->outf; 5 raw->outb
__global__ __launch_bounds__(256) void gemm2(
    const uint16_t* __restrict__ A, const uint16_t* __restrict__ Bw,
    int M, int N, int K, int mode,
    const float* __restrict__ bias, const float* __restrict__ res,
    float* __restrict__ outf, uint16_t* __restrict__ outb)
{
  __shared__ __align__(16) char AsB[2][16384];
  __shared__ __align__(16) char BsB[2][16384];
  const int tid = threadIdx.x;
  const int l = tid & 63, w = tid >> 6;
  const int wm = w >> 1, wn = w & 1;
  const int m0 = blockIdx.y*128, n0 = blockIdx.x*128;
  const int lr = l & 15, g = l >> 4;
  const int lr3 = l >> 3, lc = l & 7;
  const int c8s = lc ^ lr3;
  const int swq = (lr & 7) << 4;

  const uint16_t* aSrc = A  + (size_t)(m0 + lr3)*K + c8s*8;
  const uint16_t* bSrc = Bw + (size_t)(n0 + lr3)*K + c8s*8;

  f32x4 acc[4][4];
  #pragma unroll
  for(int i=0;i<4;i++)
    #pragma unroll
    for(int j=0;j<4;j++) acc[i][j] = (f32x4){0.f,0.f,0.f,0.f};

  const int nk = K >> 6;
  // prologue stage
  #pragma unroll
  for(int c=0;c<4;c++){
    const int ci = w*4 + c;
    gl_lds16(aSrc + (size_t)(ci*8)*K, AsB[0] + ci*1024);
    gl_lds16(bSrc + (size_t)(ci*8)*K, BsB[0] + ci*1024);
  }
  for(int ks=0; ks<nk; ks++){
    __syncthreads();                       // stage(ks) complete
    if(ks+1 < nk){
      const int k0 = (ks+1) << 6;
      #pragma unroll
      for(int c=0;c<4;c++){
        const int ci = w*4 + c;
        gl_lds16(aSrc + (size_t)(ci*8)*K + k0, AsB[(ks+1)&1] + ci*1024);
        gl_lds16(bSrc + (size_t)(ci*8)*K + k0, BsB[(ks+1)&1] + ci*1024);
      }
    }
    const char* Ac = AsB[ks&1];
    const char* Bc = BsB[ks&1];
    #pragma unroll
    for(int h=0;h<2;h++){
      bf16x8 av[4], bv[4];
      #pragma unroll
      for(int i=0;i<4;i++){
        av[i] = *(const bf16x8*)(Ac + (wm*64 + i*16 + lr)*128 + ((((h*4+g)<<4)) ^ swq));
        bv[i] = *(const bf16x8*)(Bc + (wn*64 + i*16 + lr)*128 + ((((h*4+g)<<4)) ^ swq));
      }
      #pragma unroll
      for(int i=0;i<4;i++)
        #pragma unroll
        for(int j=0;j<4;j++)
          acc[i][j] = __builtin_amdgcn_mfma_f32_16x16x32_bf16(av[i], bv[j], acc[i][j], 0,0,0);
    }
  }
  const int orow = g*4;
  #pragma unroll
  for(int i=0;i<4;i++){
    #pragma unroll
    for(int j=0;j<4;j++){
      const int gn = n0 + wn*64 + j*16 + lr;
      const float bval = (mode==1||mode==2||mode==3||mode==4) ? bias[gn] : 0.f;
      #pragma unroll
      for(int r=0;r<4;r++){
        const int gm = m0 + wm*64 + i*16 + orow + r;
        const float vv = acc[i][j][r];
        const size_t off = (size_t)gm*N + gn;
        if(mode==0){ outf[off] = vv; }
        else if(mode==1){ outb[off] = f2bf(vv + bval); }
        else if(mode==2){ outf[off] = vv + bval + res[off]; }
        else if(mode==3){ outb[off] = f2bf(fmaxf(vv + bval, 0.f)); }
        else if(mode==4){ outf[off] = fmaxf(vv + bval, 0.f) + res[off]; }
        else { outb[off] = f2bf(vv); }
      }
    }
  }
}

// ---------- MFMA flash attention v2: 2 q-tiles/block, precomputed norms/lambda ----------
template<int HYP>
__global__ __launch_bounds__(256) void attn2(
  const uint16_t* __restrict__ Qb, const uint16_t* __restrict__ Kb,
  const uint16_t* __restrict__ Vb, const float* __restrict__ qnG,
  const float* __restrict__ knG, const float* __restrict__ lamG,
  uint16_t* __restrict__ outB)
{
  __shared__ __align__(16) char QsB[16384];     // 2 q-tiles [64][64] bf16 swz
  __shared__ __align__(16) char KsB[2][8192];   // dbuf K tile
  __shared__ __align__(16) char VtB[8192];      // V^T [64d][64k] bf16 swz
  __shared__ __align__(16) char PB[16384];      // 4w x 2qt x [16q][64k] bf16 swz (+ epilogue overlay)
  __shared__ float kkL[512];
  __shared__ float lamL[512];

  const int tid = threadIdx.x;
  const int l = tid & 63, w = tid >> 6;
  const int lr = l & 15, g = l >> 4;
  const int lr3 = l >> 3, lc = l & 7;
  const int c8s = lc ^ lr3;
  const int swq = (lr & 7) << 4;
  const int bh = blockIdx.y;
  const int q0 = blockIdx.x * 128;
  const size_t gstride = (size_t)B_*E_;
  const size_t gbase = (size_t)(bh>>3)*E_ + (size_t)(bh&7)*D_;
  const int sr = tid >> 2, scol = (tid & 3) << 4;

  // ---- prologue staging ----
  #pragma unroll
  for(int c=0;c<4;c++){
    const int ci = w*4 + c;
    gl_lds16(Qb + (size_t)(q0 + ci*8 + lr3)*gstride + gbase + c8s*8, QsB + ci*1024);
  }
  kkL[tid]       = knG[bh*512 + tid];
  kkL[tid + 256] = knG[bh*512 + 256 + tid];
  if(HYP){
    lamL[tid]       = lamG[bh*512 + tid];
    lamL[tid + 256] = lamG[bh*512 + 256 + tid];
  }
  #pragma unroll
  for(int c=0;c<2;c++){
    const int ci = w*2 + c;
    gl_lds16(Kb + (size_t)(ci*8 + lr3)*gstride + gbase + c8s*8, KsB[0] + ci*1024);
  }
  uint4 vr0 = *(const uint4*)(Vb + (size_t)sr*gstride + gbase + scol);
  uint4 vr1 = *(const uint4*)(Vb + (size_t)sr*gstride + gbase + scol + 8);
  __syncthreads();

  // hoist Q fragments + qq
  const int qrow = w*16 + lr;
  bf16x8 qb00, qb01, qb10, qb11;
  qb00 = *(const bf16x8*)(QsB +        qrow*128 + (((0*4+g)<<4) ^ swq));
  qb01 = *(const bf16x8*)(QsB +        qrow*128 + (((1*4+g)<<4) ^ swq));
  qb10 = *(const bf16x8*)(QsB + 8192 + qrow*128 + (((0*4+g)<<4) ^ swq));
  qb11 = *(const bf16x8*)(QsB + 8192 + qrow*128 + (((1*4+g)<<4) ^ swq));
  float qq[2];
  qq[0] = qnG[bh*512 + q0 + qrow];
  qq[1] = qnG[bh*512 + q0 + 64 + qrow];

  f32x4 oa[2][4];
  #pragma unroll
  for(int qt=0;qt<2;qt++)
    #pragma unroll
    for(int m=0;m<4;m++) oa[qt][m] = (f32x4){0.f,0.f,0.f,0.f};
  float mrun[2] = {-3.0e38f, -3.0e38f};
  float lrun[2] = {0.f, 0.f};
  float dnr[2]  = {0.f, 0.f};

  for(int kt=0; kt<8; kt++){
    // ---- V write to LDS (transposed, swizzled) ----
    {
      uint16_t us[16];
      *(uint4*)&us[0] = vr0; *(uint4*)&us[8] = vr1;
      const int rot = (tid & 3) * 4;
      #pragma unroll
      for(int ii=0; ii<16; ii++){
        const int i = (ii + rot) & 15;
        const int d = scol + i;
        *(uint16_t*)(VtB + d*128 + ((((sr>>3) ^ (d&7))<<4)) + ((sr&7)<<1)) = us[i];
      }
    }
    __syncthreads();   // (A): V visible, K(kt) drained
    if(kt < 7){
      #pragma unroll
      for(int c=0;c<2;c++){
        const int ci = w*2 + c;
        gl_lds16(Kb + (size_t)((kt+1)*64 + ci*8 + lr3)*gstride + gbase + c8s*8,
                 KsB[(kt+1)&1] + ci*1024);
      }
      vr0 = *(const uint4*)(Vb + (size_t)((kt+1)*64 + sr)*gstride + gbase + scol);
      vr1 = *(const uint4*)(Vb + (size_t)((kt+1)*64 + sr)*gstride + gbase + scol + 8);
    }
    const char* Kc = KsB[kt&1];
    const float* kkt = &kkL[kt*64];
    const float* lmt = &lamL[kt*64];

    #pragma unroll
    for(int qt=0; qt<2; qt++){
      // scores S^T = K * Q^T
      f32x4 st[4];
      #pragma unroll
      for(int t=0;t<4;t++){
        f32x4 c = (f32x4){0.f,0.f,0.f,0.f};
        const bf16x8 ka0 = *(const bf16x8*)(Kc + (t*16+lr)*128 + (((0*4+g)<<4) ^ swq));
        const bf16x8 ka1 = *(const bf16x8*)(Kc + (t*16+lr)*128 + (((1*4+g)<<4) ^ swq));
        c = __builtin_amdgcn_mfma_f32_16x16x32_bf16(ka0, qt? qb10 : qb00, c, 0,0,0);
        c = __builtin_amdgcn_mfma_f32_16x16x32_bf16(ka1, qt? qb11 : qb01, c, 0,0,0);
        st[t] = c;
      }
      // transform (log2 domain)
      float ps2[16]; float mloc = -3.0e38f;
      const float q2 = qq[qt];
      #pragma unroll
      for(int t=0;t<4;t++){
        const f32x4 kkv = *(const f32x4*)(kkt + t*16 + g*4);
        #pragma unroll
        for(int r=0;r<4;r++){
          const float qk = st[t][r], kk = kkv[r];
          float s2;
          if(HYP){
            const float u = fmaxf(fmaf(-2.f, qk, q2 + kk), 0.f);
            const float v = fmaxf(fmaf(q2, kk, fmaf(-2.f, qk, 1.f)), EPSF);
            const float ww = __builtin_amdgcn_sqrtf(u*v);
            const float L1 = __builtin_amdgcn_logf(v + ww);
            const float L23 = __builtin_amdgcn_logf(fmaxf(v*(v - u), 1e-30f));
            s2 = fmaxf(fmaf(-0.25f, L1, 0.125f*L23), -3.0317087f);
          } else {
            const float d2 = fmaxf(fmaf(-2.f, qk, q2 + kk), 0.f) + 1e-12f;
            s2 = -0.18033688f * __builtin_amdgcn_sqrtf(d2);
          }
          ps2[t*4+r] = s2;
          mloc = fmaxf(mloc, s2);
        }
      }
      mloc = fmaxf(mloc, __shfl_xor(mloc,16));
      mloc = fmaxf(mloc, __shfl_xor(mloc,32));
      const float mnew = fmaxf(mrun[qt], mloc);
      const float corr = __builtin_amdgcn_exp2f(mrun[qt] - mnew);
      mrun[qt] = mnew;
      float ls = 0.f, dl = 0.f;
      char* Pmy = PB + (w*2+qt)*2048 + lr*128 + ((g&1)<<3);
      #pragma unroll
      for(int t=0;t<4;t++){
        const float e0 = __builtin_amdgcn_exp2f(ps2[t*4+0]-mnew);
        const float e1 = __builtin_amdgcn_exp2f(ps2[t*4+1]-mnew);
        const float e2 = __builtin_amdgcn_exp2f(ps2[t*4+2]-mnew);
        const float e3 = __builtin_amdgcn_exp2f(ps2[t*4+3]-mnew);
        ls += (e0+e1)+(e2+e3);
        if(HYP){
          const f32x4 lv = *(const f32x4*)(lmt + t*16 + g*4);
          dl += e0*(lv[0]-1.f) + e1*(lv[1]-1.f) + e2*(lv[2]-1.f) + e3*(lv[3]-1.f);
        }
        uint2 pw;
        pw.x = (uint32_t)f2bf(e0) | ((uint32_t)f2bf(e1)<<16);
        pw.y = (uint32_t)f2bf(e2) | ((uint32_t)f2bf(e3)<<16);
        *(uint2*)(Pmy + ((((t*2 + (g>>1)) ^ (lr&7)))<<4)) = pw;
      }
      ls += __shfl_xor(ls,16); ls += __shfl_xor(ls,32);
      lrun[qt] = lrun[qt]*corr + ls;
      if(HYP){
        dl += __shfl_xor(dl,16); dl += __shfl_xor(dl,32);
        dnr[qt] = dnr[qt]*corr + dl;
      }
      #pragma unroll
      for(int m=0;m<4;m++){
        oa[qt][m][0]*=corr; oa[qt][m][1]*=corr; oa[qt][m][2]*=corr; oa[qt][m][3]*=corr;
      }
    }
    // ---- PV: O^T += V^T * P^T (both q-tiles share va) ----
    #pragma unroll
    for(int h=0;h<2;h++){
      const bf16x8 pb0 = *(const bf16x8*)(PB + (w*2+0)*2048 + lr*128 + ((((h*4+g) ^ (lr&7)))<<4));
      const bf16x8 pb1 = *(const bf16x8*)(PB + (w*2+1)*2048 + lr*128 + ((((h*4+g) ^ (lr&7)))<<4));
      #pragma unroll
      for(int m=0;m<4;m++){
        const int d = m*16 + lr;
        const bf16x8 va = *(const bf16x8*)(VtB + d*128 + ((((h*4+g) ^ (lr&7)))<<4));
        oa[0][m] = __builtin_amdgcn_mfma_f32_16x16x32_bf16(va, pb0, oa[0][m], 0,0,0);
        oa[1][m] = __builtin_amdgcn_mfma_f32_16x16x32_bf16(va, pb1, oa[1][m], 0,0,0);
      }
    }
    __syncthreads();   // (B): compute done; Vt/P free, prefetch drained
  }

  // ---- epilogue: wave-local restage (overlay on own PB region) + store ----
  #pragma unroll
  for(int qt=0; qt<2; qt++){
    float scale;
    {
      const float invl = 1.f/lrun[qt];
      if(HYP){
        const float dn = fmaxf(dnr[qt]*invl, EPSF);
        scale = invl/dn;
      } else scale = invl;
    }
    #pragma unroll
    for(int m=0;m<4;m++){
      f32x4 vv;
      vv[0]=oa[qt][m][0]*scale; vv[1]=oa[qt][m][1]*scale;
      vv[2]=oa[qt][m][2]*scale; vv[3]=oa[qt][m][3]*scale;
      *(f32x4*)(PB + w*4096 + lr*256 + (((m*64 + g*16)) ^ ((lr&7)<<4))) = vv;
    }
    {
      const int row = tid >> 2, cw = tid & 3;
      const int wsrc = row >> 4, ql = row & 15;
      float vals[16];
      #pragma unroll
      for(int ii=0;ii<4;ii++)
        *(f32x4*)&vals[ii*4] = *(const f32x4*)(PB + wsrc*4096 + ql*256 + (((cw*64 + ii*16)) ^ ((ql&7)<<4)));
      const size_t go = (size_t)(q0 + qt*64 + row)*gstride + gbase + cw*16;
      *(uint4*)(outB + go)     = pack8(vals);
      *(uint4*)(outB + go + 8) = pack8(vals+8);
    }
  }
}

// =====================================================================
extern "C" void kernel_launch(void* const* d_in, const int* in_sizes, int n_in,
                              void* d_out, int out_size, void* d_ws, size_t ws_size,
                              hipStream_t stream)
{
  (void)in_sizes; (void)n_in; (void)out_size; (void)ws_size;
  const float* x    = (const float*)d_in[0];
  const float* ln1g = (const float*)d_in[1];
  const float* ln1b = (const float*)d_in[2];
  const float* ln2g = (const float*)d_in[3];
  const float* ln2b = (const float*)d_in[4];
  const float* Wq = (const float*)d_in[5];
  const float* bq = (const float*)d_in[6];
  const float* Wk = (const float*)d_in[7];
  const float* bk = (const float*)d_in[8];
  const float* Wv = (const float*)d_in[9];
  const float* bv = (const float*)d_in[10];
  const float* Wo = (const float*)d_in[11];
  const float* bo = (const float*)d_in[12];
  const float* W1 = (const float*)d_in[13];
  const float* b1 = (const float*)d_in[14];
  const float* W2 = (const float*)d_in[15];
  const float* b2 = (const float*)d_in[16];
  float* out = (float*)d_out;

  char* ws = (char*)d_ws;
  uint16_t* MXb = (uint16_t*)(ws);                          // 8MB bf16 GEMM scratch
  float*    X2  = (float*)   (ws + ((size_t)8<<20));        // 16MB fp32
  uint16_t* HB  = (uint16_t*)(ws + ((size_t)24<<20));       // 8MB
  uint16_t* QB  = (uint16_t*)(ws + ((size_t)32<<20));
  uint16_t* KB  = (uint16_t*)(ws + ((size_t)40<<20));
  uint16_t* VB  = (uint16_t*)(ws + ((size_t)48<<20));
  uint16_t* OB  = (uint16_t*)(ws + ((size_t)56<<20));
  uint16_t* F1B = (uint16_t*)(ws + ((size_t)64<<20));       // 32MB
  uint16_t* WB  = (uint16_t*)(ws + ((size_t)96<<20));       // 12MB (both experts)
  float*    YV  = (float*)   (ws + ((size_t)108<<20));      // expmap'd biases
  float*    NH  = (float*)   (ws + ((size_t)108<<20) + (32<<10));
  float*    NO  = NH + R_;
  float*    N3  = NO + R_;
  float*    N4  = N3 + R_;
  float*    qnG = (float*)   (ws + ((size_t)109<<20));      // [128][512]
  float*    knG = qnG + 65536;
  float*    lamG= knG + 65536;

  // ---- weights + biases (both experts) ----
  cvt_all<<<6144,256,0,stream>>>(Wq,Wk,Wv,Wo,W1,W2, WB);
  expmap_all<<<6,256,0,stream>>>(bq,bk,bv,bo,b1,b2, YV);

  // ================= Expert 0: Euclidean =================
  ln_k<<<R_,256,0,stream>>>(x, ln1g, ln1b, HB);
  gemm2<<<dim3(4,64),256,0,stream>>>(HB, WB,          R_,512,512, 1, bq, nullptr, nullptr, QB);
  gemm2<<<dim3(4,64),256,0,stream>>>(HB, WB+262144,   R_,512,512, 1, bk, nullptr, nullptr, KB);
  gemm2<<<dim3(4,64),256,0,stream>>>(HB, WB+524288,   R_,512,512, 1, bv, nullptr, nullptr, VB);
  qk_norms<<<2048,256,0,stream>>>(QB, KB, qnG, knG);
  attn2<0><<<dim3(4,128),256,0,stream>>>(QB, KB, VB, qnG, knG, nullptr, OB);
  gemm2<<<dim3(4,64),256,0,stream>>>(OB, WB+786432,   R_,512,512, 2, bo, x, X2, nullptr);
  ln_k<<<R_,256,0,stream>>>(X2, ln2g, ln2b, HB);
  gemm2<<<dim3(16,64),256,0,stream>>>(HB, WB+1048576, R_,2048,512, 3, b1, nullptr, nullptr, F1B);
  gemm2<<<dim3(4,64),256,0,stream>>>(F1B, WB+2097152, R_,512,2048, 4, b2, X2, out, nullptr);

  // ================= Expert 1: Hyperbolic =================
  const float* x1 = x + (size_t)R_*E_;
  uint16_t* WBe = WB + 3145728;
  hyp_lnexp<<<R_,256,0,stream>>>(x1, ln1g+E_, ln1b+E_, HB, NH, 0);
  gemm2<<<dim3(4,64),256,0,stream>>>(HB, WBe,          R_,512,512, 5, nullptr,nullptr, nullptr, MXb);
  man_epi<2><<<R_,256,0,stream>>>(MXb, NH, YV+0,    QB, nullptr, qnG, nullptr, nullptr, nullptr, 2);
  gemm2<<<dim3(4,64),256,0,stream>>>(HB, WBe+262144,   R_,512,512, 5, nullptr,nullptr, nullptr, MXb);
  man_epi<2><<<R_,256,0,stream>>>(MXb, NH, YV+513,  KB, nullptr, knG, nullptr, nullptr, nullptr, 2);
  gemm2<<<dim3(4,64),256,0,stream>>>(HB, WBe+524288,   R_,512,512, 5, nullptr,nullptr, nullptr, MXb);
  man_epi<2><<<R_,256,0,stream>>>(MXb, NH, YV+1026, VB, nullptr, nullptr, lamG, nullptr, nullptr, 2|4);
  attn2<1><<<dim3(4,128),256,0,stream>>>(QB, KB, VB, qnG, knG, lamG, OB);
  o_finish2<<<R_,256,0,stream>>>(OB, HB, NO);
  gemm2<<<dim3(4,64),256,0,stream>>>(HB, WBe+786432,   R_,512,512, 5, nullptr,nullptr, nullptr, MXb);
  man_epi<2><<<R_,256,0,stream>>>(MXb, NO, YV+1539, nullptr, nullptr, nullptr, nullptr, x1, X2, 0);
  hyp_lnexp<<<R_,256,0,stream>>>(X2, ln2g+E_, ln2b+E_, HB, N3, 1);
  for(int c=0;c<4;c++){
    gemm2<<<dim3(16,16),256,0,stream>>>(HB + (size_t)c*2048*E_, WBe+1048576,
                                        2048, 2048, 512, 5, nullptr,nullptr, nullptr, MXb);
    man_epi<8><<<2048,256,0,stream>>>(MXb, N3 + c*2048, YV+2052,
                                      F1B + (size_t)c*2048*FFN_, N4 + c*2048,
                                      nullptr, nullptr, nullptr, nullptr, 1);
  }
  gemm2<<<dim3(4,64),256,0,stream>>>(F1B, WBe+2097152, R_,512,2048, 5, nullptr,nullptr, nullptr, MXb);
  man_epi<2><<<R_,256,0,stream>>>(MXb, N4, YV+4101, nullptr, nullptr, nullptr, nullptr,
                                  X2, out + (size_t)R_*E_, 1|8);
}

// Round 4
// 537.402 us; speedup vs baseline: 6.6400x; 1.2487x over previous
//
#include <hip/hip_runtime.h>
#include <cstdint>
#include <cstddef>

#define S_ 512
#define B_ 16
#define H_ 8
#define D_ 64
#define E_ 512
#define FFN_ 2048
#define R_ (S_*B_)          // 8192 rows (s*B+b)
#define EPSF 1e-6f
#define PROJ_M 0.99999f     // 1 - 1e-5

typedef __attribute__((ext_vector_type(8))) short bf16x8;
typedef __attribute__((ext_vector_type(4))) float f32x4;
typedef __attribute__((ext_vector_type(2))) unsigned int u32x2;

// ---------- helpers ----------
__device__ __forceinline__ float bf2f(uint32_t u){
  union{uint32_t i; float f;} c; c.i = u<<16; return c.f;
}
__device__ __forceinline__ uint16_t f2bf(float f){
  union{float f; uint32_t i;} c; c.f = f;
  return (uint16_t)((c.i + 0x7FFFu + ((c.i>>16)&1u))>>16);
}
__device__ __forceinline__ void unpack8(uint4 u, float* f){
  f[0]=bf2f(u.x&0xFFFFu); f[1]=bf2f(u.x>>16);
  f[2]=bf2f(u.y&0xFFFFu); f[3]=bf2f(u.y>>16);
  f[4]=bf2f(u.z&0xFFFFu); f[5]=bf2f(u.z>>16);
  f[6]=bf2f(u.w&0xFFFFu); f[7]=bf2f(u.w>>16);
}
__device__ __forceinline__ uint4 pack8(const float* f){
  uint4 u;
  u.x = (uint32_t)f2bf(f[0]) | ((uint32_t)f2bf(f[1])<<16);
  u.y = (uint32_t)f2bf(f[2]) | ((uint32_t)f2bf(f[3])<<16);
  u.z = (uint32_t)f2bf(f[4]) | ((uint32_t)f2bf(f[5])<<16);
  u.w = (uint32_t)f2bf(f[6]) | ((uint32_t)f2bf(f[7])<<16);
  return u;
}
__device__ __forceinline__ float artanh_c(float x){
  return (x >= 0.99999994f) ? 8.4056215f : atanhf(x);
}
__device__ __forceinline__ float wave_sum(float x){
  #pragma unroll
  for(int o=32;o>=1;o>>=1) x += __shfl_xor(x,o);
  return x;
}
__device__ __forceinline__ float halfsum32(float x){
  #pragma unroll
  for(int o=16;o>=1;o>>=1) x += __shfl_xor(x,o);
  return x;
}
__device__ __forceinline__ float block_sum(float x, float* sb){
  x = wave_sum(x);
  const int w = threadIdx.x >> 6;
  __syncthreads();
  if((threadIdx.x & 63)==0) sb[w] = x;
  __syncthreads();
  return sb[0]+sb[1]+sb[2]+sb[3];
}
// async global->LDS, 16B per lane; LDS dest = wave-uniform base + lane*16
__device__ __forceinline__ void gl_lds16(const void* g, void* l){
  __builtin_amdgcn_global_load_lds(
    (const __attribute__((address_space(1))) void*)(uintptr_t)g,
    (__attribute__((address_space(3))) void*)(uint32_t)(uintptr_t)l, 16, 0, 0);
}
__device__ __forceinline__ uint32_t cvtpk(float a, float b){
  uint32_t r;
  asm("v_cvt_pk_bf16_f32 %0, %1, %2" : "=v"(r) : "v"(a), "v"(b));
  return r;
}
template<int OFF>
__device__ __forceinline__ u32x2 trrd(uint32_t addr){
  u32x2 r;
  asm volatile("ds_read_b64_tr_b16 %0, %1 offset:%2" : "=v"(r) : "v"(addr), "n"(OFF));
  return r;
}
__device__ __forceinline__ bf16x8 vcomb(u32x2 a, u32x2 b){
  union{ uint32_t u[4]; bf16x8 v; } c;
  c.u[0]=a[0]; c.u[1]=a[1]; c.u[2]=b[0]; c.u[3]=b[1];
  return c.v;
}

// ---------- all weights fp32 -> bf16 (both experts), one launch ----------
__global__ __launch_bounds__(256) void cvt_all(
  const float* __restrict__ Wq, const float* __restrict__ Wk,
  const float* __restrict__ Wv, const float* __restrict__ Wo,
  const float* __restrict__ W1, const float* __restrict__ W2,
  uint16_t* __restrict__ dst)
{
  int i4 = blockIdx.x*256 + threadIdx.x;   // 4-elem units, total 1572864
  int e = 0;
  if(i4 >= 786432){ e = 1; i4 -= 786432; }
  const int r = i4;
  const float* s;
  if(r < 65536)        s = Wq + (size_t)(r)*4        + (size_t)e*262144;
  else if(r < 131072)  s = Wk + (size_t)(r-65536)*4  + (size_t)e*262144;
  else if(r < 196608)  s = Wv + (size_t)(r-131072)*4 + (size_t)e*262144;
  else if(r < 262144)  s = Wo + (size_t)(r-196608)*4 + (size_t)e*262144;
  else if(r < 524288)  s = W1 + (size_t)(r-262144)*4 + (size_t)e*1048576;
  else                 s = W2 + (size_t)(r-524288)*4 + (size_t)e*1048576;
  const float4 f = *(const float4*)s;
  uint2 o;
  o.x = (uint32_t)f2bf(f.x) | ((uint32_t)f2bf(f.y)<<16);
  o.y = (uint32_t)f2bf(f.z) | ((uint32_t)f2bf(f.w)<<16);
  *(uint2*)(dst + (size_t)e*3145728 + (size_t)r*4) = o;
}

// ---------- expmap0 of all 6 expert-1 biases ----------
__global__ __launch_bounds__(256) void expmap_all(
  const float* __restrict__ bq, const float* __restrict__ bk,
  const float* __restrict__ bv, const float* __restrict__ bo,
  const float* __restrict__ b1, const float* __restrict__ b2,
  float* __restrict__ YV)
{
  __shared__ float sb[4];
  const int id = blockIdx.x, t = threadIdx.x;
  const float* src; float* dst; int C;
  if(id==0){ src=bq+E_;   dst=YV+0;    C=E_; }
  else if(id==1){ src=bk+E_;   dst=YV+513;  C=E_; }
  else if(id==2){ src=bv+E_;   dst=YV+1026; C=E_; }
  else if(id==3){ src=bo+E_;   dst=YV+1539; C=E_; }
  else if(id==4){ src=b1+FFN_; dst=YV+2052; C=FFN_; }
  else          { src=b2+E_;   dst=YV+4101; C=E_; }
  const int npc = C >> 8;
  float v[8]; float s2 = 0.f;
  for(int i=0;i<npc;i++){ v[i] = src[t+256*i]; s2 += v[i]*v[i]; }
  s2 = block_sum(s2, sb);
  const float n = sqrtf(s2 + 1e-15f);
  const float th = tanhf(n);
  const float sc = th/n;
  for(int i=0;i<npc;i++) dst[t+256*i] = v[i]*sc;
  if(t==0) dst[C] = th*th;
}

// ---------- plain layernorm (euclid), row=512, fp32 in -> bf16 ----------
__global__ __launch_bounds__(256) void ln_k(const float* __restrict__ x,
  const float* __restrict__ g, const float* __restrict__ b, uint16_t* __restrict__ out)
{
  __shared__ float sb[4];
  const int row = blockIdx.x, t = threadIdx.x;
  const size_t base = (size_t)row*E_;
  float v0 = x[base+t], v1 = x[base+t+256];
  const float mu  = block_sum(v0+v1, sb) * (1.f/E_);
  const float d0 = v0-mu, d1 = v1-mu;
  const float var = block_sum(d0*d0+d1*d1, sb) * (1.f/E_);
  const float rs = 1.f/sqrtf(var + 1e-5f);
  out[base+t]     = f2bf(d0*rs*g[t] + b[t]);
  out[base+t+256] = f2bf(d1*rs*g[t+256] + b[t+256]);
}

// ---------- hyp: expmap0(LN(x)) [+projx]  (logmap0 scale cancels in LN) ----------
__global__ __launch_bounds__(256) void hyp_lnexp(const float* __restrict__ x,
  const float* __restrict__ g, const float* __restrict__ b,
  uint16_t* __restrict__ out, float* __restrict__ nout, int do_projx)
{
  __shared__ float sb[4];
  const int row = blockIdx.x, t = threadIdx.x;
  const size_t base = (size_t)row*E_;
  float v0 = x[base+t], v1 = x[base+t+256];
  const float mu  = block_sum(v0+v1, sb) * (1.f/E_);
  const float d0 = v0-mu, d1 = v1-mu;
  const float var = block_sum(d0*d0+d1*d1, sb) * (1.f/E_);
  const float rs = 1.f/sqrtf(var + 1e-5f);
  float t0 = d0*rs*g[t] + b[t];
  float t1 = d1*rs*g[t+256] + b[t+256];
  const float n2s = block_sum(t0*t0+t1*t1, sb);
  const float n2 = sqrtf(n2s + 1e-15f);
  const float nh = tanhf(n2);
  const float scl = nh/n2;
  t0 *= scl; t1 *= scl;
  float nrm = nh;
  if(do_projx && nrm > PROJ_M){ const float s = PROJ_M/nrm; t0*=s; t1*=s; nrm = PROJ_M; }
  out[base+t] = f2bf(t0); out[base+t+256] = f2bf(t1);
  if(t==0) nout[row] = nrm;
}

// ---------- per-head squared norms of euclid Q,K (layout [b*8+h][s]) ----------
__global__ __launch_bounds__(256) void qk_norms(
  const uint16_t* __restrict__ Qb, const uint16_t* __restrict__ Kb,
  float* __restrict__ qn, float* __restrict__ kn)
{
  const int w = threadIdx.x >> 6, l = threadIdx.x & 63;
  const int row = blockIdx.x*4 + w;
  const int s = row >> 4, b = row & 15;
  const size_t base = (size_t)row*E_ + l*8;
  {
    uint4 u = *(const uint4*)(Qb + base);
    float f[8]; unpack8(u, f);
    float ss = 0.f;
    #pragma unroll
    for(int i=0;i<8;i++) ss += f[i]*f[i];
    ss += __shfl_xor(ss,1); ss += __shfl_xor(ss,2); ss += __shfl_xor(ss,4);
    if((l&7)==0) qn[((b<<3) + (l>>3))*512 + s] = ss;
  }
  {
    uint4 u = *(const uint4*)(Kb + base);
    float f[8]; unpack8(u, f);
    float ss = 0.f;
    #pragma unroll
    for(int i=0;i<8;i++) ss += f[i]*f[i];
    ss += __shfl_xor(ss,1); ss += __shfl_xor(ss,2); ss += __shfl_xor(ss,4);
    if((l&7)==0) kn[((b<<3) + (l>>3))*512 + s] = ss;
  }
}

// ---------- man_linear epilogue (generic): flags 1 relu; 8 projx on midpoint ----------
template<int NPC>
__global__ __launch_bounds__(256) void man_epi(
  const uint16_t* __restrict__ mxb, const float* __restrict__ nxbuf,
  const float* __restrict__ y, uint16_t* __restrict__ outb,
  float* __restrict__ nout,
  const float* __restrict__ midres, float* __restrict__ midout, int flags)
{
  constexpr int C = NPC*256;
  __shared__ float sb[4];
  const int row = blockIdx.x, t = threadIdx.x;
  const size_t base = (size_t)row*C + (size_t)t*NPC;
  float v[NPC], yv[NPC];
  if(NPC==2){
    const uint32_t u = *(const uint32_t*)(mxb + base);
    v[0] = bf2f(u & 0xFFFFu); v[1] = bf2f(u >> 16);
  } else {
    const uint4 u = *(const uint4*)(mxb + base);
    unpack8(u, v);
  }
  float s2 = 0.f;
  #pragma unroll
  for(int i=0;i<NPC;i++){ yv[i] = y[t*NPC + i]; s2 += v[i]*v[i]; }
  s2 = block_sum(s2, sb);
  const float nmx = sqrtf(s2 + 1e-15f);
  const float nx  = nxbuf[row];
  const float sc  = tanhf(nmx/nx * artanh_c(nx));
  const bool ok   = (nmx > 1e-7f);
  const float fmul = ok ? (sc/nmx) : 0.f;
  const float x2   = ok ? sc*sc : 0.f;
  float xy = 0.f;
  #pragma unroll
  for(int i=0;i<NPC;i++){ v[i] *= fmul; xy += v[i]*yv[i]; }
  xy = block_sum(xy, sb);
  const float y2 = y[C];
  const float aa = 1.f + 2.f*xy + y2;
  const float bb = 1.f - x2;
  const float iden = 1.f/fmaxf(1.f + 2.f*xy + x2*y2, EPSF);
  const float num2 = aa*aa*x2 + 2.f*aa*bb*xy + bb*bb*y2;
  const float nz = sqrtf(num2*iden*iden + 1e-15f);
  const float ps = (nz > PROJ_M) ? (PROJ_M/nz) : 1.f;
  float nfin = (nz > PROJ_M) ? PROJ_M : nz;
  #pragma unroll
  for(int i=0;i<NPC;i++) v[i] = (aa*v[i] + bb*yv[i]) * iden * ps;
  if(flags & 1){
    float rs = 0.f;
    #pragma unroll
    for(int i=0;i<NPC;i++){ v[i] = fmaxf(v[i], 0.f); rs += v[i]*v[i]; }
    rs = block_sum(rs, sb);
    nfin = sqrtf(rs + 1e-15f);
  }
  if(midres){
    float bv2[NPC];
    float pb = 0.f, pab = 0.f;
    #pragma unroll
    for(int i=0;i<NPC;i++){ bv2[i] = midres[base + i]; pb += bv2[i]*bv2[i]; pab += v[i]*bv2[i]; }
    const float sa  = nfin*nfin;
    const float sbb = block_sum(pb, sb);
    const float sab = block_sum(pab, sb);
    const float l1 = 2.f/fmaxf(1.f - sa,  EPSF);
    const float l2 = 2.f/fmaxf(1.f - sbb, EPSF);
    const float idn = 1.f/fmaxf(l1 + l2 - 2.f, EPSF);
    const float nt2 = (l1*l1*sa + 2.f*l1*l2*sab + l2*l2*sbb)*idn*idn;
    const float nt = sqrtf(nt2 + 1e-15f);
    const float sfin = tanhf(0.5f*artanh_c(nt));
    float scm = sfin/nt;
    if((flags & 8) && sfin > PROJ_M) scm *= PROJ_M/sfin;
    #pragma unroll
    for(int i=0;i<NPC;i++) midout[base + i] = (v[i]*l1 + bv2[i]*l2)*idn*scm;
  } else {
    if(NPC==2){
      uint32_t u = (uint32_t)f2bf(v[0]) | ((uint32_t)f2bf(v[1])<<16);
      *(uint32_t*)(outb + base) = u;
    } else {
      *(uint4*)(outb + base) = pack8(v);
    }
    if(nout && t==0) nout[row] = nfin;
  }
}

// ---------- fused hyp q/k/v man_linear epilogue: per-head projx, lam fold for v ----------
__global__ __launch_bounds__(256) void man_epi_qkv(
  const uint16_t* __restrict__ mxb, const float* __restrict__ nxbuf,
  const float* __restrict__ YV, uint16_t* __restrict__ qkv,
  float* __restrict__ qnG, float* __restrict__ knG, float* __restrict__ lamG)
{
  __shared__ float sb[4];
  const int sel = blockIdx.y;
  const int row = blockIdx.x, t = threadIdx.x;
  const float* y = YV + sel*513;
  float v[2], yv[2];
  {
    const uint32_t u = *(const uint32_t*)(mxb + (size_t)row*1536 + sel*512 + t*2);
    v[0] = bf2f(u & 0xFFFFu); v[1] = bf2f(u >> 16);
  }
  float s2 = 0.f;
  #pragma unroll
  for(int i=0;i<2;i++){ yv[i] = y[t*2 + i]; s2 += v[i]*v[i]; }
  s2 = block_sum(s2, sb);
  const float nmx = sqrtf(s2 + 1e-15f);
  const float nx  = nxbuf[row];
  const float sc  = tanhf(nmx/nx * artanh_c(nx));
  const bool ok   = (nmx > 1e-7f);
  const float fmul = ok ? (sc/nmx) : 0.f;
  const float x2   = ok ? sc*sc : 0.f;
  float xy = 0.f;
  #pragma unroll
  for(int i=0;i<2;i++){ v[i] *= fmul; xy += v[i]*yv[i]; }
  xy = block_sum(xy, sb);
  const float y2 = y[512];
  const float aa = 1.f + 2.f*xy + y2;
  const float bb = 1.f - x2;
  const float iden = 1.f/fmaxf(1.f + 2.f*xy + x2*y2, EPSF);
  const float num2 = aa*aa*x2 + 2.f*aa*bb*xy + bb*bb*y2;
  const float nz = sqrtf(num2*iden*iden + 1e-15f);
  const float ps = (nz > PROJ_M) ? (PROJ_M/nz) : 1.f;
  #pragma unroll
  for(int i=0;i<2;i++) v[i] = (aa*v[i] + bb*yv[i]) * iden * ps;
  // per-head projx (+ lambda)
  float hs = halfsum32(v[0]*v[0] + v[1]*v[1]);
  float nh = sqrtf(hs + 1e-15f);
  float phs = 1.f;
  if(nh > PROJ_M){ phs = PROJ_M/nh; nh = PROJ_M; }
  v[0] *= phs; v[1] *= phs;
  const float nh2 = nh*nh;
  const float lam = 2.f/fmaxf(1.f - nh2, EPSF);
  if(sel==2){ v[0] *= lam; v[1] *= lam; }
  if((t & 31) == 0){
    const int s = row >> 4, b = row & 15;
    const int idx = ((b<<3) + (t>>5))*512 + s;
    if(sel==0) qnG[idx] = nh2;
    else if(sel==1) knG[idx] = nh2;
    else lamG[idx] = lam;
  }
  uint32_t u = (uint32_t)f2bf(v[0]) | ((uint32_t)f2bf(v[1])<<16);
  *(uint32_t*)(qkv + (size_t)sel*4194304 + (size_t)row*512 + t*2) = u;
}

// ---------- hyp attention-output finish ----------
__global__ __launch_bounds__(256) void o_finish2(const uint16_t* __restrict__ op,
  uint16_t* __restrict__ outb, float* __restrict__ nout)
{
  __shared__ float sb[4];
  const int row = blockIdx.x, t = threadIdx.x;
  const size_t base = (size_t)row*E_ + t*2;
  const uint32_t u = *(const uint32_t*)(op + base);
  float v0 = bf2f(u & 0xFFFFu), v1 = bf2f(u >> 16);
  const float hs = halfsum32(v0*v0 + v1*v1);
  const float ns = sqrtf(hs + 1e-15f);
  const float tt = tanhf(0.5f*artanh_c(ns));
  float scv = tt/ns;
  float sn = tt;
  if(sn > PROJ_M){ scv *= PROJ_M/sn; sn = PROJ_M; }
  v0 *= scv; v1 *= scv;
  const float tot = block_sum(v0*v0 + v1*v1, sb);
  const float n = sqrtf(tot + 1e-15f);
  float nf = n;
  if(n > PROJ_M){ const float s = PROJ_M/n; v0 *= s; v1 *= s; nf = PROJ_M; }
  *(uint32_t*)(outb + base) = (uint32_t)f2bf(v0) | ((uint32_t)f2bf(v1)<<16);
  if(t==0) nout[row] = nf;
}

// ---------- bf16 MFMA GEMM: C = A[M,K] @ W[N,K]^T, 128x128 tile, BK=64, dbuf ----------
// mode: 0 raw->outf; 1 +bias->outb; 2 +bias+res->outf; 3 relu+bias->outb;
//       4 relu+bias+res->outf; 5 raw->outb; 6 QKV-split +bias->outb(QKV contig)
__global__ __launch_bounds__(256) void gemm2(
    const uint16_t* __restrict__ A, const uint16_t* __restrict__ Bw,
    int M, int N, int K, int mode,
    const float* __restrict__ bias, const float* __restrict__ biasK,
    const float* __restrict__ biasV, const float* __restrict__ res,
    float* __restrict__ outf, uint16_t* __restrict__ outb)
{
  __shared__ __align__(16) char AsB[2][16384];
  __shared__ __align__(16) char BsB[2][16384];
  const int tid = threadIdx.x;
  const int l = tid & 63, w = tid >> 6;
  const int wm = w >> 1, wn = w & 1;
  const int m0 = blockIdx.y*128, n0 = blockIdx.x*128;
  const int lr = l & 15, g = l >> 4;
  const int lr3 = l >> 3, lc = l & 7;
  const int c8s = lc ^ lr3;
  const int swq = (lr & 7) << 4;

  const uint16_t* aSrc = A  + (size_t)(m0 + lr3)*K + c8s*8;
  const uint16_t* bSrc = Bw + (size_t)(n0 + lr3)*K + c8s*8;

  f32x4 acc[4][4];
  #pragma unroll
  for(int i=0;i<4;i++)
    #pragma unroll
    for(int j=0;j<4;j++) acc[i][j] = (f32x4){0.f,0.f,0.f,0.f};

  const int nk = K >> 6;
  #pragma unroll
  for(int c=0;c<4;c++){
    const int ci = w*4 + c;
    gl_lds16(aSrc + (size_t)(ci*8)*K, AsB[0] + ci*1024);
    gl_lds16(bSrc + (size_t)(ci*8)*K, BsB[0] + ci*1024);
  }
  for(int ks=0; ks<nk; ks++){
    __syncthreads();
    if(ks+1 < nk){
      const int k0 = (ks+1) << 6;
      #pragma unroll
      for(int c=0;c<4;c++){
        const int ci = w*4 + c;
        gl_lds16(aSrc + (size_t)(ci*8)*K + k0, AsB[(ks+1)&1] + ci*1024);
        gl_lds16(bSrc + (size_t)(ci*8)*K + k0, BsB[(ks+1)&1] + ci*1024);
      }
    }
    const char* Ac = AsB[ks&1];
    const char* Bc = BsB[ks&1];
    #pragma unroll
    for(int h=0;h<2;h++){
      bf16x8 av[4], bv[4];
      #pragma unroll
      for(int i=0;i<4;i++){
        av[i] = *(const bf16x8*)(Ac + (wm*64 + i*16 + lr)*128 + ((((h*4+g)<<4)) ^ swq));
        bv[i] = *(const bf16x8*)(Bc + (wn*64 + i*16 + lr)*128 + ((((h*4+g)<<4)) ^ swq));
      }
      #pragma unroll
      for(int i=0;i<4;i++)
        #pragma unroll
        for(int j=0;j<4;j++)
          acc[i][j] = __builtin_amdgcn_mfma_f32_16x16x32_bf16(av[i], bv[j], acc[i][j], 0,0,0);
    }
  }
  const int orow = g*4;
  #pragma unroll
  for(int i=0;i<4;i++){
    #pragma unroll
    for(int j=0;j<4;j++){
      const int gn = n0 + wn*64 + j*16 + lr;
      float bval = 0.f;
      if(mode==1||mode==2||mode==3||mode==4) bval = bias[gn];
      else if(mode==6){
        const float* bp = (gn<512)? bias : ((gn<1024)? biasK : biasV);
        bval = bp[gn&511];
      }
      #pragma unroll
      for(int r=0;r<4;r++){
        const int gm = m0 + wm*64 + i*16 + orow + r;
        const float vv = acc[i][j][r];
        const size_t off = (size_t)gm*N + gn;
        if(mode==0){ outf[off] = vv; }
        else if(mode==1){ outb[off] = f2bf(vv + bval); }
        else if(mode==2){ outf[off] = vv + bval + res[off]; }
        else if(mode==3){ outb[off] = f2bf(fmaxf(vv + bval, 0.f)); }
        else if(mode==4){ outf[off] = fmaxf(vv + bval, 0.f) + res[off]; }
        else if(mode==5){ outb[off] = f2bf(vv); }
        else {
          outb[(size_t)(gn>>9)*4194304 + (size_t)gm*512 + (gn&511)] = f2bf(vv + bval);
        }
      }
    }
  }
}

// ---------- MFMA flash attention v3: direct-exp softmax, tr-read V, reg-P ----------
template<int HYP>
__global__ __launch_bounds__(256,2) void attn3(
  const uint16_t* __restrict__ Qb, const uint16_t* __restrict__ Kb,
  const uint16_t* __restrict__ Vb, const float* __restrict__ qnG,
  const float* __restrict__ knG, const float* __restrict__ lamG,
  uint16_t* __restrict__ outB)
{
  __shared__ __align__(16) char QsB[16384];     // 2 q-tiles [64][64] bf16 swz
  __shared__ __align__(16) char KsB[2][8192];   // dbuf K tile (epilogue overlay)
  __shared__ __align__(16) char VtB[2][8192];   // dbuf V, tr-subtiled [s/4][d/16][4][16]
  __shared__ float kkL[512];
  __shared__ float lamL[512];

  const int tid = threadIdx.x;
  const int l = tid & 63, w = tid >> 6;
  const int lr = l & 15, g = l >> 4;
  const int lr3 = l >> 3, lc = l & 7;
  const int c8s = lc ^ lr3;
  const int swq = (lr & 7) << 4;
  const int bh = blockIdx.y;
  const int q0 = blockIdx.x * 128;
  const size_t gstride = (size_t)B_*E_;
  const size_t gbase = (size_t)(bh>>3)*E_ + (size_t)(bh&7)*D_;

  // V-staging decode: chunk ci covers LDS elems [w*1024+ci*512+l*8, +8)
  int vs[2], vd[2];
  #pragma unroll
  for(int ci=0;ci<2;ci++){
    vs[ci] = (ci*8 + (l>>3))*4 + ((l>>1)&3);
    vd[ci] = w*16 + (l&1)*8;
  }

  // ---- prologue staging ----
  #pragma unroll
  for(int c=0;c<4;c++){
    const int ci = w*4 + c;
    gl_lds16(Qb + (size_t)(q0 + ci*8 + lr3)*gstride + gbase + c8s*8, QsB + ci*1024);
  }
  #pragma unroll
  for(int c=0;c<2;c++){
    const int ci = w*2 + c;
    gl_lds16(Kb + (size_t)(ci*8 + lr3)*gstride + gbase + c8s*8, KsB[0] + ci*1024);
    gl_lds16(Vb + (size_t)vs[c]*gstride + gbase + vd[c], VtB[0] + w*2048 + c*1024);
  }
  kkL[tid]       = knG[bh*512 + tid];
  kkL[tid + 256] = knG[bh*512 + 256 + tid];
  if(HYP){
    lamL[tid]       = lamG[bh*512 + tid];
    lamL[tid + 256] = lamG[bh*512 + 256 + tid];
  }
  __syncthreads();

  // hoist Q fragments + qq
  const int qrow = w*16 + lr;
  bf16x8 qf[2][2];
  qf[0][0] = *(const bf16x8*)(QsB +        qrow*128 + ((g<<4) ^ swq));
  qf[0][1] = *(const bf16x8*)(QsB +        qrow*128 + (((4+g)<<4) ^ swq));
  qf[1][0] = *(const bf16x8*)(QsB + 8192 + qrow*128 + ((g<<4) ^ swq));
  qf[1][1] = *(const bf16x8*)(QsB + 8192 + qrow*128 + (((4+g)<<4) ^ swq));
  float qq[2];
  qq[0] = qnG[bh*512 + q0 + qrow];
  qq[1] = qnG[bh*512 + q0 + 64 + qrow];

  f32x4 oa[2][4];
  #pragma unroll
  for(int qt=0;qt<2;qt++)
    #pragma unroll
    for(int m=0;m<4;m++) oa[qt][m] = (f32x4){0.f,0.f,0.f,0.f};
  float lrun[2] = {0.f, 0.f};
  float dnr[2]  = {0.f, 0.f};

  const uint32_t vaddr_base = (uint32_t)(uintptr_t)(&VtB[0][0]) + (uint32_t)(l*8);

  for(int kt=0; kt<8; kt++){
    if(kt < 7){
      #pragma unroll
      for(int c=0;c<2;c++){
        const int ci = w*2 + c;
        gl_lds16(Kb + (size_t)((kt+1)*64 + ci*8 + lr3)*gstride + gbase + c8s*8,
                 KsB[(kt+1)&1] + ci*1024);
        gl_lds16(Vb + (size_t)((kt+1)*64 + vs[c])*gstride + gbase + vd[c],
                 VtB[(kt+1)&1] + w*2048 + c*1024);
      }
    }
    const char* Kc = KsB[kt&1];
    const float* kkt = &kkL[kt*64];
    const float* lmt = &lamL[kt*64];

    // ---- scores S^T = K * Q^T, both q-tiles share K fragments ----
    f32x4 st[2][4];
    #pragma unroll
    for(int t=0;t<4;t++){
      const bf16x8 ka0 = *(const bf16x8*)(Kc + (t*16+lr)*128 + ((g<<4) ^ swq));
      const bf16x8 ka1 = *(const bf16x8*)(Kc + (t*16+lr)*128 + (((4+g)<<4) ^ swq));
      f32x4 c0 = (f32x4){0.f,0.f,0.f,0.f};
      f32x4 c1 = (f32x4){0.f,0.f,0.f,0.f};
      c0 = __builtin_amdgcn_mfma_f32_16x16x32_bf16(ka0, qf[0][0], c0, 0,0,0);
      c1 = __builtin_amdgcn_mfma_f32_16x16x32_bf16(ka0, qf[1][0], c1, 0,0,0);
      c0 = __builtin_amdgcn_mfma_f32_16x16x32_bf16(ka1, qf[0][1], c0, 0,0,0);
      c1 = __builtin_amdgcn_mfma_f32_16x16x32_bf16(ka1, qf[1][1], c1, 0,0,0);
      st[0][t] = c0; st[1][t] = c1;
    }

    // ---- transform: p = exp(score) directly (all scores <= 0) ----
    uint32_t pbw[2][8];
    #pragma unroll
    for(int qt=0; qt<2; qt++){
      const float q2 = qq[qt];
      float ls = 0.f, dl = 0.f;
      #pragma unroll
      for(int t=0;t<4;t++){
        const f32x4 kkv = *(const f32x4*)(kkt + t*16 + g*4);
        float p[4];
        #pragma unroll
        for(int r=0;r<4;r++){
          const float qk = st[qt][t][r], kk = kkv[r];
          const float a = q2 + kk;
          if(HYP){
            const float u = fmaxf(fmaf(-2.f, qk, a), 0.f);
            const float v = fmaxf(fmaf(q2, kk, fmaf(-2.f, qk, 1.f)), EPSF);
            const float wz = __builtin_amdgcn_sqrtf(u*v);
            const float den = (u + v) + 2.f*wz;
            float ratio = (v - u) * __builtin_amdgcn_rcpf(den);
            ratio = fmaxf(ratio, 5.9604645e-8f);   // = (1-MAXT)/(1+MAXT) -> p_min 0.125
            p[r] = __builtin_amdgcn_exp2f(0.125f * __builtin_amdgcn_logf(ratio));
          } else {
            const float d2 = fmaxf(fmaf(-2.f, qk, a), 0.f) + 1e-12f;
            p[r] = __builtin_amdgcn_exp2f(-0.18033688f * __builtin_amdgcn_sqrtf(d2));
          }
        }
        ls += (p[0]+p[1])+(p[2]+p[3]);
        if(HYP){
          const f32x4 lv = *(const f32x4*)(lmt + t*16 + g*4);
          dl += p[0]*(lv[0]-1.f) + p[1]*(lv[1]-1.f) + p[2]*(lv[2]-1.f) + p[3]*(lv[3]-1.f);
        }
        pbw[qt][t*2]   = cvtpk(p[0], p[1]);
        pbw[qt][t*2+1] = cvtpk(p[2], p[3]);
      }
      ls += __shfl_xor(ls,16); ls += __shfl_xor(ls,32);
      lrun[qt] += ls;
      if(HYP){
        dl += __shfl_xor(dl,16); dl += __shfl_xor(dl,32);
        dnr[qt] += dl;
      }
    }

    // ---- PV: O^T += V^T * P^T ; V via ds_read_b64_tr_b16, P from registers ----
    const uint32_t va_kt = vaddr_base + (uint32_t)((kt&1)*8192);
    {
      // chunk c=0 (k-slots 0..31)
      u32x2 r00=trrd<0>(va_kt),    r01=trrd<512>(va_kt);
      u32x2 r10=trrd<2048>(va_kt), r11=trrd<2560>(va_kt);
      u32x2 r20=trrd<4096>(va_kt), r21=trrd<4608>(va_kt);
      u32x2 r30=trrd<6144>(va_kt), r31=trrd<6656>(va_kt);
      asm volatile("s_waitcnt lgkmcnt(0)" ::: "memory");
      __builtin_amdgcn_sched_barrier(0);
      bf16x8 pb0, pb1;
      { union{uint32_t u[4]; bf16x8 v;} c;
        c.u[0]=pbw[0][0]; c.u[1]=pbw[0][1]; c.u[2]=pbw[0][2]; c.u[3]=pbw[0][3]; pb0=c.v; }
      { union{uint32_t u[4]; bf16x8 v;} c;
        c.u[0]=pbw[1][0]; c.u[1]=pbw[1][1]; c.u[2]=pbw[1][2]; c.u[3]=pbw[1][3]; pb1=c.v; }
      __builtin_amdgcn_s_setprio(1);
      bf16x8 va;
      va = vcomb(r00,r01);
      oa[0][0] = __builtin_amdgcn_mfma_f32_16x16x32_bf16(va, pb0, oa[0][0], 0,0,0);
      oa[1][0] = __builtin_amdgcn_mfma_f32_16x16x32_bf16(va, pb1, oa[1][0], 0,0,0);
      va = vcomb(r10,r11);
      oa[0][1] = __builtin_amdgcn_mfma_f32_16x16x32_bf16(va, pb0, oa[0][1], 0,0,0);
      oa[1][1] = __builtin_amdgcn_mfma_f32_16x16x32_bf16(va, pb1, oa[1][1], 0,0,0);
      va = vcomb(r20,r21);
      oa[0][2] = __builtin_amdgcn_mfma_f32_16x16x32_bf16(va, pb0, oa[0][2], 0,0,0);
      oa[1][2] = __builtin_amdgcn_mfma_f32_16x16x32_bf16(va, pb1, oa[1][2], 0,0,0);
      va = vcomb(r30,r31);
      oa[0][3] = __builtin_amdgcn_mfma_f32_16x16x32_bf16(va, pb0, oa[0][3], 0,0,0);
      oa[1][3] = __builtin_amdgcn_mfma_f32_16x16x32_bf16(va, pb1, oa[1][3], 0,0,0);
      __builtin_amdgcn_s_setprio(0);
    }
    {
      // chunk c=1 (k-slots 32..63)
      u32x2 r00=trrd<1024>(va_kt), r01=trrd<1536>(va_kt);
      u32x2 r10=trrd<3072>(va_kt), r11=trrd<3584>(va_kt);
      u32x2 r20=trrd<5120>(va_kt), r21=trrd<5632>(va_kt);
      u32x2 r30=trrd<7168>(va_kt), r31=trrd<7680>(va_kt);
      asm volatile("s_waitcnt lgkmcnt(0)" ::: "memory");
      __builtin_amdgcn_sched_barrier(0);
      bf16x8 pb0, pb1;
      { union{uint32_t u[4]; bf16x8 v;} c;
        c.u[0]=pbw[0][4]; c.u[1]=pbw[0][5]; c.u[2]=pbw[0][6]; c.u[3]=pbw[0][7]; pb0=c.v; }
      { union{uint32_t u[4]; bf16x8 v;} c;
        c.u[0]=pbw[1][4]; c.u[1]=pbw[1][5]; c.u[2]=pbw[1][6]; c.u[3]=pbw[1][7]; pb1=c.v; }
      __builtin_amdgcn_s_setprio(1);
      bf16x8 va;
      va = vcomb(r00,r01);
      oa[0][0] = __builtin_amdgcn_mfma_f32_16x16x32_bf16(va, pb0, oa[0][0], 0,0,0);
      oa[1][0] = __builtin_amdgcn_mfma_f32_16x16x32_bf16(va, pb1, oa[1][0], 0,0,0);
      va = vcomb(r10,r11);
      oa[0][1] = __builtin_amdgcn_mfma_f32_16x16x32_bf16(va, pb0, oa[0][1], 0,0,0);
      oa[1][1] = __builtin_amdgcn_mfma_f32_16x16x32_bf16(va, pb1, oa[1][1], 0,0,0);
      va = vcomb(r20,r21);
      oa[0][2] = __builtin_amdgcn_mfma_f32_16x16x32_bf16(va, pb0, oa[0][2], 0,0,0);
      oa[1][2] = __builtin_amdgcn_mfma_f32_16x16x32_bf16(va, pb1, oa[1][2], 0,0,0);
      va = vcomb(r30,r31);
      oa[0][3] = __builtin_amdgcn_mfma_f32_16x16x32_bf16(va, pb0, oa[0][3], 0,0,0);
      oa[1][3] = __builtin_amdgcn_mfma_f32_16x16x32_bf16(va, pb1, oa[1][3], 0,0,0);
      __builtin_amdgcn_s_setprio(0);
    }
    __syncthreads();   // one barrier per kt: staging drained, buffers swap
  }

  // ---- epilogue: restage via LDS overlay (on K dbuf), coalesced store ----
  char* OTB = (char*)KsB;
  #pragma unroll
  for(int qt=0; qt<2; qt++){
    float scale;
    {
      const float invl = 1.f/lrun[qt];
      if(HYP){
        const float dn = fmaxf(dnr[qt]*invl, EPSF);
        scale = invl/dn;
      } else scale = invl;
    }
    __syncthreads();
    #pragma unroll
    for(int m=0;m<4;m++){
      f32x4 vv;
      vv[0]=oa[qt][m][0]*scale; vv[1]=oa[qt][m][1]*scale;
      vv[2]=oa[qt][m][2]*scale; vv[3]=oa[qt][m][3]*scale;
      *(f32x4*)(OTB + w*4096 + lr*256 + ((m*64 + g*16) ^ ((lr&7)<<4))) = vv;
    }
    __syncthreads();
    {
      const int row = tid >> 2, cw = tid & 3;
      const int wsrc = row >> 4, ql = row & 15;
      float vals[16];
      #pragma unroll
      for(int ii=0;ii<4;ii++)
        *(f32x4*)&vals[ii*4] = *(const f32x4*)(OTB + wsrc*4096 + ql*256 + ((cw*64 + ii*16) ^ ((ql&7)<<4)));
      const size_t go = (size_t)(q0 + qt*64 + row)*gstride + gbase + cw*16;
      *(uint4*)(outB + go)     = pack8(vals);
      *(uint4*)(outB + go + 8) = pack8(vals+8);
    }
  }
}

// =====================================================================
extern "C" void kernel_launch(void* const* d_in, const int* in_sizes, int n_in,
                              void* d_out, int out_size, void* d_ws, size_t ws_size,
                              hipStream_t stream)
{
  (void)in_sizes; (void)n_in; (void)out_size; (void)ws_size;
  const float* x    = (const float*)d_in[0];
  const float* ln1g = (const float*)d_in[1];
  const float* ln1b = (const float*)d_in[2];
  const float* ln2g = (const float*)d_in[3];
  const float* ln2b = (const float*)d_in[4];
  const float* Wq = (const float*)d_in[5];
  const float* bq = (const float*)d_in[6];
  const float* Wk = (const float*)d_in[7];
  const float* bk = (const float*)d_in[8];
  const float* Wv = (const float*)d_in[9];
  const float* bv = (const float*)d_in[10];
  const float* Wo = (const float*)d_in[11];
  const float* bo = (const float*)d_in[12];
  const float* W1 = (const float*)d_in[13];
  const float* b1 = (const float*)d_in[14];
  const float* W2 = (const float*)d_in[15];
  const float* b2 = (const float*)d_in[16];
  float* out = (float*)d_out;

  char* ws = (char*)d_ws;
  uint16_t* MXb = (uint16_t*)(ws);                          // 24MB bf16 GEMM scratch
  float*    X2  = (float*)   (ws + ((size_t)24<<20));       // 16MB fp32
  uint16_t* HB  = (uint16_t*)(ws + ((size_t)40<<20));       // 8MB
  uint16_t* QB  = (uint16_t*)(ws + ((size_t)48<<20));       // 8MB (Q,K,V contiguous)
  uint16_t* KB  = (uint16_t*)(ws + ((size_t)56<<20));
  uint16_t* VB  = (uint16_t*)(ws + ((size_t)64<<20));
  uint16_t* OB  = (uint16_t*)(ws + ((size_t)72<<20));
  uint16_t* F1B = (uint16_t*)(ws + ((size_t)80<<20));       // 32MB
  uint16_t* WB  = (uint16_t*)(ws + ((size_t)112<<20));      // 12MB (both experts)
  float*    YV  = (float*)   (ws + ((size_t)124<<20));      // expmap'd biases
  float*    NH  = (float*)   (ws + ((size_t)124<<20) + (64<<10));
  float*    NO  = NH + R_;
  float*    N3  = NO + R_;
  float*    N4  = N3 + R_;
  float*    qnG = (float*)   (ws + ((size_t)125<<20));      // [128][512]
  float*    knG = qnG + 65536;
  float*    lamG= knG + 65536;

  // ---- weights + biases (both experts) ----
  cvt_all<<<6144,256,0,stream>>>(Wq,Wk,Wv,Wo,W1,W2, WB);
  expmap_all<<<6,256,0,stream>>>(bq,bk,bv,bo,b1,b2, YV);

  // ================= Expert 0: Euclidean =================
  ln_k<<<R_,256,0,stream>>>(x, ln1g, ln1b, HB);
  gemm2<<<dim3(12,64),256,0,stream>>>(HB, WB, R_,1536,512, 6, bq, bk, bv, nullptr, nullptr, QB);
  qk_norms<<<2048,256,0,stream>>>(QB, KB, qnG, knG);
  attn3<0><<<dim3(4,128),256,0,stream>>>(QB, KB, VB, qnG, knG, nullptr, OB);
  gemm2<<<dim3(4,64),256,0,stream>>>(OB, WB+786432, R_,512,512, 2, bo, nullptr,nullptr, x, X2, nullptr);
  ln_k<<<R_,256,0,stream>>>(X2, ln2g, ln2b, HB);
  gemm2<<<dim3(16,64),256,0,stream>>>(HB, WB+1048576, R_,2048,512, 3, b1, nullptr,nullptr, nullptr, nullptr, F1B);
  gemm2<<<dim3(4,64),256,0,stream>>>(F1B, WB+2097152, R_,512,2048, 4, b2, nullptr,nullptr, X2, out, nullptr);

  // ================= Expert 1: Hyperbolic =================
  const float* x1 = x + (size_t)R_*E_;
  uint16_t* WBe = WB + 3145728;
  hyp_lnexp<<<R_,256,0,stream>>>(x1, ln1g+E_, ln1b+E_, HB, NH, 0);
  gemm2<<<dim3(12,64),256,0,stream>>>(HB, WBe, R_,1536,512, 5, nullptr,nullptr,nullptr,nullptr, nullptr, MXb);
  man_epi_qkv<<<dim3(R_,3),256,0,stream>>>(MXb, NH, YV, QB, qnG, knG, lamG);
  attn3<1><<<dim3(4,128),256,0,stream>>>(QB, KB, VB, qnG, knG, lamG, OB);
  o_finish2<<<R_,256,0,stream>>>(OB, HB, NO);
  gemm2<<<dim3(4,64),256,0,stream>>>(HB, WBe+786432, R_,512,512, 5, nullptr,nullptr,nullptr,nullptr, nullptr, MXb);
  man_epi<2><<<R_,256,0,stream>>>(MXb, NO, YV+1539, nullptr, nullptr, x1, X2, 0);
  hyp_lnexp<<<R_,256,0,stream>>>(X2, ln2g+E_, ln2b+E_, HB, N3, 1);
  gemm2<<<dim3(16,64),256,0,stream>>>(HB, WBe+1048576, R_,2048,512, 5, nullptr,nullptr,nullptr,nullptr, nullptr, F1B);
  man_epi<8><<<R_,256,0,stream>>>(F1B, N3, YV+2052, F1B, N4, nullptr, nullptr, 1);
  gemm2<<<dim3(4,64),256,0,stream>>>(F1B, WBe+2097152, R_,512,2048, 5, nullptr,nullptr,nullptr,nullptr, nullptr, MXb);
  man_epi<2><<<R_,256,0,stream>>>(MXb, N4, YV+4101, nullptr, nullptr, X2, out + (size_t)R_*E_, 1|8);
}

// Round 5
// 536.907 us; speedup vs baseline: 6.6461x; 1.0009x over previous
//
#include <hip/hip_runtime.h>
#include <cstdint>
#include <cstddef>

#define S_ 512
#define B_ 16
#define H_ 8
#define D_ 64
#define E_ 512
#define FFN_ 2048
#define R_ (S_*B_)          // 8192 rows (s*B+b)
#define EPSF 1e-6f
#define PROJ_M 0.99999f     // 1 - 1e-5

typedef __attribute__((ext_vector_type(8))) short bf16x8;
typedef __attribute__((ext_vector_type(4))) float f32x4;
typedef __attribute__((ext_vector_type(2))) unsigned int u32x2;

// ---------- helpers ----------
__device__ __forceinline__ float bf2f(uint32_t u){
  union{uint32_t i; float f;} c; c.i = u<<16; return c.f;
}
__device__ __forceinline__ uint16_t f2bf(float f){
  union{float f; uint32_t i;} c; c.f = f;
  return (uint16_t)((c.i + 0x7FFFu + ((c.i>>16)&1u))>>16);
}
__device__ __forceinline__ void unpack8(uint4 u, float* f){
  f[0]=bf2f(u.x&0xFFFFu); f[1]=bf2f(u.x>>16);
  f[2]=bf2f(u.y&0xFFFFu); f[3]=bf2f(u.y>>16);
  f[4]=bf2f(u.z&0xFFFFu); f[5]=bf2f(u.z>>16);
  f[6]=bf2f(u.w&0xFFFFu); f[7]=bf2f(u.w>>16);
}
__device__ __forceinline__ uint4 pack8(const float* f){
  uint4 u;
  u.x = (uint32_t)f2bf(f[0]) | ((uint32_t)f2bf(f[1])<<16);
  u.y = (uint32_t)f2bf(f[2]) | ((uint32_t)f2bf(f[3])<<16);
  u.z = (uint32_t)f2bf(f[4]) | ((uint32_t)f2bf(f[5])<<16);
  u.w = (uint32_t)f2bf(f[6]) | ((uint32_t)f2bf(f[7])<<16);
  return u;
}
__device__ __forceinline__ float artanh_c(float x){
  return (x >= 0.99999994f) ? 8.4056215f : atanhf(x);
}
__device__ __forceinline__ float wave_sum(float x){
  #pragma unroll
  for(int o=32;o>=1;o>>=1) x += __shfl_xor(x,o);
  return x;
}
__device__ __forceinline__ float halfsum32(float x){
  #pragma unroll
  for(int o=16;o>=1;o>>=1) x += __shfl_xor(x,o);
  return x;
}
__device__ __forceinline__ float block_sum(float x, float* sb){
  x = wave_sum(x);
  const int w = threadIdx.x >> 6;
  __syncthreads();
  if((threadIdx.x & 63)==0) sb[w] = x;
  __syncthreads();
  return sb[0]+sb[1]+sb[2]+sb[3];
}
// async global->LDS, 16B per lane; LDS dest = wave-uniform base + lane*16
__device__ __forceinline__ void gl_lds16(const void* g, void* l){
  __builtin_amdgcn_global_load_lds(
    (const __attribute__((address_space(1))) void*)(uintptr_t)g,
    (__attribute__((address_space(3))) void*)(uint32_t)(uintptr_t)l, 16, 0, 0);
}
__device__ __forceinline__ uint32_t cvtpk(float a, float b){
  uint32_t r;
  asm("v_cvt_pk_bf16_f32 %0, %1, %2" : "=v"(r) : "v"(a), "v"(b));
  return r;
}
template<int OFF>
__device__ __forceinline__ u32x2 trrd(uint32_t addr){
  u32x2 r;
  asm volatile("ds_read_b64_tr_b16 %0, %1 offset:%2" : "=v"(r) : "v"(addr), "n"(OFF));
  return r;
}
__device__ __forceinline__ bf16x8 vcomb(u32x2 a, u32x2 b){
  union{ uint32_t u[4]; bf16x8 v; } c;
  c.u[0]=a[0]; c.u[1]=a[1]; c.u[2]=b[0]; c.u[3]=b[1];
  return c.v;
}

// ---------- all weights fp32 -> bf16 (both experts), one launch ----------
__global__ __launch_bounds__(256) void cvt_all(
  const float* __restrict__ Wq, const float* __restrict__ Wk,
  const float* __restrict__ Wv, const float* __restrict__ Wo,
  const float* __restrict__ W1, const float* __restrict__ W2,
  uint16_t* __restrict__ dst)
{
  int i4 = blockIdx.x*256 + threadIdx.x;   // 4-elem units, total 1572864
  int e = 0;
  if(i4 >= 786432){ e = 1; i4 -= 786432; }
  const int r = i4;
  const float* s;
  if(r < 65536)        s = Wq + (size_t)(r)*4        + (size_t)e*262144;
  else if(r < 131072)  s = Wk + (size_t)(r-65536)*4  + (size_t)e*262144;
  else if(r < 196608)  s = Wv + (size_t)(r-131072)*4 + (size_t)e*262144;
  else if(r < 262144)  s = Wo + (size_t)(r-196608)*4 + (size_t)e*262144;
  else if(r < 524288)  s = W1 + (size_t)(r-262144)*4 + (size_t)e*1048576;
  else                 s = W2 + (size_t)(r-524288)*4 + (size_t)e*1048576;
  const float4 f = *(const float4*)s;
  uint2 o;
  o.x = (uint32_t)f2bf(f.x) | ((uint32_t)f2bf(f.y)<<16);
  o.y = (uint32_t)f2bf(f.z) | ((uint32_t)f2bf(f.w)<<16);
  *(uint2*)(dst + (size_t)e*3145728 + (size_t)r*4) = o;
}

// ---------- expmap0 of all 6 expert-1 biases ----------
__global__ __launch_bounds__(256) void expmap_all(
  const float* __restrict__ bq, const float* __restrict__ bk,
  const float* __restrict__ bv, const float* __restrict__ bo,
  const float* __restrict__ b1, const float* __restrict__ b2,
  float* __restrict__ YV)
{
  __shared__ float sb[4];
  const int id = blockIdx.x, t = threadIdx.x;
  const float* src; float* dst; int C;
  if(id==0){ src=bq+E_;   dst=YV+0;    C=E_; }
  else if(id==1){ src=bk+E_;   dst=YV+513;  C=E_; }
  else if(id==2){ src=bv+E_;   dst=YV+1026; C=E_; }
  else if(id==3){ src=bo+E_;   dst=YV+1539; C=E_; }
  else if(id==4){ src=b1+FFN_; dst=YV+2052; C=FFN_; }
  else          { src=b2+E_;   dst=YV+4101; C=E_; }
  const int npc = C >> 8;
  float v[8]; float s2 = 0.f;
  for(int i=0;i<npc;i++){ v[i] = src[t+256*i]; s2 += v[i]*v[i]; }
  s2 = block_sum(s2, sb);
  const float n = sqrtf(s2 + 1e-15f);
  const float th = tanhf(n);
  const float sc = th/n;
  for(int i=0;i<npc;i++) dst[t+256*i] = v[i]*sc;
  if(t==0) dst[C] = th*th;
}

// ---------- plain layernorm (euclid), row=512, fp32 in -> bf16 ----------
__global__ __launch_bounds__(256) void ln_k(const float* __restrict__ x,
  const float* __restrict__ g, const float* __restrict__ b, uint16_t* __restrict__ out)
{
  __shared__ float sb[4];
  const int row = blockIdx.x, t = threadIdx.x;
  const size_t base = (size_t)row*E_;
  float v0 = x[base+t], v1 = x[base+t+256];
  const float mu  = block_sum(v0+v1, sb) * (1.f/E_);
  const float d0 = v0-mu, d1 = v1-mu;
  const float var = block_sum(d0*d0+d1*d1, sb) * (1.f/E_);
  const float rs = 1.f/sqrtf(var + 1e-5f);
  out[base+t]     = f2bf(d0*rs*g[t] + b[t]);
  out[base+t+256] = f2bf(d1*rs*g[t+256] + b[t+256]);
}

// ---------- hyp: expmap0(LN(x)) [+projx]  (logmap0 scale cancels in LN) ----------
__global__ __launch_bounds__(256) void hyp_lnexp(const float* __restrict__ x,
  const float* __restrict__ g, const float* __restrict__ b,
  uint16_t* __restrict__ out, float* __restrict__ nout, int do_projx)
{
  __shared__ float sb[4];
  const int row = blockIdx.x, t = threadIdx.x;
  const size_t base = (size_t)row*E_;
  float v0 = x[base+t], v1 = x[base+t+256];
  const float mu  = block_sum(v0+v1, sb) * (1.f/E_);
  const float d0 = v0-mu, d1 = v1-mu;
  const float var = block_sum(d0*d0+d1*d1, sb) * (1.f/E_);
  const float rs = 1.f/sqrtf(var + 1e-5f);
  float t0 = d0*rs*g[t] + b[t];
  float t1 = d1*rs*g[t+256] + b[t+256];
  const float n2s = block_sum(t0*t0+t1*t1, sb);
  const float n2 = sqrtf(n2s + 1e-15f);
  const float nh = tanhf(n2);
  const float scl = nh/n2;
  t0 *= scl; t1 *= scl;
  float nrm = nh;
  if(do_projx && nrm > PROJ_M){ const float s = PROJ_M/nrm; t0*=s; t1*=s; nrm = PROJ_M; }
  out[base+t] = f2bf(t0); out[base+t+256] = f2bf(t1);
  if(t==0) nout[row] = nrm;
}

// ---------- per-head squared norms of euclid Q,K (layout [b*8+h][s]) ----------
__global__ __launch_bounds__(256) void qk_norms(
  const uint16_t* __restrict__ Qb, const uint16_t* __restrict__ Kb,
  float* __restrict__ qn, float* __restrict__ kn)
{
  const int w = threadIdx.x >> 6, l = threadIdx.x & 63;
  const int row = blockIdx.x*4 + w;
  const int s = row >> 4, b = row & 15;
  const size_t base = (size_t)row*E_ + l*8;
  {
    uint4 u = *(const uint4*)(Qb + base);
    float f[8]; unpack8(u, f);
    float ss = 0.f;
    #pragma unroll
    for(int i=0;i<8;i++) ss += f[i]*f[i];
    ss += __shfl_xor(ss,1); ss += __shfl_xor(ss,2); ss += __shfl_xor(ss,4);
    if((l&7)==0) qn[((b<<3) + (l>>3))*512 + s] = ss;
  }
  {
    uint4 u = *(const uint4*)(Kb + base);
    float f[8]; unpack8(u, f);
    float ss = 0.f;
    #pragma unroll
    for(int i=0;i<8;i++) ss += f[i]*f[i];
    ss += __shfl_xor(ss,1); ss += __shfl_xor(ss,2); ss += __shfl_xor(ss,4);
    if((l&7)==0) kn[((b<<3) + (l>>3))*512 + s] = ss;
  }
}

// ---------- man_linear epilogue (generic): flags 1 relu; 8 projx on midpoint ----------
template<int NPC>
__global__ __launch_bounds__(256) void man_epi(
  const uint16_t* __restrict__ mxb, const float* __restrict__ nxbuf,
  const float* __restrict__ y, uint16_t* __restrict__ outb,
  float* __restrict__ nout,
  const float* __restrict__ midres, float* __restrict__ midout, int flags)
{
  constexpr int C = NPC*256;
  __shared__ float sb[4];
  const int row = blockIdx.x, t = threadIdx.x;
  const size_t base = (size_t)row*C + (size_t)t*NPC;
  float v[NPC], yv[NPC];
  if(NPC==2){
    const uint32_t u = *(const uint32_t*)(mxb + base);
    v[0] = bf2f(u & 0xFFFFu); v[1] = bf2f(u >> 16);
  } else {
    const uint4 u = *(const uint4*)(mxb + base);
    unpack8(u, v);
  }
  float s2 = 0.f;
  #pragma unroll
  for(int i=0;i<NPC;i++){ yv[i] = y[t*NPC + i]; s2 += v[i]*v[i]; }
  s2 = block_sum(s2, sb);
  const float nmx = sqrtf(s2 + 1e-15f);
  const float nx  = nxbuf[row];
  const float sc  = tanhf(nmx/nx * artanh_c(nx));
  const bool ok   = (nmx > 1e-7f);
  const float fmul = ok ? (sc/nmx) : 0.f;
  const float x2   = ok ? sc*sc : 0.f;
  float xy = 0.f;
  #pragma unroll
  for(int i=0;i<NPC;i++){ v[i] *= fmul; xy += v[i]*yv[i]; }
  xy = block_sum(xy, sb);
  const float y2 = y[C];
  const float aa = 1.f + 2.f*xy + y2;
  const float bb = 1.f - x2;
  const float iden = 1.f/fmaxf(1.f + 2.f*xy + x2*y2, EPSF);
  const float num2 = aa*aa*x2 + 2.f*aa*bb*xy + bb*bb*y2;
  const float nz = sqrtf(num2*iden*iden + 1e-15f);
  const float ps = (nz > PROJ_M) ? (PROJ_M/nz) : 1.f;
  float nfin = (nz > PROJ_M) ? PROJ_M : nz;
  #pragma unroll
  for(int i=0;i<NPC;i++) v[i] = (aa*v[i] + bb*yv[i]) * iden * ps;
  if(flags & 1){
    float rs = 0.f;
    #pragma unroll
    for(int i=0;i<NPC;i++){ v[i] = fmaxf(v[i], 0.f); rs += v[i]*v[i]; }
    rs = block_sum(rs, sb);
    nfin = sqrtf(rs + 1e-15f);
  }
  if(midres){
    float bv2[NPC];
    float pb = 0.f, pab = 0.f;
    #pragma unroll
    for(int i=0;i<NPC;i++){ bv2[i] = midres[base + i]; pb += bv2[i]*bv2[i]; pab += v[i]*bv2[i]; }
    const float sa  = nfin*nfin;
    const float sbb = block_sum(pb, sb);
    const float sab = block_sum(pab, sb);
    const float l1 = 2.f/fmaxf(1.f - sa,  EPSF);
    const float l2 = 2.f/fmaxf(1.f - sbb, EPSF);
    const float idn = 1.f/fmaxf(l1 + l2 - 2.f, EPSF);
    const float nt2 = (l1*l1*sa + 2.f*l1*l2*sab + l2*l2*sbb)*idn*idn;
    const float nt = sqrtf(nt2 + 1e-15f);
    const float sfin = tanhf(0.5f*artanh_c(nt));
    float scm = sfin/nt;
    if((flags & 8) && sfin > PROJ_M) scm *= PROJ_M/sfin;
    #pragma unroll
    for(int i=0;i<NPC;i++) midout[base + i] = (v[i]*l1 + bv2[i]*l2)*idn*scm;
  } else {
    if(NPC==2){
      uint32_t u = (uint32_t)f2bf(v[0]) | ((uint32_t)f2bf(v[1])<<16);
      *(uint32_t*)(outb + base) = u;
    } else {
      *(uint4*)(outb + base) = pack8(v);
    }
    if(nout && t==0) nout[row] = nfin;
  }
}

// ---------- fused hyp q/k/v man_linear epilogue: per-head projx, lam fold for v ----------
__global__ __launch_bounds__(256) void man_epi_qkv(
  const uint16_t* __restrict__ mxb, const float* __restrict__ nxbuf,
  const float* __restrict__ YV, uint16_t* __restrict__ qkv,
  float* __restrict__ qnG, float* __restrict__ knG, float* __restrict__ lamG)
{
  __shared__ float sb[4];
  const int sel = blockIdx.y;
  const int row = blockIdx.x, t = threadIdx.x;
  const float* y = YV + sel*513;
  float v[2], yv[2];
  {
    const uint32_t u = *(const uint32_t*)(mxb + (size_t)row*1536 + sel*512 + t*2);
    v[0] = bf2f(u & 0xFFFFu); v[1] = bf2f(u >> 16);
  }
  float s2 = 0.f;
  #pragma unroll
  for(int i=0;i<2;i++){ yv[i] = y[t*2 + i]; s2 += v[i]*v[i]; }
  s2 = block_sum(s2, sb);
  const float nmx = sqrtf(s2 + 1e-15f);
  const float nx  = nxbuf[row];
  const float sc  = tanhf(nmx/nx * artanh_c(nx));
  const bool ok   = (nmx > 1e-7f);
  const float fmul = ok ? (sc/nmx) : 0.f;
  const float x2   = ok ? sc*sc : 0.f;
  float xy = 0.f;
  #pragma unroll
  for(int i=0;i<2;i++){ v[i] *= fmul; xy += v[i]*yv[i]; }
  xy = block_sum(xy, sb);
  const float y2 = y[512];
  const float aa = 1.f + 2.f*xy + y2;
  const float bb = 1.f - x2;
  const float iden = 1.f/fmaxf(1.f + 2.f*xy + x2*y2, EPSF);
  const float num2 = aa*aa*x2 + 2.f*aa*bb*xy + bb*bb*y2;
  const float nz = sqrtf(num2*iden*iden + 1e-15f);
  const float ps = (nz > PROJ_M) ? (PROJ_M/nz) : 1.f;
  #pragma unroll
  for(int i=0;i<2;i++) v[i] = (aa*v[i] + bb*yv[i]) * iden * ps;
  // per-head projx (+ lambda)
  float hs = halfsum32(v[0]*v[0] + v[1]*v[1]);
  float nh = sqrtf(hs + 1e-15f);
  float phs = 1.f;
  if(nh > PROJ_M){ phs = PROJ_M/nh; nh = PROJ_M; }
  v[0] *= phs; v[1] *= phs;
  const float nh2 = nh*nh;
  const float lam = 2.f/fmaxf(1.f - nh2, EPSF);
  if(sel==2){ v[0] *= lam; v[1] *= lam; }
  if((t & 31) == 0){
    const int s = row >> 4, b = row & 15;
    const int idx = ((b<<3) + (t>>5))*512 + s;
    if(sel==0) qnG[idx] = nh2;
    else if(sel==1) knG[idx] = nh2;
    else lamG[idx] = lam;
  }
  uint32_t u = (uint32_t)f2bf(v[0]) | ((uint32_t)f2bf(v[1])<<16);
  *(uint32_t*)(qkv + (size_t)sel*4194304 + (size_t)row*512 + t*2) = u;
}

// ---------- hyp attention-output finish ----------
__global__ __launch_bounds__(256) void o_finish2(const uint16_t* __restrict__ op,
  uint16_t* __restrict__ outb, float* __restrict__ nout)
{
  __shared__ float sb[4];
  const int row = blockIdx.x, t = threadIdx.x;
  const size_t base = (size_t)row*E_ + t*2;
  const uint32_t u = *(const uint32_t*)(op + base);
  float v0 = bf2f(u & 0xFFFFu), v1 = bf2f(u >> 16);
  const float hs = halfsum32(v0*v0 + v1*v1);
  const float ns = sqrtf(hs + 1e-15f);
  const float tt = tanhf(0.5f*artanh_c(ns));
  float scv = tt/ns;
  float sn = tt;
  if(sn > PROJ_M){ scv *= PROJ_M/sn; sn = PROJ_M; }
  v0 *= scv; v1 *= scv;
  const float tot = block_sum(v0*v0 + v1*v1, sb);
  const float n = sqrtf(tot + 1e-15f);
  float nf = n;
  if(n > PROJ_M){ const float s = PROJ_M/n; v0 *= s; v1 *= s; nf = PROJ_M; }
  *(uint32_t*)(outb + base) = (uint32_t)f2bf(v0) | ((uint32_t)f2bf(v1)<<16);
  if(t==0) nout[row] = nf;
}

// ---------- bf16 MFMA GEMM: C = A[M,K] @ W[N,K]^T, 128x128 tile, BK=64, dbuf ----------
// mode: 0 raw->outf; 1 +bias->outb; 2 +bias+res->outf; 3 relu+bias->outb;
//       4 relu+bias+res->outf; 5 raw->outb; 6 QKV-split +bias->outb(QKV contig)
__global__ __launch_bounds__(256) void gemm2(
    const uint16_t* __restrict__ A, const uint16_t* __restrict__ Bw,
    int M, int N, int K, int mode,
    const float* __restrict__ bias, const float* __restrict__ biasK,
    const float* __restrict__ biasV, const float* __restrict__ res,
    float* __restrict__ outf, uint16_t* __restrict__ outb)
{
  __shared__ __align__(16) char AsB[2][16384];
  __shared__ __align__(16) char BsB[2][16384];
  const int tid = threadIdx.x;
  const int l = tid & 63, w = tid >> 6;
  const int wm = w >> 1, wn = w & 1;
  const int m0 = blockIdx.y*128, n0 = blockIdx.x*128;
  const int lr = l & 15, g = l >> 4;
  const int lr3 = l >> 3, lc = l & 7;
  const int c8s = lc ^ lr3;
  const int swq = (lr & 7) << 4;

  const uint16_t* aSrc = A  + (size_t)(m0 + lr3)*K + c8s*8;
  const uint16_t* bSrc = Bw + (size_t)(n0 + lr3)*K + c8s*8;

  f32x4 acc[4][4];
  #pragma unroll
  for(int i=0;i<4;i++)
    #pragma unroll
    for(int j=0;j<4;j++) acc[i][j] = (f32x4){0.f,0.f,0.f,0.f};

  const int nk = K >> 6;
  #pragma unroll
  for(int c=0;c<4;c++){
    const int ci = w*4 + c;
    gl_lds16(aSrc + (size_t)(ci*8)*K, AsB[0] + ci*1024);
    gl_lds16(bSrc + (size_t)(ci*8)*K, BsB[0] + ci*1024);
  }
  for(int ks=0; ks<nk; ks++){
    __syncthreads();
    if(ks+1 < nk){
      const int k0 = (ks+1) << 6;
      #pragma unroll
      for(int c=0;c<4;c++){
        const int ci = w*4 + c;
        gl_lds16(aSrc + (size_t)(ci*8)*K + k0, AsB[(ks+1)&1] + ci*1024);
        gl_lds16(bSrc + (size_t)(ci*8)*K + k0, BsB[(ks+1)&1] + ci*1024);
      }
    }
    const char* Ac = AsB[ks&1];
    const char* Bc = BsB[ks&1];
    #pragma unroll
    for(int h=0;h<2;h++){
      bf16x8 av[4], bv[4];
      #pragma unroll
      for(int i=0;i<4;i++){
        av[i] = *(const bf16x8*)(Ac + (wm*64 + i*16 + lr)*128 + ((((h*4+g)<<4)) ^ swq));
        bv[i] = *(const bf16x8*)(Bc + (wn*64 + i*16 + lr)*128 + ((((h*4+g)<<4)) ^ swq));
      }
      #pragma unroll
      for(int i=0;i<4;i++)
        #pragma unroll
        for(int j=0;j<4;j++)
          acc[i][j] = __builtin_amdgcn_mfma_f32_16x16x32_bf16(av[i], bv[j], acc[i][j], 0,0,0);
    }
  }
  const int orow = g*4;
  #pragma unroll
  for(int i=0;i<4;i++){
    #pragma unroll
    for(int j=0;j<4;j++){
      const int gn = n0 + wn*64 + j*16 + lr;
      float bval = 0.f;
      if(mode==1||mode==2||mode==3||mode==4) bval = bias[gn];
      else if(mode==6){
        const float* bp = (gn<512)? bias : ((gn<1024)? biasK : biasV);
        bval = bp[gn&511];
      }
      #pragma unroll
      for(int r=0;r<4;r++){
        const int gm = m0 + wm*64 + i*16 + orow + r;
        const float vv = acc[i][j][r];
        const size_t off = (size_t)gm*N + gn;
        if(mode==0){ outf[off] = vv; }
        else if(mode==1){ outb[off] = f2bf(vv + bval); }
        else if(mode==2){ outf[off] = vv + bval + res[off]; }
        else if(mode==3){ outb[off] = f2bf(fmaxf(vv + bval, 0.f)); }
        else if(mode==4){ outf[off] = fmaxf(vv + bval, 0.f) + res[off]; }
        else if(mode==5){ outb[off] = f2bf(vv); }
        else {
          outb[(size_t)(gn>>9)*4194304 + (size_t)gm*512 + (gn&511)] = f2bf(vv + bval);
        }
      }
    }
  }
}

// ---------- MFMA flash attention v3: direct-exp softmax, tr-read V, reg-P ----------
template<int HYP>
__global__ __launch_bounds__(256,2) void attn3(
  const uint16_t* __restrict__ Qb, const uint16_t* __restrict__ Kb,
  const uint16_t* __restrict__ Vb, const float* __restrict__ qnG,
  const float* __restrict__ knG, const float* __restrict__ lamG,
  uint16_t* __restrict__ outB)
{
  __shared__ __align__(16) char QsB[16384];     // 2 q-tiles [64][64] bf16 swz
  __shared__ __align__(16) char KsB[2][8192];   // dbuf K tile (epilogue overlay)
  __shared__ __align__(16) char VtB[2][8192];   // dbuf V, tr-subtiled [s/4][d/16][4][16]
  __shared__ float kkL[512];
  __shared__ float lamL[512];

  const int tid = threadIdx.x;
  const int l = tid & 63, w = tid >> 6;
  const int lr = l & 15, g = l >> 4;
  const int lr3 = l >> 3, lc = l & 7;
  const int c8s = lc ^ lr3;
  const int swq = (lr & 7) << 4;
  const int bh = blockIdx.y;
  const int q0 = blockIdx.x * 128;
  const size_t gstride = (size_t)B_*E_;
  const size_t gbase = (size_t)(bh>>3)*E_ + (size_t)(bh&7)*D_;

  // V-staging decode: chunk ci covers LDS elems [w*1024+ci*512+l*8, +8)
  int vs[2], vd[2];
  #pragma unroll
  for(int ci=0;ci<2;ci++){
    vs[ci] = (ci*8 + (l>>3))*4 + ((l>>1)&3);
    vd[ci] = w*16 + (l&1)*8;
  }

  // ---- prologue staging ----
  #pragma unroll
  for(int c=0;c<4;c++){
    const int ci = w*4 + c;
    gl_lds16(Qb + (size_t)(q0 + ci*8 + lr3)*gstride + gbase + c8s*8, QsB + ci*1024);
  }
  #pragma unroll
  for(int c=0;c<2;c++){
    const int ci = w*2 + c;
    gl_lds16(Kb + (size_t)(ci*8 + lr3)*gstride + gbase + c8s*8, KsB[0] + ci*1024);
    gl_lds16(Vb + (size_t)vs[c]*gstride + gbase + vd[c], VtB[0] + w*2048 + c*1024);
  }
  kkL[tid]       = knG[bh*512 + tid];
  kkL[tid + 256] = knG[bh*512 + 256 + tid];
  if(HYP){
    lamL[tid]       = lamG[bh*512 + tid];
    lamL[tid + 256] = lamG[bh*512 + 256 + tid];
  }
  __syncthreads();

  // hoist Q fragments + qq
  const int qrow = w*16 + lr;
  bf16x8 qf[2][2];
  qf[0][0] = *(const bf16x8*)(QsB +        qrow*128 + ((g<<4) ^ swq));
  qf[0][1] = *(const bf16x8*)(QsB +        qrow*128 + (((4+g)<<4) ^ swq));
  qf[1][0] = *(const bf16x8*)(QsB + 8192 + qrow*128 + ((g<<4) ^ swq));
  qf[1][1] = *(const bf16x8*)(QsB + 8192 + qrow*128 + (((4+g)<<4) ^ swq));
  float qq[2];
  qq[0] = qnG[bh*512 + q0 + qrow];
  qq[1] = qnG[bh*512 + q0 + 64 + qrow];

  f32x4 oa[2][4];
  #pragma unroll
  for(int qt=0;qt<2;qt++)
    #pragma unroll
    for(int m=0;m<4;m++) oa[qt][m] = (f32x4){0.f,0.f,0.f,0.f};
  float lrun[2] = {0.f, 0.f};
  float dnr[2]  = {0.f, 0.f};

  const uint32_t vaddr_base = (uint32_t)(uintptr_t)(&VtB[0][0]) + (uint32_t)(l*8);

  for(int kt=0; kt<8; kt++){
    if(kt < 7){
      #pragma unroll
      for(int c=0;c<2;c++){
        const int ci = w*2 + c;
        gl_lds16(Kb + (size_t)((kt+1)*64 + ci*8 + lr3)*gstride + gbase + c8s*8,
                 KsB[(kt+1)&1] + ci*1024);
        gl_lds16(Vb + (size_t)((kt+1)*64 + vs[c])*gstride + gbase + vd[c],
                 VtB[(kt+1)&1] + w*2048 + c*1024);
      }
    }
    const char* Kc = KsB[kt&1];
    const float* kkt = &kkL[kt*64];
    const float* lmt = &lamL[kt*64];

    // ---- scores S^T = K * Q^T, both q-tiles share K fragments ----
    f32x4 st[2][4];
    #pragma unroll
    for(int t=0;t<4;t++){
      const bf16x8 ka0 = *(const bf16x8*)(Kc + (t*16+lr)*128 + ((g<<4) ^ swq));
      const bf16x8 ka1 = *(const bf16x8*)(Kc + (t*16+lr)*128 + (((4+g)<<4) ^ swq));
      f32x4 c0 = (f32x4){0.f,0.f,0.f,0.f};
      f32x4 c1 = (f32x4){0.f,0.f,0.f,0.f};
      c0 = __builtin_amdgcn_mfma_f32_16x16x32_bf16(ka0, qf[0][0], c0, 0,0,0);
      c1 = __builtin_amdgcn_mfma_f32_16x16x32_bf16(ka0, qf[1][0], c1, 0,0,0);
      c0 = __builtin_amdgcn_mfma_f32_16x16x32_bf16(ka1, qf[0][1], c0, 0,0,0);
      c1 = __builtin_amdgcn_mfma_f32_16x16x32_bf16(ka1, qf[1][1], c1, 0,0,0);
      st[0][t] = c0; st[1][t] = c1;
    }

    // ---- transform: p = exp(score) directly (all scores <= 0) ----
    uint32_t pbw[2][8];
    #pragma unroll
    for(int qt=0; qt<2; qt++){
      const float q2 = qq[qt];
      float ls = 0.f, dl = 0.f;
      #pragma unroll
      for(int t=0;t<4;t++){
        const f32x4 kkv = *(const f32x4*)(kkt + t*16 + g*4);
        float p[4];
        #pragma unroll
        for(int r=0;r<4;r++){
          const float qk = st[qt][t][r], kk = kkv[r];
          const float a = q2 + kk;
          if(HYP){
            const float u = fmaxf(fmaf(-2.f, qk, a), 0.f);
            const float v = fmaxf(fmaf(q2, kk, fmaf(-2.f, qk, 1.f)), EPSF);
            const float wz = __builtin_amdgcn_sqrtf(u*v);
            const float den = (u + v) + 2.f*wz;
            float ratio = (v - u) * __builtin_amdgcn_rcpf(den);
            ratio = fmaxf(ratio, 5.9604645e-8f);   // = (1-MAXT)/(1+MAXT) -> p_min 0.125
            p[r] = __builtin_amdgcn_exp2f(0.125f * __builtin_amdgcn_logf(ratio));
          } else {
            const float d2 = fmaxf(fmaf(-2.f, qk, a), 0.f) + 1e-12f;
            p[r] = __builtin_amdgcn_exp2f(-0.18033688f * __builtin_amdgcn_sqrtf(d2));
          }
        }
        ls += (p[0]+p[1])+(p[2]+p[3]);
        if(HYP){
          const f32x4 lv = *(const f32x4*)(lmt + t*16 + g*4);
          dl += p[0]*(lv[0]-1.f) + p[1]*(lv[1]-1.f) + p[2]*(lv[2]-1.f) + p[3]*(lv[3]-1.f);
        }
        pbw[qt][t*2]   = cvtpk(p[0], p[1]);
        pbw[qt][t*2+1] = cvtpk(p[2], p[3]);
      }
      ls += __shfl_xor(ls,16); ls += __shfl_xor(ls,32);
      lrun[qt] += ls;
      if(HYP){
        dl += __shfl_xor(dl,16); dl += __shfl_xor(dl,32);
        dnr[qt] += dl;
      }
    }

    // ---- PV: O^T += V^T * P^T ; V via ds_read_b64_tr_b16, P from registers ----
    const uint32_t va_kt = vaddr_base + (uint32_t)((kt&1)*8192);
    {
      // chunk c=0 (k-slots 0..31)
      u32x2 r00=trrd<0>(va_kt),    r01=trrd<512>(va_kt);
      u32x2 r10=trrd<2048>(va_kt), r11=trrd<2560>(va_kt);
      u32x2 r20=trrd<4096>(va_kt), r21=trrd<4608>(va_kt);
      u32x2 r30=trrd<6144>(va_kt), r31=trrd<6656>(va_kt);
      asm volatile("s_waitcnt lgkmcnt(0)" ::: "memory");
      __builtin_amdgcn_sched_barrier(0);
      bf16x8 pb0, pb1;
      { union{uint32_t u[4]; bf16x8 v;} c;
        c.u[0]=pbw[0][0]; c.u[1]=pbw[0][1]; c.u[2]=pbw[0][2]; c.u[3]=pbw[0][3]; pb0=c.v; }
      { union{uint32_t u[4]; bf16x8 v;} c;
        c.u[0]=pbw[1][0]; c.u[1]=pbw[1][1]; c.u[2]=pbw[1][2]; c.u[3]=pbw[1][3]; pb1=c.v; }
      __builtin_amdgcn_s_setprio(1);
      bf16x8 va;
      va = vcomb(r00,r01);
      oa[0][0] = __builtin_amdgcn_mfma_f32_16x16x32_bf16(va, pb0, oa[0][0], 0,0,0);
      oa[1][0] = __builtin_amdgcn_mfma_f32_16x16x32_bf16(va, pb1, oa[1][0], 0,0,0);
      va = vcomb(r10,r11);
      oa[0][1] = __builtin_amdgcn_mfma_f32_16x16x32_bf16(va, pb0, oa[0][1], 0,0,0);
      oa[1][1] = __builtin_amdgcn_mfma_f32_16x16x32_bf16(va, pb1, oa[1][1], 0,0,0);
      va = vcomb(r20,r21);
      oa[0][2] = __builtin_amdgcn_mfma_f32_16x16x32_bf16(va, pb0, oa[0][2], 0,0,0);
      oa[1][2] = __builtin_amdgcn_mfma_f32_16x16x32_bf16(va, pb1, oa[1][2], 0,0,0);
      va = vcomb(r30,r31);
      oa[0][3] = __builtin_amdgcn_mfma_f32_16x16x32_bf16(va, pb0, oa[0][3], 0,0,0);
      oa[1][3] = __builtin_amdgcn_mfma_f32_16x16x32_bf16(va, pb1, oa[1][3], 0,0,0);
      __builtin_amdgcn_s_setprio(0);
    }
    {
      // chunk c=1 (k-slots 32..63)
      u32x2 r00=trrd<1024>(va_kt), r01=trrd<1536>(va_kt);
      u32x2 r10=trrd<3072>(va_kt), r11=trrd<3584>(va_kt);
      u32x2 r20=trrd<5120>(va_kt), r21=trrd<5632>(va_kt);
      u32x2 r30=trrd<7168>(va_kt), r31=trrd<7680>(va_kt);
      asm volatile("s_waitcnt lgkmcnt(0)" ::: "memory");
      __builtin_amdgcn_sched_barrier(0);
      bf16x8 pb0, pb1;
      { union{uint32_t u[4]; bf16x8 v;} c;
        c.u[0]=pbw[0][4]; c.u[1]=pbw[0][5]; c.u[2]=pbw[0][6]; c.u[3]=pbw[0][7]; pb0=c.v; }
      { union{uint32_t u[4]; bf16x8 v;} c;
        c.u[0]=pbw[1][4]; c.u[1]=pbw[1][5]; c.u[2]=pbw[1][6]; c.u[3]=pbw[1][7]; pb1=c.v; }
      __builtin_amdgcn_s_setprio(1);
      bf16x8 va;
      va = vcomb(r00,r01);
      oa[0][0] = __builtin_amdgcn_mfma_f32_16x16x32_bf16(va, pb0, oa[0][0], 0,0,0);
      oa[1][0] = __builtin_amdgcn_mfma_f32_16x16x32_bf16(va, pb1, oa[1][0], 0,0,0);
      va = vcomb(r10,r11);
      oa[0][1] = __builtin_amdgcn_mfma_f32_16x16x32_bf16(va, pb0, oa[0][1], 0,0,0);
      oa[1][1] = __builtin_amdgcn_mfma_f32_16x16x32_bf16(va, pb1, oa[1][1], 0,0,0);
      va = vcomb(r20,r21);
      oa[0][2] = __builtin_amdgcn_mfma_f32_16x16x32_bf16(va, pb0, oa[0][2], 0,0,0);
      oa[1][2] = __builtin_amdgcn_mfma_f32_16x16x32_bf16(va, pb1, oa[1][2], 0,0,0);
      va = vcomb(r30,r31);
      oa[0][3] = __builtin_amdgcn_mfma_f32_16x16x32_bf16(va, pb0, oa[0][3], 0,0,0);
      oa[1][3] = __builtin_amdgcn_mfma_f32_16x16x32_bf16(va, pb1, oa[1][3], 0,0,0);
      __builtin_amdgcn_s_setprio(0);
    }
    __syncthreads();   // one barrier per kt: staging drained, buffers swap
  }

  // ---- epilogue: restage via LDS overlay (on K dbuf), coalesced store ----
  char* OTB = (char*)KsB;
  #pragma unroll
  for(int qt=0; qt<2; qt++){
    float scale;
    {
      const float invl = 1.f/lrun[qt];
      if(HYP){
        const float dn = fmaxf(dnr[qt]*invl, EPSF);
        scale = invl/dn;
      } else scale = invl;
    }
    __syncthreads();
    #pragma unroll
    for(int m=0;m<4;m++){
      f32x4 vv;
      vv[0]=oa[qt][m][0]*scale; vv[1]=oa[qt][m][1]*scale;
      vv[2]=oa[qt][m][2]*scale; vv[3]=oa[qt][m][3]*scale;
      *(f32x4*)(OTB + w*4096 + lr*256 + ((m*64 + g*16) ^ ((lr&7)<<4))) = vv;
    }
    __syncthreads();
    {
      const int row = tid >> 2, cw = tid & 3;
      const int wsrc = row >> 4, ql = row & 15;
      float vals[16];
      #pragma unroll
      for(int ii=0;ii<4;ii++)
        *(f32x4*)&vals[ii*4] = *(const f32x4*)(OTB + wsrc*4096 + ql*256 + ((cw*64 + ii*16) ^ ((ql&7)<<4)));
      const size_t go = (size_t)(q0 + qt*64 + row)*gstride + gbase + cw*16;
      *(uint4*)(outB + go)     = pack8(vals);
      *(uint4*)(outB + go + 8) = pack8(vals+8);
    }
  }
}

// =====================================================================
extern "C" void kernel_launch(void* const* d_in, const int* in_sizes, int n_in,
                              void* d_out, int out_size, void* d_ws, size_t ws_size,
                              hipStream_t stream)
{
  (void)in_sizes; (void)n_in; (void)out_size; (void)ws_size;
  const float* x    = (const float*)d_in[0];
  const float* ln1g = (const float*)d_in[1];
  const float* ln1b = (const float*)d_in[2];
  const float* ln2g = (const float*)d_in[3];
  const float* ln2b = (const float*)d_in[4];
  const float* Wq = (const float*)d_in[5];
  const float* bq = (const float*)d_in[6];
  const float* Wk = (const float*)d_in[7];
  const float* bk = (const float*)d_in[8];
  const float* Wv = (const float*)d_in[9];
  const float* bv = (const float*)d_in[10];
  const float* Wo = (const float*)d_in[11];
  const float* bo = (const float*)d_in[12];
  const float* W1 = (const float*)d_in[13];
  const float* b1 = (const float*)d_in[14];
  const float* W2 = (const float*)d_in[15];
  const float* b2 = (const float*)d_in[16];
  float* out = (float*)d_out;

  char* ws = (char*)d_ws;
  uint16_t* MXb = (uint16_t*)(ws);                          // 24MB bf16 GEMM scratch
  float*    X2  = (float*)   (ws + ((size_t)24<<20));       // 16MB fp32
  uint16_t* HB  = (uint16_t*)(ws + ((size_t)40<<20));       // 8MB
  uint16_t* QB  = (uint16_t*)(ws + ((size_t)48<<20));       // 8MB (Q,K,V contiguous)
  uint16_t* KB  = (uint16_t*)(ws + ((size_t)56<<20));
  uint16_t* VB  = (uint16_t*)(ws + ((size_t)64<<20));
  uint16_t* OB  = (uint16_t*)(ws + ((size_t)72<<20));
  uint16_t* F1B = (uint16_t*)(ws + ((size_t)80<<20));       // 32MB
  uint16_t* WB  = (uint16_t*)(ws + ((size_t)112<<20));      // 12MB (both experts)
  float*    YV  = (float*)   (ws + ((size_t)124<<20));      // expmap'd biases
  float*    NH  = (float*)   (ws + ((size_t)124<<20) + (64<<10));
  float*    NO  = NH + R_;
  float*    N3  = NO + R_;
  float*    N4  = N3 + R_;
  float*    qnG = (float*)   (ws + ((size_t)125<<20));      // [128][512]
  float*    knG = qnG + 65536;
  float*    lamG= knG + 65536;

  // ---- weights + biases (both experts) ----
  cvt_all<<<6144,256,0,stream>>>(Wq,Wk,Wv,Wo,W1,W2, WB);
  expmap_all<<<6,256,0,stream>>>(bq,bk,bv,bo,b1,b2, YV);

  // ================= Expert 0: Euclidean =================
  ln_k<<<R_,256,0,stream>>>(x, ln1g, ln1b, HB);
  gemm2<<<dim3(12,64),256,0,stream>>>(HB, WB, R_,1536,512, 6, bq, bk, bv, nullptr, nullptr, QB);
  qk_norms<<<2048,256,0,stream>>>(QB, KB, qnG, knG);
  attn3<0><<<dim3(4,128),256,0,stream>>>(QB, KB, VB, qnG, knG, nullptr, OB);
  gemm2<<<dim3(4,64),256,0,stream>>>(OB, WB+786432, R_,512,512, 2, bo, nullptr,nullptr, x, X2, nullptr);
  ln_k<<<R_,256,0,stream>>>(X2, ln2g, ln2b, HB);
  gemm2<<<dim3(16,64),256,0,stream>>>(HB, WB+1048576, R_,2048,512, 3, b1, nullptr,nullptr, nullptr, nullptr, F1B);
  gemm2<<<dim3(4,64),256,0,stream>>>(F1B, WB+2097152, R_,512,2048, 4, b2, nullptr,nullptr, X2, out, nullptr);

  // ================= Expert 1: Hyperbolic =================
  const float* x1 = x + (size_t)R_*E_;
  uint16_t* WBe = WB + 3145728;
  hyp_lnexp<<<R_,256,0,stream>>>(x1, ln1g+E_, ln1b+E_, HB, NH, 0);
  gemm2<<<dim3(12,64),256,0,stream>>>(HB, WBe, R_,1536,512, 5, nullptr,nullptr,nullptr,nullptr, nullptr, MXb);
  man_epi_qkv<<<dim3(R_,3),256,0,stream>>>(MXb, NH, YV, QB, qnG, knG, lamG);
  attn3<1><<<dim3(4,128),256,0,stream>>>(QB, KB, VB, qnG, knG, lamG, OB);
  o_finish2<<<R_,256,0,stream>>>(OB, HB, NO);
  gemm2<<<dim3(4,64),256,0,stream>>>(HB, WBe+786432, R_,512,512, 5, nullptr,nullptr,nullptr,nullptr, nullptr, MXb);
  man_epi<2><<<R_,256,0,stream>>>(MXb, NO, YV+1539, nullptr, nullptr, x1, X2, 0);
  hyp_lnexp<<<R_,256,0,stream>>>(X2, ln2g+E_, ln2b+E_, HB, N3, 1);
  gemm2<<<dim3(16,64),256,0,stream>>>(HB, WBe+1048576, R_,2048,512, 5, nullptr,nullptr,nullptr,nullptr, nullptr, F1B);
  man_epi<8><<<R_,256,0,stream>>>(F1B, N3, YV+2052, F1B, N4, nullptr, nullptr, 1);
  gemm2<<<dim3(4,64),256,0,stream>>>(F1B, WBe+2097152, R_,512,2048, 5, nullptr,nullptr,nullptr,nullptr, nullptr, MXb);
  man_epi<2><<<R_,256,0,stream>>>(MXb, N4, YV+4101, nullptr, nullptr, X2, out + (size_t)R_*E_, 1|8);
}

// Round 6
// 503.306 us; speedup vs baseline: 7.0898x; 1.0668x over previous
//
#include <hip/hip_runtime.h>
#include <cstdint>
#include <cstddef>

#define S_ 512
#define B_ 16
#define H_ 8
#define D_ 64
#define E_ 512
#define FFN_ 2048
#define R_ (S_*B_)          // 8192 rows (s*B+b)
#define EPSF 1e-6f
#define PROJ_M 0.99999f     // 1 - 1e-5

typedef __attribute__((ext_vector_type(8))) short bf16x8;
typedef __attribute__((ext_vector_type(4))) float f32x4;
typedef __attribute__((ext_vector_type(2))) unsigned int u32x2;

// ---------- helpers ----------
__device__ __forceinline__ float bf2f(uint32_t u){
  union{uint32_t i; float f;} c; c.i = u<<16; return c.f;
}
__device__ __forceinline__ uint16_t f2bf(float f){
  union{float f; uint32_t i;} c; c.f = f;
  return (uint16_t)((c.i + 0x7FFFu + ((c.i>>16)&1u))>>16);
}
__device__ __forceinline__ void unpack8(uint4 u, float* f){
  f[0]=bf2f(u.x&0xFFFFu); f[1]=bf2f(u.x>>16);
  f[2]=bf2f(u.y&0xFFFFu); f[3]=bf2f(u.y>>16);
  f[4]=bf2f(u.z&0xFFFFu); f[5]=bf2f(u.z>>16);
  f[6]=bf2f(u.w&0xFFFFu); f[7]=bf2f(u.w>>16);
}
__device__ __forceinline__ uint4 pack8(const float* f){
  uint4 u;
  u.x = (uint32_t)f2bf(f[0]) | ((uint32_t)f2bf(f[1])<<16);
  u.y = (uint32_t)f2bf(f[2]) | ((uint32_t)f2bf(f[3])<<16);
  u.z = (uint32_t)f2bf(f[4]) | ((uint32_t)f2bf(f[5])<<16);
  u.w = (uint32_t)f2bf(f[6]) | ((uint32_t)f2bf(f[7])<<16);
  return u;
}
__device__ __forceinline__ float artanh_c(float x){
  return (x >= 0.99999994f) ? 8.4056215f : atanhf(x);
}
__device__ __forceinline__ float wave_sum(float x){
  #pragma unroll
  for(int o=32;o>=1;o>>=1) x += __shfl_xor(x,o);
  return x;
}
__device__ __forceinline__ float halfsum32(float x){
  #pragma unroll
  for(int o=16;o>=1;o>>=1) x += __shfl_xor(x,o);
  return x;
}
__device__ __forceinline__ float block_sum(float x, float* sb){
  x = wave_sum(x);
  const int w = threadIdx.x >> 6;
  __syncthreads();
  if((threadIdx.x & 63)==0) sb[w] = x;
  __syncthreads();
  return sb[0]+sb[1]+sb[2]+sb[3];
}
// async global->LDS, 16B per lane; LDS dest = wave-uniform base + lane*16
__device__ __forceinline__ void gl_lds16(const void* g, void* l){
  __builtin_amdgcn_global_load_lds(
    (const __attribute__((address_space(1))) void*)(uintptr_t)g,
    (__attribute__((address_space(3))) void*)(uint32_t)(uintptr_t)l, 16, 0, 0);
}
__device__ __forceinline__ uint32_t cvtpk(float a, float b){
  uint32_t r;
  asm("v_cvt_pk_bf16_f32 %0, %1, %2" : "=v"(r) : "v"(a), "v"(b));
  return r;
}
template<int OFF>
__device__ __forceinline__ u32x2 trrd(uint32_t addr){
  u32x2 r;
  asm volatile("ds_read_b64_tr_b16 %0, %1 offset:%2" : "=v"(r) : "v"(addr), "n"(OFF));
  return r;
}
__device__ __forceinline__ bf16x8 vcomb(u32x2 a, u32x2 b){
  union{ uint32_t u[4]; bf16x8 v; } c;
  c.u[0]=a[0]; c.u[1]=a[1]; c.u[2]=b[0]; c.u[3]=b[1];
  return c.v;
}

// ---------- all weights fp32 -> bf16 (both experts), one launch ----------
__global__ __launch_bounds__(256) void cvt_all(
  const float* __restrict__ Wq, const float* __restrict__ Wk,
  const float* __restrict__ Wv, const float* __restrict__ Wo,
  const float* __restrict__ W1, const float* __restrict__ W2,
  uint16_t* __restrict__ dst)
{
  int i4 = blockIdx.x*256 + threadIdx.x;   // 4-elem units, total 1572864
  int e = 0;
  if(i4 >= 786432){ e = 1; i4 -= 786432; }
  const int r = i4;
  const float* s;
  if(r < 65536)        s = Wq + (size_t)(r)*4        + (size_t)e*262144;
  else if(r < 131072)  s = Wk + (size_t)(r-65536)*4  + (size_t)e*262144;
  else if(r < 196608)  s = Wv + (size_t)(r-131072)*4 + (size_t)e*262144;
  else if(r < 262144)  s = Wo + (size_t)(r-196608)*4 + (size_t)e*262144;
  else if(r < 524288)  s = W1 + (size_t)(r-262144)*4 + (size_t)e*1048576;
  else                 s = W2 + (size_t)(r-524288)*4 + (size_t)e*1048576;
  const float4 f = *(const float4*)s;
  uint2 o;
  o.x = (uint32_t)f2bf(f.x) | ((uint32_t)f2bf(f.y)<<16);
  o.y = (uint32_t)f2bf(f.z) | ((uint32_t)f2bf(f.w)<<16);
  *(uint2*)(dst + (size_t)e*3145728 + (size_t)r*4) = o;
}

// ---------- expmap0 of all 6 expert-1 biases ----------
__global__ __launch_bounds__(256) void expmap_all(
  const float* __restrict__ bq, const float* __restrict__ bk,
  const float* __restrict__ bv, const float* __restrict__ bo,
  const float* __restrict__ b1, const float* __restrict__ b2,
  float* __restrict__ YV)
{
  __shared__ float sb[4];
  const int id = blockIdx.x, t = threadIdx.x;
  const float* src; float* dst; int C;
  if(id==0){ src=bq+E_;   dst=YV+0;    C=E_; }
  else if(id==1){ src=bk+E_;   dst=YV+513;  C=E_; }
  else if(id==2){ src=bv+E_;   dst=YV+1026; C=E_; }
  else if(id==3){ src=bo+E_;   dst=YV+1539; C=E_; }
  else if(id==4){ src=b1+FFN_; dst=YV+2052; C=FFN_; }
  else          { src=b2+E_;   dst=YV+4101; C=E_; }
  const int npc = C >> 8;
  float v[8]; float s2 = 0.f;
  for(int i=0;i<npc;i++){ v[i] = src[t+256*i]; s2 += v[i]*v[i]; }
  s2 = block_sum(s2, sb);
  const float n = sqrtf(s2 + 1e-15f);
  const float th = tanhf(n);
  const float sc = th/n;
  for(int i=0;i<npc;i++) dst[t+256*i] = v[i]*sc;
  if(t==0) dst[C] = th*th;
}

// ---------- plain layernorm (euclid), row=512, fp32 in -> bf16 ----------
__global__ __launch_bounds__(256) void ln_k(const float* __restrict__ x,
  const float* __restrict__ g, const float* __restrict__ b, uint16_t* __restrict__ out)
{
  __shared__ float sb[4];
  const int row = blockIdx.x, t = threadIdx.x;
  const size_t base = (size_t)row*E_;
  float v0 = x[base+t], v1 = x[base+t+256];
  const float mu  = block_sum(v0+v1, sb) * (1.f/E_);
  const float d0 = v0-mu, d1 = v1-mu;
  const float var = block_sum(d0*d0+d1*d1, sb) * (1.f/E_);
  const float rs = 1.f/sqrtf(var + 1e-5f);
  out[base+t]     = f2bf(d0*rs*g[t] + b[t]);
  out[base+t+256] = f2bf(d1*rs*g[t+256] + b[t+256]);
}

// ---------- hyp: expmap0(LN(x)) [+projx]  (logmap0 scale cancels in LN) ----------
__global__ __launch_bounds__(256) void hyp_lnexp(const float* __restrict__ x,
  const float* __restrict__ g, const float* __restrict__ b,
  uint16_t* __restrict__ out, float* __restrict__ nout, int do_projx)
{
  __shared__ float sb[4];
  const int row = blockIdx.x, t = threadIdx.x;
  const size_t base = (size_t)row*E_;
  float v0 = x[base+t], v1 = x[base+t+256];
  const float mu  = block_sum(v0+v1, sb) * (1.f/E_);
  const float d0 = v0-mu, d1 = v1-mu;
  const float var = block_sum(d0*d0+d1*d1, sb) * (1.f/E_);
  const float rs = 1.f/sqrtf(var + 1e-5f);
  float t0 = d0*rs*g[t] + b[t];
  float t1 = d1*rs*g[t+256] + b[t+256];
  const float n2s = block_sum(t0*t0+t1*t1, sb);
  const float n2 = sqrtf(n2s + 1e-15f);
  const float nh = tanhf(n2);
  const float scl = nh/n2;
  t0 *= scl; t1 *= scl;
  float nrm = nh;
  if(do_projx && nrm > PROJ_M){ const float s = PROJ_M/nrm; t0*=s; t1*=s; nrm = PROJ_M; }
  out[base+t] = f2bf(t0); out[base+t+256] = f2bf(t1);
  if(t==0) nout[row] = nrm;
}

// ---------- per-head squared norms of euclid Q,K (layout [b*8+h][s]) ----------
__global__ __launch_bounds__(256) void qk_norms(
  const uint16_t* __restrict__ Qb, const uint16_t* __restrict__ Kb,
  float* __restrict__ qn, float* __restrict__ kn)
{
  const int w = threadIdx.x >> 6, l = threadIdx.x & 63;
  const int row = blockIdx.x*4 + w;
  const int s = row >> 4, b = row & 15;
  const size_t base = (size_t)row*E_ + l*8;
  {
    uint4 u = *(const uint4*)(Qb + base);
    float f[8]; unpack8(u, f);
    float ss = 0.f;
    #pragma unroll
    for(int i=0;i<8;i++) ss += f[i]*f[i];
    ss += __shfl_xor(ss,1); ss += __shfl_xor(ss,2); ss += __shfl_xor(ss,4);
    if((l&7)==0) qn[((b<<3) + (l>>3))*512 + s] = ss;
  }
  {
    uint4 u = *(const uint4*)(Kb + base);
    float f[8]; unpack8(u, f);
    float ss = 0.f;
    #pragma unroll
    for(int i=0;i<8;i++) ss += f[i]*f[i];
    ss += __shfl_xor(ss,1); ss += __shfl_xor(ss,2); ss += __shfl_xor(ss,4);
    if((l&7)==0) kn[((b<<3) + (l>>3))*512 + s] = ss;
  }
}

// ---------- man_linear epilogue (generic): flags 1 relu; 8 projx on midpoint ----------
template<int NPC>
__global__ __launch_bounds__(256) void man_epi(
  const uint16_t* __restrict__ mxb, const float* __restrict__ nxbuf,
  const float* __restrict__ y, uint16_t* __restrict__ outb,
  float* __restrict__ nout,
  const float* __restrict__ midres, float* __restrict__ midout, int flags)
{
  constexpr int C = NPC*256;
  __shared__ float sb[4];
  const int row = blockIdx.x, t = threadIdx.x;
  const size_t base = (size_t)row*C + (size_t)t*NPC;
  float v[NPC], yv[NPC];
  if(NPC==2){
    const uint32_t u = *(const uint32_t*)(mxb + base);
    v[0] = bf2f(u & 0xFFFFu); v[1] = bf2f(u >> 16);
  } else {
    const uint4 u = *(const uint4*)(mxb + base);
    unpack8(u, v);
  }
  float s2 = 0.f;
  #pragma unroll
  for(int i=0;i<NPC;i++){ yv[i] = y[t*NPC + i]; s2 += v[i]*v[i]; }
  s2 = block_sum(s2, sb);
  const float nmx = sqrtf(s2 + 1e-15f);
  const float nx  = nxbuf[row];
  const float sc  = tanhf(nmx/nx * artanh_c(nx));
  const bool ok   = (nmx > 1e-7f);
  const float fmul = ok ? (sc/nmx) : 0.f;
  const float x2   = ok ? sc*sc : 0.f;
  float xy = 0.f;
  #pragma unroll
  for(int i=0;i<NPC;i++){ v[i] *= fmul; xy += v[i]*yv[i]; }
  xy = block_sum(xy, sb);
  const float y2 = y[C];
  const float aa = 1.f + 2.f*xy + y2;
  const float bb = 1.f - x2;
  const float iden = 1.f/fmaxf(1.f + 2.f*xy + x2*y2, EPSF);
  const float num2 = aa*aa*x2 + 2.f*aa*bb*xy + bb*bb*y2;
  const float nz = sqrtf(num2*iden*iden + 1e-15f);
  const float ps = (nz > PROJ_M) ? (PROJ_M/nz) : 1.f;
  float nfin = (nz > PROJ_M) ? PROJ_M : nz;
  #pragma unroll
  for(int i=0;i<NPC;i++) v[i] = (aa*v[i] + bb*yv[i]) * iden * ps;
  if(flags & 1){
    float rs = 0.f;
    #pragma unroll
    for(int i=0;i<NPC;i++){ v[i] = fmaxf(v[i], 0.f); rs += v[i]*v[i]; }
    rs = block_sum(rs, sb);
    nfin = sqrtf(rs + 1e-15f);
  }
  if(midres){
    float bv2[NPC];
    float pb = 0.f, pab = 0.f;
    #pragma unroll
    for(int i=0;i<NPC;i++){ bv2[i] = midres[base + i]; pb += bv2[i]*bv2[i]; pab += v[i]*bv2[i]; }
    const float sa  = nfin*nfin;
    const float sbb = block_sum(pb, sb);
    const float sab = block_sum(pab, sb);
    const float l1 = 2.f/fmaxf(1.f - sa,  EPSF);
    const float l2 = 2.f/fmaxf(1.f - sbb, EPSF);
    const float idn = 1.f/fmaxf(l1 + l2 - 2.f, EPSF);
    const float nt2 = (l1*l1*sa + 2.f*l1*l2*sab + l2*l2*sbb)*idn*idn;
    const float nt = sqrtf(nt2 + 1e-15f);
    const float sfin = tanhf(0.5f*artanh_c(nt));
    float scm = sfin/nt;
    if((flags & 8) && sfin > PROJ_M) scm *= PROJ_M/sfin;
    #pragma unroll
    for(int i=0;i<NPC;i++) midout[base + i] = (v[i]*l1 + bv2[i]*l2)*idn*scm;
  } else {
    if(NPC==2){
      uint32_t u = (uint32_t)f2bf(v[0]) | ((uint32_t)f2bf(v[1])<<16);
      *(uint32_t*)(outb + base) = u;
    } else {
      *(uint4*)(outb + base) = pack8(v);
    }
    if(nout && t==0) nout[row] = nfin;
  }
}

// ---------- fused hyp q/k/v man_linear epilogue: per-head projx, lam fold for v ----------
__global__ __launch_bounds__(256) void man_epi_qkv(
  const uint16_t* __restrict__ mxb, const float* __restrict__ nxbuf,
  const float* __restrict__ YV, uint16_t* __restrict__ qkv,
  float* __restrict__ qnG, float* __restrict__ knG, float* __restrict__ lamG)
{
  __shared__ float sb[4];
  const int sel = blockIdx.y;
  const int row = blockIdx.x, t = threadIdx.x;
  const float* y = YV + sel*513;
  float v[2], yv[2];
  {
    const uint32_t u = *(const uint32_t*)(mxb + (size_t)row*1536 + sel*512 + t*2);
    v[0] = bf2f(u & 0xFFFFu); v[1] = bf2f(u >> 16);
  }
  float s2 = 0.f;
  #pragma unroll
  for(int i=0;i<2;i++){ yv[i] = y[t*2 + i]; s2 += v[i]*v[i]; }
  s2 = block_sum(s2, sb);
  const float nmx = sqrtf(s2 + 1e-15f);
  const float nx  = nxbuf[row];
  const float sc  = tanhf(nmx/nx * artanh_c(nx));
  const bool ok   = (nmx > 1e-7f);
  const float fmul = ok ? (sc/nmx) : 0.f;
  const float x2   = ok ? sc*sc : 0.f;
  float xy = 0.f;
  #pragma unroll
  for(int i=0;i<2;i++){ v[i] *= fmul; xy += v[i]*yv[i]; }
  xy = block_sum(xy, sb);
  const float y2 = y[512];
  const float aa = 1.f + 2.f*xy + y2;
  const float bb = 1.f - x2;
  const float iden = 1.f/fmaxf(1.f + 2.f*xy + x2*y2, EPSF);
  const float num2 = aa*aa*x2 + 2.f*aa*bb*xy + bb*bb*y2;
  const float nz = sqrtf(num2*iden*iden + 1e-15f);
  const float ps = (nz > PROJ_M) ? (PROJ_M/nz) : 1.f;
  #pragma unroll
  for(int i=0;i<2;i++) v[i] = (aa*v[i] + bb*yv[i]) * iden * ps;
  // per-head projx (+ lambda)
  float hs = halfsum32(v[0]*v[0] + v[1]*v[1]);
  float nh = sqrtf(hs + 1e-15f);
  float phs = 1.f;
  if(nh > PROJ_M){ phs = PROJ_M/nh; nh = PROJ_M; }
  v[0] *= phs; v[1] *= phs;
  const float nh2 = nh*nh;
  const float lam = 2.f/fmaxf(1.f - nh2, EPSF);
  if(sel==2){ v[0] *= lam; v[1] *= lam; }
  if((t & 31) == 0){
    const int s = row >> 4, b = row & 15;
    const int idx = ((b<<3) + (t>>5))*512 + s;
    if(sel==0) qnG[idx] = nh2;
    else if(sel==1) knG[idx] = nh2;
    else lamG[idx] = lam;
  }
  uint32_t u = (uint32_t)f2bf(v[0]) | ((uint32_t)f2bf(v[1])<<16);
  *(uint32_t*)(qkv + (size_t)sel*4194304 + (size_t)row*512 + t*2) = u;
}

// ---------- hyp attention-output finish ----------
__global__ __launch_bounds__(256) void o_finish2(const uint16_t* __restrict__ op,
  uint16_t* __restrict__ outb, float* __restrict__ nout)
{
  __shared__ float sb[4];
  const int row = blockIdx.x, t = threadIdx.x;
  const size_t base = (size_t)row*E_ + t*2;
  const uint32_t u = *(const uint32_t*)(op + base);
  float v0 = bf2f(u & 0xFFFFu), v1 = bf2f(u >> 16);
  const float hs = halfsum32(v0*v0 + v1*v1);
  const float ns = sqrtf(hs + 1e-15f);
  const float tt = tanhf(0.5f*artanh_c(ns));
  float scv = tt/ns;
  float sn = tt;
  if(sn > PROJ_M){ scv *= PROJ_M/sn; sn = PROJ_M; }
  v0 *= scv; v1 *= scv;
  const float tot = block_sum(v0*v0 + v1*v1, sb);
  const float n = sqrtf(tot + 1e-15f);
  float nf = n;
  if(n > PROJ_M){ const float s = PROJ_M/n; v0 *= s; v1 *= s; nf = PROJ_M; }
  *(uint32_t*)(outb + base) = (uint32_t)f2bf(v0) | ((uint32_t)f2bf(v1)<<16);
  if(t==0) nout[row] = nf;
}

// ---------- bf16 MFMA GEMM v3: 128x128 tile, BK=64, 3-stage depth-2 pipeline,
// counted vmcnt + raw barrier, XCD-swizzled blocks, 512 threads ----------
// mode: 0 raw->outf; 1 +bias->outb; 2 +bias+res->outf; 3 relu+bias->outb;
//       4 relu+bias+res->outf; 5 raw->outb; 6 QKV-split +bias->outb(QKV contig)
__global__ __launch_bounds__(512,2) void gemm3(
    const uint16_t* __restrict__ A, const uint16_t* __restrict__ Bw,
    int M, int N, int K, int mode,
    const float* __restrict__ bias, const float* __restrict__ biasK,
    const float* __restrict__ biasV, const float* __restrict__ res,
    float* __restrict__ outf, uint16_t* __restrict__ outb)
{
  __shared__ __align__(16) char AsB[3][16384];
  __shared__ __align__(16) char BsB[3][16384];
  const int gx = gridDim.x;
  int lid = blockIdx.x + gx*blockIdx.y;
  {
    const int nwg = gx*gridDim.y;           // always % 8 == 0 here
    const int cpx = nwg >> 3;
    lid = (lid & 7)*cpx + (lid >> 3);       // XCD-contiguous chunks, N-fastest
  }
  const int m0 = (lid/gx)*128;
  const int n0 = (lid%gx)*128;

  const int tid = threadIdx.x;
  const int l = tid & 63, w = tid >> 6;     // 8 waves
  const int wm = w >> 2, wn = w & 3;        // 2 x 4 wave grid; 64x32 out/wave
  const int lr = l & 15, g = l >> 4;
  // staging: per issue 64 rows x 128B; thread row tid>>3, phys chunk tid&7
  const int srow = tid >> 3;
  const int schunk = (tid & 7) ^ (srow & 7);   // pre-swizzled global source
  const uint16_t* aS = A  + (size_t)(m0 + srow)*K + schunk*8;
  const uint16_t* bS = Bw + (size_t)(n0 + srow)*K + schunk*8;
  char* ldsA0 = (char*)AsB + (size_t)w*1024;   // wave-uniform base (+lane*16 by HW)
  char* ldsB0 = (char*)BsB + (size_t)w*1024;

  f32x4 acc[4][2];
  #pragma unroll
  for(int i=0;i<4;i++)
    #pragma unroll
    for(int j=0;j<2;j++) acc[i][j] = (f32x4){0.f,0.f,0.f,0.f};

  const int nk = K >> 6;

#define STAGE3(ks, bufi) { \
    const int k0s = (ks) << 6; \
    gl_lds16(aS + k0s,                    ldsA0 + (bufi)*16384); \
    gl_lds16(aS + (size_t)64*K + k0s,     ldsA0 + (bufi)*16384 + 8192); \
    gl_lds16(bS + k0s,                    ldsB0 + (bufi)*16384); \
    gl_lds16(bS + (size_t)64*K + k0s,     ldsB0 + (bufi)*16384 + 8192); \
  }

  STAGE3(0, 0);
  STAGE3(1, 1);
  int buf = 0;
  for(int ks=0; ks<nk; ks++){
    if(ks+1 < nk){ asm volatile("s_waitcnt vmcnt(4)" ::: "memory"); }
    else         { asm volatile("s_waitcnt vmcnt(0)" ::: "memory"); }
    __builtin_amdgcn_s_barrier();
    if(ks+2 < nk){
      const int nb = (buf+2 >= 3) ? buf-1 : buf+2;
      STAGE3(ks+2, nb);
    }
    const char* Ac = AsB[buf];
    const char* Bc = BsB[buf];
    #pragma unroll
    for(int h=0;h<2;h++){
      bf16x8 av[4], bv[2];
      #pragma unroll
      for(int i=0;i<4;i++)
        av[i] = *(const bf16x8*)(Ac + (wm*64 + i*16 + lr)*128 + ((((h*4+g)<<4)) ^ ((lr&7)<<4)));
      #pragma unroll
      for(int j=0;j<2;j++)
        bv[j] = *(const bf16x8*)(Bc + (wn*32 + j*16 + lr)*128 + ((((h*4+g)<<4)) ^ ((lr&7)<<4)));
      #pragma unroll
      for(int i=0;i<4;i++)
        #pragma unroll
        for(int j=0;j<2;j++)
          acc[i][j] = __builtin_amdgcn_mfma_f32_16x16x32_bf16(av[i], bv[j], acc[i][j], 0,0,0);
    }
    buf = (buf+1 >= 3) ? 0 : buf+1;
  }
#undef STAGE3

  const int orow = g*4;
  #pragma unroll
  for(int i=0;i<4;i++){
    #pragma unroll
    for(int j=0;j<2;j++){
      const int gn = n0 + wn*32 + j*16 + lr;
      float bval = 0.f;
      if(mode==1||mode==2||mode==3||mode==4) bval = bias[gn];
      else if(mode==6){
        const float* bp = (gn<512)? bias : ((gn<1024)? biasK : biasV);
        bval = bp[gn&511];
      }
      #pragma unroll
      for(int r=0;r<4;r++){
        const int gm = m0 + wm*64 + i*16 + orow + r;
        const float vv = acc[i][j][r];
        const size_t off = (size_t)gm*N + gn;
        if(mode==0){ outf[off] = vv; }
        else if(mode==1){ outb[off] = f2bf(vv + bval); }
        else if(mode==2){ outf[off] = vv + bval + res[off]; }
        else if(mode==3){ outb[off] = f2bf(fmaxf(vv + bval, 0.f)); }
        else if(mode==4){ outf[off] = fmaxf(vv + bval, 0.f) + res[off]; }
        else if(mode==5){ outb[off] = f2bf(vv); }
        else {
          outb[(size_t)(gn>>9)*4194304 + (size_t)gm*512 + (gn&511)] = f2bf(vv + bval);
        }
      }
    }
  }
}

// ---------- MFMA flash attention v3: direct-exp softmax, tr-read V, reg-P ----------
template<int HYP>
__global__ __launch_bounds__(256,2) void attn3(
  const uint16_t* __restrict__ Qb, const uint16_t* __restrict__ Kb,
  const uint16_t* __restrict__ Vb, const float* __restrict__ qnG,
  const float* __restrict__ knG, const float* __restrict__ lamG,
  uint16_t* __restrict__ outB)
{
  __shared__ __align__(16) char QsB[16384];     // 2 q-tiles [64][64] bf16 swz
  __shared__ __align__(16) char KsB[2][8192];   // dbuf K tile (epilogue overlay)
  __shared__ __align__(16) char VtB[2][8192];   // dbuf V, tr-subtiled
  __shared__ float kkL[512];
  __shared__ float lamL[512];

  const int tid = threadIdx.x;
  const int l = tid & 63, w = tid >> 6;
  const int lr = l & 15, g = l >> 4;
  const int lr3 = l >> 3, lc = l & 7;
  const int c8s = lc ^ lr3;
  const int swq = (lr & 7) << 4;
  // XCD swizzle: 512 blocks -> each XCD owns 16 consecutive bh groups
  int lid = blockIdx.x + (blockIdx.y << 2);
  lid = (lid & 7)*64 + (lid >> 3);
  const int bh = lid >> 2;
  const int q0 = (lid & 3) * 128;
  const size_t gstride = (size_t)B_*E_;
  const size_t gbase = (size_t)(bh>>3)*E_ + (size_t)(bh&7)*D_;

  // V-staging decode: chunk ci covers LDS elems [w*1024+ci*512+l*8, +8)
  int vs[2], vd[2];
  #pragma unroll
  for(int ci=0;ci<2;ci++){
    vs[ci] = (ci*8 + (l>>3))*4 + ((l>>1)&3);
    vd[ci] = w*16 + (l&1)*8;
  }

  // ---- prologue staging ----
  #pragma unroll
  for(int c=0;c<4;c++){
    const int ci = w*4 + c;
    gl_lds16(Qb + (size_t)(q0 + ci*8 + lr3)*gstride + gbase + c8s*8, QsB + ci*1024);
  }
  #pragma unroll
  for(int c=0;c<2;c++){
    const int ci = w*2 + c;
    gl_lds16(Kb + (size_t)(ci*8 + lr3)*gstride + gbase + c8s*8, KsB[0] + ci*1024);
    gl_lds16(Vb + (size_t)vs[c]*gstride + gbase + vd[c], VtB[0] + w*2048 + c*1024);
  }
  kkL[tid]       = knG[bh*512 + tid];
  kkL[tid + 256] = knG[bh*512 + 256 + tid];
  if(HYP){
    lamL[tid]       = lamG[bh*512 + tid];
    lamL[tid + 256] = lamG[bh*512 + 256 + tid];
  }
  __syncthreads();

  // hoist Q fragments + qq
  const int qrow = w*16 + lr;
  bf16x8 qf[2][2];
  qf[0][0] = *(const bf16x8*)(QsB +        qrow*128 + ((g<<4) ^ swq));
  qf[0][1] = *(const bf16x8*)(QsB +        qrow*128 + (((4+g)<<4) ^ swq));
  qf[1][0] = *(const bf16x8*)(QsB + 8192 + qrow*128 + ((g<<4) ^ swq));
  qf[1][1] = *(const bf16x8*)(QsB + 8192 + qrow*128 + (((4+g)<<4) ^ swq));
  float qq[2];
  qq[0] = qnG[bh*512 + q0 + qrow];
  qq[1] = qnG[bh*512 + q0 + 64 + qrow];

  f32x4 oa[2][4];
  #pragma unroll
  for(int qt=0;qt<2;qt++)
    #pragma unroll
    for(int m=0;m<4;m++) oa[qt][m] = (f32x4){0.f,0.f,0.f,0.f};
  float lrun[2] = {0.f, 0.f};
  float dnr[2]  = {0.f, 0.f};

  const uint32_t vaddr_base = (uint32_t)(uintptr_t)(&VtB[0][0]) + (uint32_t)(l*8);

  for(int kt=0; kt<8; kt++){
    if(kt < 7){
      #pragma unroll
      for(int c=0;c<2;c++){
        const int ci = w*2 + c;
        gl_lds16(Kb + (size_t)((kt+1)*64 + ci*8 + lr3)*gstride + gbase + c8s*8,
                 KsB[(kt+1)&1] + ci*1024);
        gl_lds16(Vb + (size_t)((kt+1)*64 + vs[c])*gstride + gbase + vd[c],
                 VtB[(kt+1)&1] + w*2048 + c*1024);
      }
    }
    const char* Kc = KsB[kt&1];
    const float* kkt = &kkL[kt*64];
    const float* lmt = &lamL[kt*64];

    // ---- scores S^T = K * Q^T, both q-tiles share K fragments ----
    f32x4 st[2][4];
    #pragma unroll
    for(int t=0;t<4;t++){
      const bf16x8 ka0 = *(const bf16x8*)(Kc + (t*16+lr)*128 + ((g<<4) ^ swq));
      const bf16x8 ka1 = *(const bf16x8*)(Kc + (t*16+lr)*128 + (((4+g)<<4) ^ swq));
      f32x4 c0 = (f32x4){0.f,0.f,0.f,0.f};
      f32x4 c1 = (f32x4){0.f,0.f,0.f,0.f};
      c0 = __builtin_amdgcn_mfma_f32_16x16x32_bf16(ka0, qf[0][0], c0, 0,0,0);
      c1 = __builtin_amdgcn_mfma_f32_16x16x32_bf16(ka0, qf[1][0], c1, 0,0,0);
      c0 = __builtin_amdgcn_mfma_f32_16x16x32_bf16(ka1, qf[0][1], c0, 0,0,0);
      c1 = __builtin_amdgcn_mfma_f32_16x16x32_bf16(ka1, qf[1][1], c1, 0,0,0);
      st[0][t] = c0; st[1][t] = c1;
    }

    // ---- transform: p = exp(score) directly (all scores <= 0) ----
    uint32_t pbw[2][8];
    #pragma unroll
    for(int qt=0; qt<2; qt++){
      const float q2 = qq[qt];
      float ls = 0.f, dl = 0.f;
      #pragma unroll
      for(int t=0;t<4;t++){
        const f32x4 kkv = *(const f32x4*)(kkt + t*16 + g*4);
        float p[4];
        #pragma unroll
        for(int r=0;r<4;r++){
          const float qk = st[qt][t][r], kk = kkv[r];
          const float a = q2 + kk;
          if(HYP){
            const float u = fmaxf(fmaf(-2.f, qk, a), 0.f);
            const float v = fmaxf(fmaf(q2, kk, fmaf(-2.f, qk, 1.f)), EPSF);
            const float wz = __builtin_amdgcn_sqrtf(u*v);
            const float den = (u + v) + 2.f*wz;
            float ratio = (v - u) * __builtin_amdgcn_rcpf(den);
            ratio = fmaxf(ratio, 5.9604645e-8f);   // = (1-MAXT)/(1+MAXT) -> p_min 0.125
            p[r] = __builtin_amdgcn_exp2f(0.125f * __builtin_amdgcn_logf(ratio));
          } else {
            const float d2 = fmaxf(fmaf(-2.f, qk, a), 0.f) + 1e-12f;
            p[r] = __builtin_amdgcn_exp2f(-0.18033688f * __builtin_amdgcn_sqrtf(d2));
          }
        }
        ls += (p[0]+p[1])+(p[2]+p[3]);
        if(HYP){
          const f32x4 lv = *(const f32x4*)(lmt + t*16 + g*4);
          dl += p[0]*(lv[0]-1.f) + p[1]*(lv[1]-1.f) + p[2]*(lv[2]-1.f) + p[3]*(lv[3]-1.f);
        }
        pbw[qt][t*2]   = cvtpk(p[0], p[1]);
        pbw[qt][t*2+1] = cvtpk(p[2], p[3]);
      }
      ls += __shfl_xor(ls,16); ls += __shfl_xor(ls,32);
      lrun[qt] += ls;
      if(HYP){
        dl += __shfl_xor(dl,16); dl += __shfl_xor(dl,32);
        dnr[qt] += dl;
      }
    }

    // ---- PV: O^T += V^T * P^T ; V via ds_read_b64_tr_b16, P from registers ----
    const uint32_t va_kt = vaddr_base + (uint32_t)((kt&1)*8192);
    {
      u32x2 r00=trrd<0>(va_kt),    r01=trrd<512>(va_kt);
      u32x2 r10=trrd<2048>(va_kt), r11=trrd<2560>(va_kt);
      u32x2 r20=trrd<4096>(va_kt), r21=trrd<4608>(va_kt);
      u32x2 r30=trrd<6144>(va_kt), r31=trrd<6656>(va_kt);
      asm volatile("s_waitcnt lgkmcnt(0)" ::: "memory");
      __builtin_amdgcn_sched_barrier(0);
      bf16x8 pb0, pb1;
      { union{uint32_t u[4]; bf16x8 v;} c;
        c.u[0]=pbw[0][0]; c.u[1]=pbw[0][1]; c.u[2]=pbw[0][2]; c.u[3]=pbw[0][3]; pb0=c.v; }
      { union{uint32_t u[4]; bf16x8 v;} c;
        c.u[0]=pbw[1][0]; c.u[1]=pbw[1][1]; c.u[2]=pbw[1][2]; c.u[3]=pbw[1][3]; pb1=c.v; }
      __builtin_amdgcn_s_setprio(1);
      bf16x8 va;
      va = vcomb(r00,r01);
      oa[0][0] = __builtin_amdgcn_mfma_f32_16x16x32_bf16(va, pb0, oa[0][0], 0,0,0);
      oa[1][0] = __builtin_amdgcn_mfma_f32_16x16x32_bf16(va, pb1, oa[1][0], 0,0,0);
      va = vcomb(r10,r11);
      oa[0][1] = __builtin_amdgcn_mfma_f32_16x16x32_bf16(va, pb0, oa[0][1], 0,0,0);
      oa[1][1] = __builtin_amdgcn_mfma_f32_16x16x32_bf16(va, pb1, oa[1][1], 0,0,0);
      va = vcomb(r20,r21);
      oa[0][2] = __builtin_amdgcn_mfma_f32_16x16x32_bf16(va, pb0, oa[0][2], 0,0,0);
      oa[1][2] = __builtin_amdgcn_mfma_f32_16x16x32_bf16(va, pb1, oa[1][2], 0,0,0);
      va = vcomb(r30,r31);
      oa[0][3] = __builtin_amdgcn_mfma_f32_16x16x32_bf16(va, pb0, oa[0][3], 0,0,0);
      oa[1][3] = __builtin_amdgcn_mfma_f32_16x16x32_bf16(va, pb1, oa[1][3], 0,0,0);
      __builtin_amdgcn_s_setprio(0);
    }
    {
      u32x2 r00=trrd<1024>(va_kt), r01=trrd<1536>(va_kt);
      u32x2 r10=trrd<3072>(va_kt), r11=trrd<3584>(va_kt);
      u32x2 r20=trrd<5120>(va_kt), r21=trrd<5632>(va_kt);
      u32x2 r30=trrd<7168>(va_kt), r31=trrd<7680>(va_kt);
      asm volatile("s_waitcnt lgkmcnt(0)" ::: "memory");
      __builtin_amdgcn_sched_barrier(0);
      bf16x8 pb0, pb1;
      { union{uint32_t u[4]; bf16x8 v;} c;
        c.u[0]=pbw[0][4]; c.u[1]=pbw[0][5]; c.u[2]=pbw[0][6]; c.u[3]=pbw[0][7]; pb0=c.v; }
      { union{uint32_t u[4]; bf16x8 v;} c;
        c.u[0]=pbw[1][4]; c.u[1]=pbw[1][5]; c.u[2]=pbw[1][6]; c.u[3]=pbw[1][7]; pb1=c.v; }
      __builtin_amdgcn_s_setprio(1);
      bf16x8 va;
      va = vcomb(r00,r01);
      oa[0][0] = __builtin_amdgcn_mfma_f32_16x16x32_bf16(va, pb0, oa[0][0], 0,0,0);
      oa[1][0] = __builtin_amdgcn_mfma_f32_16x16x32_bf16(va, pb1, oa[1][0], 0,0,0);
      va = vcomb(r10,r11);
      oa[0][1] = __builtin_amdgcn_mfma_f32_16x16x32_bf16(va, pb0, oa[0][1], 0,0,0);
      oa[1][1] = __builtin_amdgcn_mfma_f32_16x16x32_bf16(va, pb1, oa[1][1], 0,0,0);
      va = vcomb(r20,r21);
      oa[0][2] = __builtin_amdgcn_mfma_f32_16x16x32_bf16(va, pb0, oa[0][2], 0,0,0);
      oa[1][2] = __builtin_amdgcn_mfma_f32_16x16x32_bf16(va, pb1, oa[1][2], 0,0,0);
      va = vcomb(r30,r31);
      oa[0][3] = __builtin_amdgcn_mfma_f32_16x16x32_bf16(va, pb0, oa[0][3], 0,0,0);
      oa[1][3] = __builtin_amdgcn_mfma_f32_16x16x32_bf16(va, pb1, oa[1][3], 0,0,0);
      __builtin_amdgcn_s_setprio(0);
    }
    __syncthreads();   // one barrier per kt: staging drained, buffers swap
  }

  // ---- epilogue: restage via LDS overlay (on K dbuf), coalesced store ----
  char* OTB = (char*)KsB;
  #pragma unroll
  for(int qt=0; qt<2; qt++){
    float scale;
    {
      const float invl = 1.f/lrun[qt];
      if(HYP){
        const float dn = fmaxf(dnr[qt]*invl, EPSF);
        scale = invl/dn;
      } else scale = invl;
    }
    __syncthreads();
    #pragma unroll
    for(int m=0;m<4;m++){
      f32x4 vv;
      vv[0]=oa[qt][m][0]*scale; vv[1]=oa[qt][m][1]*scale;
      vv[2]=oa[qt][m][2]*scale; vv[3]=oa[qt][m][3]*scale;
      *(f32x4*)(OTB + w*4096 + lr*256 + ((m*64 + g*16) ^ ((lr&7)<<4))) = vv;
    }
    __syncthreads();
    {
      const int row = tid >> 2, cw = tid & 3;
      const int wsrc = row >> 4, ql = row & 15;
      float vals[16];
      #pragma unroll
      for(int ii=0;ii<4;ii++)
        *(f32x4*)&vals[ii*4] = *(const f32x4*)(OTB + wsrc*4096 + ql*256 + ((cw*64 + ii*16) ^ ((ql&7)<<4)));
      const size_t go = (size_t)(q0 + qt*64 + row)*gstride + gbase + cw*16;
      *(uint4*)(outB + go)     = pack8(vals);
      *(uint4*)(outB + go + 8) = pack8(vals+8);
    }
  }
}

// =====================================================================
extern "C" void kernel_launch(void* const* d_in, const int* in_sizes, int n_in,
                              void* d_out, int out_size, void* d_ws, size_t ws_size,
                              hipStream_t stream)
{
  (void)in_sizes; (void)n_in; (void)out_size; (void)ws_size;
  const float* x    = (const float*)d_in[0];
  const float* ln1g = (const float*)d_in[1];
  const float* ln1b = (const float*)d_in[2];
  const float* ln2g = (const float*)d_in[3];
  const float* ln2b = (const float*)d_in[4];
  const float* Wq = (const float*)d_in[5];
  const float* bq = (const float*)d_in[6];
  const float* Wk = (const float*)d_in[7];
  const float* bk = (const float*)d_in[8];
  const float* Wv = (const float*)d_in[9];
  const float* bv = (const float*)d_in[10];
  const float* Wo = (const float*)d_in[11];
  const float* bo = (const float*)d_in[12];
  const float* W1 = (const float*)d_in[13];
  const float* b1 = (const float*)d_in[14];
  const float* W2 = (const float*)d_in[15];
  const float* b2 = (const float*)d_in[16];
  float* out = (float*)d_out;

  char* ws = (char*)d_ws;
  uint16_t* MXb = (uint16_t*)(ws);                          // 24MB bf16 GEMM scratch
  float*    X2  = (float*)   (ws + ((size_t)24<<20));       // 16MB fp32
  uint16_t* HB  = (uint16_t*)(ws + ((size_t)40<<20));       // 8MB
  uint16_t* QB  = (uint16_t*)(ws + ((size_t)48<<20));       // 8MB (Q,K,V contiguous)
  uint16_t* KB  = (uint16_t*)(ws + ((size_t)56<<20));
  uint16_t* VB  = (uint16_t*)(ws + ((size_t)64<<20));
  uint16_t* OB  = (uint16_t*)(ws + ((size_t)72<<20));
  uint16_t* F1B = (uint16_t*)(ws + ((size_t)80<<20));       // 32MB
  uint16_t* WB  = (uint16_t*)(ws + ((size_t)112<<20));      // 12MB (both experts)
  float*    YV  = (float*)   (ws + ((size_t)124<<20));      // expmap'd biases
  float*    NH  = (float*)   (ws + ((size_t)124<<20) + (64<<10));
  float*    NO  = NH + R_;
  float*    N3  = NO + R_;
  float*    N4  = N3 + R_;
  float*    qnG = (float*)   (ws + ((size_t)125<<20));      // [128][512]
  float*    knG = qnG + 65536;
  float*    lamG= knG + 65536;

  // ---- weights + biases (both experts) ----
  cvt_all<<<6144,256,0,stream>>>(Wq,Wk,Wv,Wo,W1,W2, WB);
  expmap_all<<<6,256,0,stream>>>(bq,bk,bv,bo,b1,b2, YV);

  // ================= Expert 0: Euclidean =================
  ln_k<<<R_,256,0,stream>>>(x, ln1g, ln1b, HB);
  gemm3<<<dim3(12,64),512,0,stream>>>(HB, WB, R_,1536,512, 6, bq, bk, bv, nullptr, nullptr, QB);
  qk_norms<<<2048,256,0,stream>>>(QB, KB, qnG, knG);
  attn3<0><<<dim3(4,128),256,0,stream>>>(QB, KB, VB, qnG, knG, nullptr, OB);
  gemm3<<<dim3(4,64),512,0,stream>>>(OB, WB+786432, R_,512,512, 2, bo, nullptr,nullptr, x, X2, nullptr);
  ln_k<<<R_,256,0,stream>>>(X2, ln2g, ln2b, HB);
  gemm3<<<dim3(16,64),512,0,stream>>>(HB, WB+1048576, R_,2048,512, 3, b1, nullptr,nullptr, nullptr, nullptr, F1B);
  gemm3<<<dim3(4,64),512,0,stream>>>(F1B, WB+2097152, R_,512,2048, 4, b2, nullptr,nullptr, X2, out, nullptr);

  // ================= Expert 1: Hyperbolic =================
  const float* x1 = x + (size_t)R_*E_;
  uint16_t* WBe = WB + 3145728;
  hyp_lnexp<<<R_,256,0,stream>>>(x1, ln1g+E_, ln1b+E_, HB, NH, 0);
  gemm3<<<dim3(12,64),512,0,stream>>>(HB, WBe, R_,1536,512, 5, nullptr,nullptr,nullptr,nullptr, nullptr, MXb);
  man_epi_qkv<<<dim3(R_,3),256,0,stream>>>(MXb, NH, YV, QB, qnG, knG, lamG);
  attn3<1><<<dim3(4,128),256,0,stream>>>(QB, KB, VB, qnG, knG, lamG, OB);
  o_finish2<<<R_,256,0,stream>>>(OB, HB, NO);
  gemm3<<<dim3(4,64),512,0,stream>>>(HB, WBe+786432, R_,512,512, 5, nullptr,nullptr,nullptr,nullptr, nullptr, MXb);
  man_epi<2><<<R_,256,0,stream>>>(MXb, NO, YV+1539, nullptr, nullptr, x1, X2, 0);
  hyp_lnexp<<<R_,256,0,stream>>>(X2, ln2g+E_, ln2b+E_, HB, N3, 1);
  gemm3<<<dim3(16,64),512,0,stream>>>(HB, WBe+1048576, R_,2048,512, 5, nullptr,nullptr,nullptr,nullptr, nullptr, F1B);
  man_epi<8><<<R_,256,0,stream>>>(F1B, N3, YV+2052, F1B, N4, nullptr, nullptr, 1);
  gemm3<<<dim3(4,64),512,0,stream>>>(F1B, WBe+2097152, R_,512,2048, 5, nullptr,nullptr,nullptr,nullptr, nullptr, MXb);
  man_epi<2><<<R_,256,0,stream>>>(MXb, N4, YV+4101, nullptr, nullptr, X2, out + (size_t)R_*E_, 1|8);
}